// Round 5
// baseline (465.269 us; speedup 1.0000x reference)
//
#include <hip/hip_runtime.h>
#include <hip/hip_bf16.h>
#include <math.h>

// PaGCN forward, restructured:
//   h0 = relu(AM ⊙ spmm(adjZ, (M⊙x)@W0) + b0)      (spmm gathers 128 bf16 feats)
//   h1 = relu(AM ⊙ spmm(adjZ, (M⊙h0)@W1) + b1)     (spmm gathers 64 bf16 feats)
//   out = log_softmax(spmm(adj, h1@W2) + b2)        (spmm gathers 40 bf16 feats)
//
// R13: launch-structure pass. R10-R12 single-kernel tweaks were all flat ->
// cost is spread across 10 serial dispatches + round-trips. Now 7 dispatches:
//  - prep_wt folded into hist_gemm0 (blk 0). gemm0 blocks load A-frags
//    first, then gate on device-scope flag + acquire __threadfence() before
//    reading wt0 (cross-XCD: regular-store->regular-load needs release/
//    acquire fences; flag via atomics). Grid 222<=256 -> all resident ->
//    poll deadlock-free.
//  - scan_one + scatter fused (scan_scatter): blocks 0..195 scan + publish
//    done-counter (fence+atomic); ALL 1568 blocks poll, acquire-fence, then
//    scatter 511-edge slices. __launch_bounds__(256,8) guarantees 1568 <
//    capacity residency; poller blocks can't deadlock scan blocks (scan
//    never waits on pollers).
//  - gemm2 folded into spmm64 epilogue: post-reduction every lane holds the
//    full h1 row; 16 readlane steps x uint2 W2^T loads -> y=h1@W2 in-wave,
//    write 40-col rows directly (f32 h1, better rounding). Kills a launch +
//    the h1 round-trip.
// Carried: LDS counting-sort hist (no global atomics), publish/poll scan,
// one 16B random store per edge (uint4 payload), no-LDS MFMA GEMMs, bf16
// gather targets, M folded into spmm128 epilogue, clamped epilogues.

typedef __attribute__((ext_vector_type(8))) short bf16x8;
typedef __attribute__((ext_vector_type(4))) float f32x4;

#define HIST_EPB_LOG 15
#define HIST_EPB 32768          // edges per hist block
#define NBINS 50176             // >= N, = 196*256, even (u16-pair packing)
#define NBMAX 26                // reserved chunk capacity (E <= 26*32768)
#define SCAN_BLOCKS 196         // 256 bins per block = 50176
#define SS_GRID 1568            // scan_scatter grid (8*196; <= resident cap)

__device__ __forceinline__ float rl_f(float v, int j) {
    return __builtin_bit_cast(float,
        __builtin_amdgcn_readlane(__builtin_bit_cast(int, v), j));
}
__device__ __forceinline__ int rl_i(int v, int j) {
    return __builtin_amdgcn_readlane(v, j);
}
__device__ __forceinline__ unsigned short f2bf(float f) {
    unsigned u = __builtin_bit_cast(unsigned, f);
    u += 0x7fffu + ((u >> 16) & 1u);   // round-to-nearest-even
    return (unsigned short)(u >> 16);
}
__device__ __forceinline__ unsigned pack2bf(float lo, float hi) {
    return (unsigned)f2bf(lo) | ((unsigned)f2bf(hi) << 16);
}
__device__ __forceinline__ float bf_lo(unsigned u) {
    return __builtin_bit_cast(float, u << 16);
}
__device__ __forceinline__ float bf_hi(unsigned u) {
    return __builtin_bit_cast(float, u & 0xffff0000u);
}
__device__ __forceinline__ float clampf(float v) {   // NaN -> -1e30 (finite)
    return fminf(fmaxf(v, -1e30f), 1e30f);
}

// ---------------- MFMA GEMM body (no LDS, no barriers) ----------------
// 4 waves per 256-thread group, each wave 16 rows x COLS via 16x16x32 bf16
// MFMA. Fragment maps (HW-verified): A[m=lane&15][k=(lane>>4)*8+j],
// B[k=(lane>>4)*8+j][n=lane&15], D[row=(lane>>4)*4+reg][col=lane&15].

template <int K, int COLS, int NTPAD>
__device__ __forceinline__ void gemm_mfma_body_bf16(const unsigned short* __restrict__ A,
                                                    const unsigned short* __restrict__ Wt,
                                                    unsigned short* __restrict__ outp,
                                                    int n, int bid, int tid) {
    constexpr int KS = K / 32;
    const int lane = tid & 63;
    const int wid = tid >> 6;
    const int m15 = lane & 15;
    const int q = lane >> 4;
    const int rA = bid * 64 + wid * 16 + m15;

    bf16x8 a[KS];
#pragma unroll
    for (int ks = 0; ks < KS; ++ks) {
        uint4 z = make_uint4(0u, 0u, 0u, 0u);
        if (rA < n) z = *(const uint4*)(A + (size_t)rA * K + ks * 32 + q * 8);
        a[ks] = __builtin_bit_cast(bf16x8, z);
    }

#pragma unroll
    for (int nt = 0; nt < NTPAD / 16; ++nt) {
        f32x4 acc = {0.f, 0.f, 0.f, 0.f};
        const int bn = nt * 16 + m15;
#pragma unroll
        for (int ks = 0; ks < KS; ++ks) {
            const uint4 z = *(const uint4*)(Wt + (size_t)bn * K + ks * 32 + q * 8);
            acc = __builtin_amdgcn_mfma_f32_16x16x32_bf16(
                a[ks], __builtin_bit_cast(bf16x8, z), acc, 0, 0, 0);
        }
        const int gc = nt * 16 + m15;
#pragma unroll
        for (int rr = 0; rr < 4; ++rr) {
            const int gr = bid * 64 + wid * 16 + q * 4 + rr;
            bool ok = gr < n;
            if constexpr (NTPAD != COLS) ok = ok && (gc < COLS);
            if (ok) outp[(size_t)gr * COLS + gc] = f2bf(clampf(acc[rr]));
        }
    }
}

template <int K, int COLS, int NTPAD>
__launch_bounds__(256)
__global__ void gemm_mfma(const unsigned short* __restrict__ A,
                          const unsigned short* __restrict__ Wt,
                          unsigned short* __restrict__ out, int n) {
    gemm_mfma_body_bf16<K, COLS, NTPAD>(A, Wt, out, n, blockIdx.x, threadIdx.x);
}

// ---------------- fused: W prep (blk 0) + LDS histogram (blk 1..NB)
//                  + gemm0 MFMA (rest, flag-gated on wt0) ----------------
// All 1+NB+gemmB4 = 222 blocks resident (1/CU: 98KB LDS) -> flag poll is
// deadlock-free. Release: prep stores -> __threadfence -> atomicExch flag.
// Acquire: poll flag -> __syncthreads -> __threadfence -> read wt0.

__launch_bounds__(1024)
__global__ void hist_gemm0(const int* __restrict__ row,
                           unsigned short* __restrict__ cntmat,
                           unsigned short* __restrict__ lrank, int E, int NB,
                           const float* __restrict__ x, const float* __restrict__ Mv,
                           const float* __restrict__ W0, const float* __restrict__ W1,
                           const float* __restrict__ W2,
                           unsigned short* __restrict__ wt0,
                           unsigned short* __restrict__ wt1,
                           unsigned short* __restrict__ wt2,
                           unsigned short* __restrict__ t_buf,
                           unsigned long long* __restrict__ gpub, int n) {
    __shared__ __align__(16) unsigned hcnt[NBINS / 2];   // 98KB: u16 bin pairs
    const int blk = blockIdx.x;
    const int t = threadIdx.x;
    if (blk == 0) {
        // ---- prep: Wt[n][k] = bf16(W[k][n]) ----
        for (int idx = t; idx < 128 * 128; idx += 1024) {
            int nn = idx >> 7, k = idx & 127;
            wt0[idx] = f2bf(W0[k * 128 + nn]);
        }
        for (int idx = t; idx < 64 * 128; idx += 1024) {
            int nn = idx >> 7, k = idx & 127;
            wt1[idx] = f2bf(W1[k * 64 + nn]);
        }
        for (int idx = t; idx < 48 * 64; idx += 1024) {
            int nn = idx >> 6, k = idx & 63;
            wt2[idx] = (nn < 40) ? f2bf(W2[k * 40 + nn]) : (unsigned short)0;
        }
        __threadfence();
        __syncthreads();
        if (t == 0) atomicExch(&gpub[255], 1ULL);        // wt-ready flag
    } else if (blk <= NB) {
        // ---- histogram chunk blk-1 (counting-sort ranks, LDS u16 pairs) ----
        uint4* h4 = (uint4*)hcnt;
        const uint4 z4 = make_uint4(0u, 0u, 0u, 0u);
        for (int i = t; i < NBINS / 8; i += 1024) h4[i] = z4;
        __syncthreads();
        const int s = (blk - 1) << HIST_EPB_LOG;
        const int e = min(E, s + HIST_EPB);
        for (int i = s + t; i < e; i += 1024) {
            const int r = row[i];               // r < n <= NBINS
            const unsigned sh = (unsigned)(r & 1) << 4;
            const unsigned old = atomicAdd(&hcnt[r >> 1], 1u << sh);
            lrank[i] = (unsigned short)((old >> sh) & 0xffffu);
        }
        __syncthreads();
        uint4* dst = (uint4*)(cntmat + (size_t)(blk - 1) * NBINS);
        for (int i = t; i < NBINS / 8; i += 1024) dst[i] = h4[i];
    } else {
        // ---- gemm0: (M⊙x)@W0 -> t_buf bf16, 4x 256-thread groups ----
        const int tid = t & 255;
        const int bid = (blk - 1 - NB) * 4 + (t >> 8);
        const int lane = tid & 63;
        const int wid = tid >> 6;
        const int m15 = lane & 15;
        const int q = lane >> 4;
        const int rA = bid * 64 + wid * 16 + m15;

        bf16x8 a[4];
        {
            float m = 1.0f;
            if (rA < n) m = Mv[rA];
#pragma unroll
            for (int ks = 0; ks < 4; ++ks) {
                float4 lo = make_float4(0.f, 0.f, 0.f, 0.f);
                float4 hi = make_float4(0.f, 0.f, 0.f, 0.f);
                if (rA < n) {
                    lo = *(const float4*)(x + (size_t)rA * 128 + ks * 32 + q * 8);
                    hi = *(const float4*)(x + (size_t)rA * 128 + ks * 32 + q * 8 + 4);
                }
                union { bf16x8 v; unsigned short u[8]; } pk;
                pk.u[0] = f2bf(lo.x * m); pk.u[1] = f2bf(lo.y * m);
                pk.u[2] = f2bf(lo.z * m); pk.u[3] = f2bf(lo.w * m);
                pk.u[4] = f2bf(hi.x * m); pk.u[5] = f2bf(hi.y * m);
                pk.u[6] = f2bf(hi.z * m); pk.u[7] = f2bf(hi.w * m);
                a[ks] = pk.v;
            }
        }
        // gate on wt0 ready (acquire)
        if (t == 0) {
            while (atomicAdd(&gpub[255], 0ULL) == 0ULL) __builtin_amdgcn_s_sleep(2);
        }
        __syncthreads();
        __threadfence();
#pragma unroll
        for (int nt = 0; nt < 8; ++nt) {
            f32x4 acc = {0.f, 0.f, 0.f, 0.f};
            const int bn = nt * 16 + m15;
#pragma unroll
            for (int ks = 0; ks < 4; ++ks) {
                const uint4 z = *(const uint4*)(wt0 + (size_t)bn * 128 + ks * 32 + q * 8);
                acc = __builtin_amdgcn_mfma_f32_16x16x32_bf16(
                    a[ks], __builtin_bit_cast(bf16x8, z), acc, 0, 0, 0);
            }
            const int gc = nt * 16 + m15;
#pragma unroll
            for (int rr = 0; rr < 4; ++rr) {
                const int gr = bid * 64 + wid * 16 + q * 4 + rr;
                if (gr < n) t_buf[(size_t)gr * 128 + gc] = f2bf(clampf(acc[rr]));
            }
        }
    }
}

// ---------------- fused scan + scatter ----------------
// Blocks 0..195: per-256-bin scan (totals -> publish gpub[g] -> poll prior
// -> rp + absolute cmabs) then publish done-counter gpub[254].
// ALL blocks: poll counter==196, acquire-fence, scatter 16B payload for a
// contiguous edge slice. Residency: __launch_bounds__(256,8) => VGPR<=64 =>
// 8 blocks/CU => 2048 >= SS_GRID all resident; and poller blocks can never
// starve scan blocks (scan never waits on pollers) -> no deadlock either way.

__launch_bounds__(256, 8)
__global__ void scan_scatter(const unsigned short* __restrict__ cm,
                             unsigned* __restrict__ cmabs, int* __restrict__ rp,
                             unsigned long long* __restrict__ gpub,
                             const int* __restrict__ row, const int* __restrict__ col,
                             const float* __restrict__ vA, const float* __restrict__ vZ,
                             const unsigned short* __restrict__ lrank,
                             uint4* __restrict__ packed16,
                             int n, int NB, int E) {
    __shared__ int sd[256];
    const int g = blockIdx.x;
    const int t = threadIdx.x;

    if (g < SCAN_BLOCKS) {
        const int bin = g * 256 + t;
        unsigned tot = 0;
        for (int b = 0; b < NB; ++b) tot += cm[(size_t)b * NBINS + bin];

        sd[t] = (int)tot;
        __syncthreads();
        for (int off = 1; off < 256; off <<= 1) {
            int xv = (t >= off) ? sd[t - off] : 0;
            __syncthreads();
            sd[t] += xv;
            __syncthreads();
        }
        const int excl = sd[t] - (int)tot;
        const int gtot = sd[255];
        __syncthreads();

        if (t == 0)
            atomicExch(&gpub[g], (1ULL << 32) | (unsigned long long)(unsigned)gtot);

        int my = 0;
        for (int p = t; p < g; p += 256) {
            unsigned long long v;
            do { v = atomicAdd(&gpub[p], 0ULL); } while ((v >> 32) == 0ULL);
            my += (int)(unsigned)v;
        }
        sd[t] = my;
        __syncthreads();
        for (int off = 128; off > 0; off >>= 1) {
            if (t < off) sd[t] += sd[t + off];
            __syncthreads();
        }
        const int base = sd[0];

        const int rpf = base + excl;
        if (bin < n) rp[bin] = rpf;
        if (g == 0 && t == 0) rp[n] = E;

        int run = rpf;
        for (int b = 0; b < NB; ++b) {
            cmabs[(size_t)b * NBINS + bin] = (unsigned)run;
            run += (int)cm[(size_t)b * NBINS + bin];
        }
        __threadfence();                       // release cmabs/rp stores
        __syncthreads();
        if (t == 0) atomicAdd(&gpub[254], 1ULL);
    }

    // grid-wide gate: all 196 scan blocks done
    if (t == 0) {
        while (atomicAdd(&gpub[254], 0ULL) < (unsigned long long)SCAN_BLOCKS)
            __builtin_amdgcn_s_sleep(2);
    }
    __syncthreads();
    __threadfence();                           // acquire: invalidate stale L1/L2

    // scatter slice (one 16B random store per edge)
    const int ce = (E + SS_GRID - 1) / SS_GRID;
    const int s0 = g * ce;
    const int s1 = min(E, s0 + ce);
    for (int i = s0 + t; i < s1; i += 256) {
        const int r = row[i];
        const int pos = (int)(cmabs[(size_t)(i >> HIST_EPB_LOG) * NBINS + r]
                              + (unsigned)lrank[i]);
        uint4 pk;
        pk.x = (unsigned)col[i];
        pk.y = __builtin_bit_cast(unsigned, vZ[i]);
        pk.z = __builtin_bit_cast(unsigned, vA[i]);
        pk.w = 0u;
        packed16[pos] = pk;
    }
}

// ---------------- SpMM F=128: wave/row, 16-deep bursts; out = M⊙relu(...) bf16 ----------------

__launch_bounds__(256)
__global__ void spmm128_kernel(const uint4* __restrict__ packed16,
                               const int* __restrict__ rp, const unsigned short* __restrict__ X,
                               const float* __restrict__ AM, const float* __restrict__ Mv,
                               const float* __restrict__ bias,
                               unsigned short* __restrict__ out, int n) {
    const int lane = threadIdx.x & 63;
    const int r = (int)((blockIdx.x * (unsigned)blockDim.x + threadIdx.x) >> 6);
    if (r >= n) return;
    const int s = __builtin_amdgcn_readfirstlane(rp[r]);
    const int e = __builtin_amdgcn_readfirstlane(rp[r + 1]);

    float acc0 = 0.0f, acc1 = 0.0f;
    for (int base = s; base < e; base += 64) {
        const int nn = min(64, e - base);
        int ci = 0; float vf = 0.0f;
        if (lane < nn) {
            const uint4 pk = packed16[base + lane];
            ci = (int)pk.x;
            vf = __builtin_bit_cast(float, pk.y);
        }
        int j = 0;
        for (; j + 16 <= nn; j += 16) {         // avg deg = 16: one latency round
            unsigned u[16];
#pragma unroll
            for (int q = 0; q < 16; ++q) {
                const int cq = rl_i(ci, j + q);
                u[q] = *(const unsigned*)(X + (size_t)cq * 128 + lane * 2);
            }
#pragma unroll
            for (int q = 0; q < 16; ++q) {
                const float vq = rl_f(vf, j + q);
                acc0 += vq * bf_lo(u[q]);
                acc1 += vq * bf_hi(u[q]);
            }
        }
        for (; j + 8 <= nn; j += 8) {
            unsigned u[8];
#pragma unroll
            for (int q = 0; q < 8; ++q) {
                const int cq = rl_i(ci, j + q);
                u[q] = *(const unsigned*)(X + (size_t)cq * 128 + lane * 2);
            }
#pragma unroll
            for (int q = 0; q < 8; ++q) {
                const float vq = rl_f(vf, j + q);
                acc0 += vq * bf_lo(u[q]);
                acc1 += vq * bf_hi(u[q]);
            }
        }
        for (; j < nn; ++j) {
            const int cq = rl_i(ci, j);
            const float vq = rl_f(vf, j);
            const unsigned u = *(const unsigned*)(X + (size_t)cq * 128 + lane * 2);
            acc0 += vq * bf_lo(u);
            acc1 += vq * bf_hi(u);
        }
    }

    const float am = AM[r];
    const float mr = Mv[r];   // fold M (>=0): M⊙relu(y) = relu(M⊙y)
    const float o0 = fminf(fmaxf((acc0 * am + bias[2 * lane]) * mr, 0.0f), 1e30f);
    const float o1 = fminf(fmaxf((acc1 * am + bias[2 * lane + 1]) * mr, 0.0f), 1e30f);
    ((unsigned*)out)[(size_t)r * 64 + lane] = pack2bf(o0, o1);
}

// ---------------- SpMM F=64 + fused gemm2: out40 = relu(AM⊙agg+b1)@W2 ----------------
// Gather as before (4 edges/wave, uint2/lane). After the xor-16/xor-32
// reductions ALL 64 lanes hold the reduced a0..a3 for ls=lane&15 -> every
// lane computes the h1 epilogue, then lane j accumulates y_j = sum_k
// h1[k]*W2[k][j] via 16 readlane steps (wt2 is [48][64] transposed, rows
// 40..47 zero).

__launch_bounds__(256)
__global__ void spmm64_gemm2(const uint4* __restrict__ packed16,
                             const int* __restrict__ rp, const unsigned short* __restrict__ X,
                             const float* __restrict__ AM, const float* __restrict__ bias1,
                             const unsigned short* __restrict__ wt2,
                             unsigned short* __restrict__ out40, int n) {
    const int lane = threadIdx.x & 63;
    const int g = lane >> 4;        // edge slot 0..3
    const int ls = lane & 15;       // feat quad: feats 4*ls..4*ls+3
    const int r = (int)((blockIdx.x * (unsigned)blockDim.x + threadIdx.x) >> 6);
    if (r >= n) return;
    const int s = __builtin_amdgcn_readfirstlane(rp[r]);
    const int e = __builtin_amdgcn_readfirstlane(rp[r + 1]);

    float a0 = 0.0f, a1 = 0.0f, a2 = 0.0f, a3 = 0.0f;
    for (int base = s; base < e; base += 64) {
        const int nn = min(64, e - base);
        int ci = 0; float vf = 0.0f;
        if (lane < nn) {
            const uint4 pk = packed16[base + lane];
            ci = (int)pk.x;
            vf = __builtin_bit_cast(float, pk.y);
        }
        for (int j = 0; j < nn; j += 16) {
#pragma unroll
            for (int q = 0; q < 4; ++q) {
                const int jj = j + 4 * q + g;
                const bool ok = jj < nn;
                const int idx = jj & 63;
                const int c = __shfl(ci, idx);
                const float v = __shfl(vf, idx);
                if (ok) {
                    const uint2 u = *(const uint2*)(X + (size_t)c * 64 + ls * 4);
                    a0 += v * bf_lo(u.x);
                    a1 += v * bf_hi(u.x);
                    a2 += v * bf_lo(u.y);
                    a3 += v * bf_hi(u.y);
                }
            }
        }
    }
    a0 += __shfl_xor(a0, 16); a0 += __shfl_xor(a0, 32);
    a1 += __shfl_xor(a1, 16); a1 += __shfl_xor(a1, 32);
    a2 += __shfl_xor(a2, 16); a2 += __shfl_xor(a2, 32);
    a3 += __shfl_xor(a3, 16); a3 += __shfl_xor(a3, 32);

    // h1 epilogue in every lane (for its ls)
    const float am = AM[r];
    const float o0 = fminf(fmaxf(a0 * am + bias1[4 * ls + 0], 0.0f), 1e30f);
    const float o1 = fminf(fmaxf(a1 * am + bias1[4 * ls + 1], 0.0f), 1e30f);
    const float o2 = fminf(fmaxf(a2 * am + bias1[4 * ls + 2], 0.0f), 1e30f);
    const float o3 = fminf(fmaxf(a3 * am + bias1[4 * ls + 3], 0.0f), 1e30f);

    // gemm2: lane j computes y_j (j<48; rows 40..47 of wt2 are zero-padded)
    const int wrow = (lane < 48) ? lane : 0;
    const unsigned short* wp = wt2 + wrow * 64;
    float y = 0.0f;
#pragma unroll
    for (int qq = 0; qq < 16; ++qq) {
        const uint2 w = *(const uint2*)(wp + 4 * qq);
        const float h0v = rl_f(o0, qq);
        const float h1v = rl_f(o1, qq);
        const float h2v = rl_f(o2, qq);
        const float h3v = rl_f(o3, qq);
        y += h0v * bf_lo(w.x) + h1v * bf_hi(w.x)
           + h2v * bf_lo(w.y) + h3v * bf_hi(w.y);
    }
    if (lane < 40) out40[(size_t)r * 40 + lane] = f2bf(clampf(y));
}

// ---------------- SpMM F=40 + log_softmax: 3 edges/wave, 24 in flight ----------------

__launch_bounds__(256)
__global__ void spmm40_kernel(const uint4* __restrict__ packed16,
                              const int* __restrict__ rp, const unsigned short* __restrict__ X,
                              const float* __restrict__ bias,
                              float* __restrict__ out, int n) {
    const int lane = threadIdx.x & 63;
    const int g = lane / 20;
    const int ls = lane - 20 * g;
    const bool active = g < 3;
    const int r = (int)((blockIdx.x * (unsigned)blockDim.x + threadIdx.x) >> 6);
    if (r >= n) return;
    const int s = __builtin_amdgcn_readfirstlane(rp[r]);
    const int e = __builtin_amdgcn_readfirstlane(rp[r + 1]);

    float acc0 = 0.0f, acc1 = 0.0f;
    for (int base = s; base < e; base += 64) {
        const int nn = min(64, e - base);
        int ci = 0; float vf = 0.0f;
        if (lane < nn) {
            const uint4 pk = packed16[base + lane];
            ci = (int)pk.x;
            vf = __builtin_bit_cast(float, pk.z);    // adj (not adjZ) values
        }
        for (int j = 0; j < nn; j += 24) {
#pragma unroll
            for (int q = 0; q < 8; ++q) {
                const int jj = j + 3 * q + g;
                const bool ok = active && jj < nn;
                const int idx = jj & 63;
                const int c = __shfl(ci, idx);
                const float v = __shfl(vf, idx);
                if (ok) {
                    const unsigned u = *(const unsigned*)(X + (size_t)c * 40 + ls * 2);
                    acc0 += v * bf_lo(u);
                    acc1 += v * bf_hi(u);
                }
            }
        }
    }
    {
        const float a1 = __shfl(acc0, (lane + 20) & 63);
        const float a2 = __shfl(acc0, (lane + 40) & 63);
        const float b1 = __shfl(acc1, (lane + 20) & 63);
        const float b2 = __shfl(acc1, (lane + 40) & 63);
        acc0 += a1 + a2;
        acc1 += b1 + b2;
    }

    const bool own = lane < 20;
    const float vv0 = own ? fminf(fmaxf(acc0 + bias[2 * ls], -1e30f), 1e30f) : -INFINITY;
    const float vv1 = own ? fminf(fmaxf(acc1 + bias[2 * ls + 1], -1e30f), 1e30f) : -INFINITY;
    float mx = fmaxf(vv0, vv1);
#pragma unroll
    for (int off = 32; off > 0; off >>= 1) mx = fmaxf(mx, __shfl_xor(mx, off));
    float sum = own ? (expf(vv0 - mx) + expf(vv1 - mx)) : 0.0f;
#pragma unroll
    for (int off = 32; off > 0; off >>= 1) sum += __shfl_xor(sum, off);
    if (own) {
        const float lse = mx + logf(sum);
        *(float2*)(out + (size_t)r * 40 + ls * 2) = make_float2(vv0 - lse, vv1 - lse);
    }
}

// ---------------- launch ----------------

extern "C" void kernel_launch(void* const* d_in, const int* in_sizes, int n_in,
                              void* d_out, int out_size, void* d_ws, size_t ws_size,
                              hipStream_t stream) {
    const float* x    = (const float*)d_in[0];
    const float* M    = (const float*)d_in[1];
    const float* AM   = (const float*)d_in[2];
    const float* adjv = (const float*)d_in[3];
    const float* adjZ = (const float*)d_in[4];
    const float* W0   = (const float*)d_in[5];
    const float* b0   = (const float*)d_in[6];
    const float* W1   = (const float*)d_in[7];
    const float* b1   = (const float*)d_in[8];
    const float* W2   = (const float*)d_in[9];
    const float* b2   = (const float*)d_in[10];
    const int* row    = (const int*)d_in[11];
    const int* col    = (const int*)d_in[12];
    float* out = (float*)d_out;

    const int n = in_sizes[1];   // N  (must be <= NBINS = 50176)
    const int E = in_sizes[3];   // edges (<= NBMAX*32768)

    // workspace layout (~39 MB):
    //   t_buf  : N*128 bf16 (gemm0 out / gemm1 out)
    //   wt0/1/2: bf16 W^T arrays
    //   h region (N*128 bf16 reserve) aliased by lrank/cntmat/cmabs (dead
    //     before spmm128 writes h_buf); later h0 [N][128], then t40 [N][40]
    //   rp     : N+2 int
    //   gpub   : 256 u64 sync slots ([0..195] scan, [254] done-ctr, [255] wt flag)
    //   packed16: E uint4 {col, vZ, vA, 0}
    unsigned short* t_buf = (unsigned short*)d_ws;          // N*128 bf16
    unsigned short* wt0 = t_buf + (size_t)n * 128;          // 128*128
    unsigned short* wt1 = wt0 + 128 * 128;                  // 64*128
    unsigned short* wt2 = wt1 + 64 * 128;                   // 48*64
    unsigned short* h_buf = wt2 + 48 * 64;                  // N*128 bf16 reserve
    unsigned short* lrank  = h_buf;                         // E u16
    unsigned short* cntmat = lrank + (size_t)E;             // [NBMAX][NBINS] u16
    unsigned* cmabs = (unsigned*)(cntmat + (size_t)NBMAX * NBINS);
    int* rp = (int*)(h_buf + (size_t)n * 128);              // N+1 (+pad)
    unsigned long long* gpub = (unsigned long long*)
        (((uintptr_t)(rp + n + 2) + 7) & ~(uintptr_t)7);    // 256 u64
    uint4* packed16 = (uint4*)
        (((uintptr_t)(gpub + 256) + 15) & ~(uintptr_t)15);  // E uint4

    const int NB = (E + HIST_EPB - 1) >> HIST_EPB_LOG;      // hist chunks (<=26)
    const int gemmBlocks = (n + 63) / 64;                   // 4-wave gemm groups
    const int gemmB4 = (gemmBlocks + 3) / 4;                // 1024-thr gemm blocks

    // zero sync slots (poisoned every iteration by the harness)
    hipMemsetAsync(gpub, 0, 256 * sizeof(unsigned long long), stream);

    // fused W-prep + LDS histogram + gemm0 MFMA (grid 1+NB+gemmB4 <= 256)
    hist_gemm0<<<1 + NB + gemmB4, 1024, 0, stream>>>(row, cntmat, lrank, E, NB,
                                                     x, M, W0, W1, W2,
                                                     wt0, wt1, wt2, t_buf, gpub, n);

    // fused scan (196 blocks) + scatter (all 1568 blocks)
    scan_scatter<<<SS_GRID, 256, 0, stream>>>(cntmat, cmabs, rp, gpub,
                                              row, col, adjv, adjZ, lrank,
                                              packed16, n, NB, E);

    const int spmmBlocks = (n + 3) / 4;   // 4 rows (waves) per block

    // layer 0 aggregate: h_buf = M⊙relu(AM⊙agg+b0) bf16 (overwrites aliases)
    spmm128_kernel<<<spmmBlocks, 256, 0, stream>>>(packed16, rp, t_buf, AM, M, b0, h_buf, n);
    // layer 1: t_buf = h0@W1 bf16 (M already folded into h0)
    gemm_mfma<128, 64, 64><<<gemmBlocks, 256, 0, stream>>>(h_buf, wt1, t_buf, n);
    // layer 1 aggregate + fused gemm2: h_buf(40-stride) = relu(AM⊙agg+b1)@W2
    spmm64_gemm2<<<spmmBlocks, 256, 0, stream>>>(packed16, rp, t_buf, AM, b1, wt2, h_buf, n);
    // layer 2 aggregate + log_softmax
    spmm40_kernel<<<spmmBlocks, 256, 0, stream>>>(packed16, rp, h_buf, b2, out, n);
}

// Round 7
// 462.002 us; speedup vs baseline: 1.0071x; 1.0071x over previous
//
#include <hip/hip_runtime.h>
#include <hip/hip_bf16.h>
#include <math.h>

// PaGCN forward, restructured:
//   h0 = relu(AM ⊙ spmm(adjZ, (M⊙x)@W0) + b0)      (spmm gathers 128 bf16 feats)
//   h1 = relu(AM ⊙ spmm(adjZ, (M⊙h0)@W1) + b1)     (spmm gathers 64 bf16 feats)
//   out = log_softmax(spmm(adj, h1@W2) + b2)        (spmm gathers 40 bf16 feats)
//
// R14 (resubmit; R6 bench was an infra timeout, no measurement): recover
// from R13's spin-storm. scan_scatter's grid-wide gate (1568 blocks x
// atomicAdd(addr,0) on ONE line) serialized at the coherence point ->
// 170µs. Fixes:
//  - scan/scatter UN-fused back to R12's two kernels (standalone scatter at
//    3125 blocks needs no sync and measured 43µs).
//  - all remaining polls use __hip_atomic_load(ACQUIRE, AGENT scope) -- read
//    spins don't serialize; RMW spins do (R13 lesson).
// Kept from R13 (both proven correct in the passing 465µs run, structurally
// safe):
//  - prep_wt fused into hist_gemm0 blk 0 (only ~56 gemm waves briefly gate
//    on the wt-ready flag; release = fence+atomicExch, acquire = atomic
//    load + fence).
//  - gemm2 fused into spmm64 epilogue (in-wave 16-step readlane y=h1@W2,
//    f32 h1 -> better rounding, kills a launch + h1 round-trip).
// Carried: LDS counting-sort hist (no global atomics), 196-block publish/
// poll scan (distinct addresses, read-spin), one 16B random store per edge,
// no-LDS MFMA GEMMs (W L1-resident), bf16 gather targets, M folded into
// spmm128 epilogue, clamped epilogues, 16-deep spmm128 bursts.

typedef __attribute__((ext_vector_type(8))) short bf16x8;
typedef __attribute__((ext_vector_type(4))) float f32x4;

#define HIST_EPB_LOG 15
#define HIST_EPB 32768          // edges per hist block
#define NBINS 50176             // >= N, = 196*256, even (u16-pair packing)
#define NBMAX 26                // reserved chunk capacity (E <= 26*32768)
#define SCAN_BLOCKS 196         // 256 bins per block = 50176

__device__ __forceinline__ float rl_f(float v, int j) {
    return __builtin_bit_cast(float,
        __builtin_amdgcn_readlane(__builtin_bit_cast(int, v), j));
}
__device__ __forceinline__ int rl_i(int v, int j) {
    return __builtin_amdgcn_readlane(v, j);
}
__device__ __forceinline__ unsigned short f2bf(float f) {
    unsigned u = __builtin_bit_cast(unsigned, f);
    u += 0x7fffu + ((u >> 16) & 1u);   // round-to-nearest-even
    return (unsigned short)(u >> 16);
}
__device__ __forceinline__ unsigned pack2bf(float lo, float hi) {
    return (unsigned)f2bf(lo) | ((unsigned)f2bf(hi) << 16);
}
__device__ __forceinline__ float bf_lo(unsigned u) {
    return __builtin_bit_cast(float, u << 16);
}
__device__ __forceinline__ float bf_hi(unsigned u) {
    return __builtin_bit_cast(float, u & 0xffff0000u);
}
__device__ __forceinline__ float clampf(float v) {   // NaN -> -1e30 (finite)
    return fminf(fmaxf(v, -1e30f), 1e30f);
}
__device__ __forceinline__ unsigned long long aload(const unsigned long long* p) {
    return __hip_atomic_load(p, __ATOMIC_ACQUIRE, __HIP_MEMORY_SCOPE_AGENT);
}

// ---------------- MFMA GEMM (no LDS, no barriers) ----------------
// 4 waves per 256-thread group, each wave 16 rows x COLS via 16x16x32 bf16
// MFMA. Fragment maps (HW-verified): A[m=lane&15][k=(lane>>4)*8+j],
// B[k=(lane>>4)*8+j][n=lane&15], D[row=(lane>>4)*4+reg][col=lane&15].

template <int K, int COLS, int NTPAD>
__launch_bounds__(256)
__global__ void gemm_mfma(const unsigned short* __restrict__ A,
                          const unsigned short* __restrict__ Wt,
                          unsigned short* __restrict__ outp, int n) {
    constexpr int KS = K / 32;
    const int tid = threadIdx.x;
    const int bid = blockIdx.x;
    const int lane = tid & 63;
    const int wid = tid >> 6;
    const int m15 = lane & 15;
    const int q = lane >> 4;
    const int rA = bid * 64 + wid * 16 + m15;

    bf16x8 a[KS];
#pragma unroll
    for (int ks = 0; ks < KS; ++ks) {
        uint4 z = make_uint4(0u, 0u, 0u, 0u);
        if (rA < n) z = *(const uint4*)(A + (size_t)rA * K + ks * 32 + q * 8);
        a[ks] = __builtin_bit_cast(bf16x8, z);
    }

#pragma unroll
    for (int nt = 0; nt < NTPAD / 16; ++nt) {
        f32x4 acc = {0.f, 0.f, 0.f, 0.f};
        const int bn = nt * 16 + m15;
#pragma unroll
        for (int ks = 0; ks < KS; ++ks) {
            const uint4 z = *(const uint4*)(Wt + (size_t)bn * K + ks * 32 + q * 8);
            acc = __builtin_amdgcn_mfma_f32_16x16x32_bf16(
                a[ks], __builtin_bit_cast(bf16x8, z), acc, 0, 0, 0);
        }
        const int gc = nt * 16 + m15;
#pragma unroll
        for (int rr = 0; rr < 4; ++rr) {
            const int gr = bid * 64 + wid * 16 + q * 4 + rr;
            bool ok = gr < n;
            if constexpr (NTPAD != COLS) ok = ok && (gc < COLS);
            if (ok) outp[(size_t)gr * COLS + gc] = f2bf(clampf(acc[rr]));
        }
    }
}

// ---------------- fused: W prep (blk 0) + LDS histogram (blk 1..NB)
//                  + gemm0 MFMA (rest, flag-gated on wt0) ----------------
// Grid 1+NB+gemmB4 = 222 <= 256 CUs at 1 block/CU (98KB LDS) -> all blocks
// resident -> flag poll deadlock-free. Release: prep stores -> __threadfence
// -> atomicExch flag. Acquire: atomic-load flag -> __syncthreads -> fence.

__launch_bounds__(1024)
__global__ void hist_gemm0(const int* __restrict__ row,
                           unsigned short* __restrict__ cntmat,
                           unsigned short* __restrict__ lrank, int E, int NB,
                           const float* __restrict__ x, const float* __restrict__ Mv,
                           const float* __restrict__ W0, const float* __restrict__ W1,
                           const float* __restrict__ W2,
                           unsigned short* __restrict__ wt0,
                           unsigned short* __restrict__ wt1,
                           unsigned short* __restrict__ wt2,
                           unsigned short* __restrict__ t_buf,
                           unsigned long long* __restrict__ gpub, int n) {
    __shared__ __align__(16) unsigned hcnt[NBINS / 2];   // 98KB: u16 bin pairs
    const int blk = blockIdx.x;
    const int t = threadIdx.x;
    if (blk == 0) {
        // ---- prep: Wt[n][k] = bf16(W[k][n]) ----
        for (int idx = t; idx < 128 * 128; idx += 1024) {
            int nn = idx >> 7, k = idx & 127;
            wt0[idx] = f2bf(W0[k * 128 + nn]);
        }
        for (int idx = t; idx < 64 * 128; idx += 1024) {
            int nn = idx >> 7, k = idx & 127;
            wt1[idx] = f2bf(W1[k * 64 + nn]);
        }
        for (int idx = t; idx < 48 * 64; idx += 1024) {
            int nn = idx >> 6, k = idx & 63;
            wt2[idx] = (nn < 40) ? f2bf(W2[k * 40 + nn]) : (unsigned short)0;
        }
        __threadfence();
        __syncthreads();
        if (t == 0) atomicExch(&gpub[255], 1ULL);        // wt-ready flag
    } else if (blk <= NB) {
        // ---- histogram chunk blk-1 (counting-sort ranks, LDS u16 pairs) ----
        uint4* h4 = (uint4*)hcnt;
        const uint4 z4 = make_uint4(0u, 0u, 0u, 0u);
        for (int i = t; i < NBINS / 8; i += 1024) h4[i] = z4;
        __syncthreads();
        const int s = (blk - 1) << HIST_EPB_LOG;
        const int e = min(E, s + HIST_EPB);
        for (int i = s + t; i < e; i += 1024) {
            const int r = row[i];               // r < n <= NBINS
            const unsigned sh = (unsigned)(r & 1) << 4;
            const unsigned old = atomicAdd(&hcnt[r >> 1], 1u << sh);
            lrank[i] = (unsigned short)((old >> sh) & 0xffffu);
        }
        __syncthreads();
        uint4* dst = (uint4*)(cntmat + (size_t)(blk - 1) * NBINS);
        for (int i = t; i < NBINS / 8; i += 1024) dst[i] = h4[i];
    } else {
        // ---- gemm0: (M⊙x)@W0 -> t_buf bf16, 4x 256-thread groups ----
        const int tid = t & 255;
        const int bid = (blk - 1 - NB) * 4 + (t >> 8);
        const int lane = tid & 63;
        const int wid = tid >> 6;
        const int m15 = lane & 15;
        const int q = lane >> 4;
        const int rA = bid * 64 + wid * 16 + m15;

        bf16x8 a[4];
        {
            float m = 1.0f;
            if (rA < n) m = Mv[rA];
#pragma unroll
            for (int ks = 0; ks < 4; ++ks) {
                float4 lo = make_float4(0.f, 0.f, 0.f, 0.f);
                float4 hi = make_float4(0.f, 0.f, 0.f, 0.f);
                if (rA < n) {
                    lo = *(const float4*)(x + (size_t)rA * 128 + ks * 32 + q * 8);
                    hi = *(const float4*)(x + (size_t)rA * 128 + ks * 32 + q * 8 + 4);
                }
                union { bf16x8 v; unsigned short u[8]; } pk;
                pk.u[0] = f2bf(lo.x * m); pk.u[1] = f2bf(lo.y * m);
                pk.u[2] = f2bf(lo.z * m); pk.u[3] = f2bf(lo.w * m);
                pk.u[4] = f2bf(hi.x * m); pk.u[5] = f2bf(hi.y * m);
                pk.u[6] = f2bf(hi.z * m); pk.u[7] = f2bf(hi.w * m);
                a[ks] = pk.v;
            }
        }
        // gate on wt0 ready (read-spin; loads don't serialize)
        if (tid == 0) {
            while (aload(&gpub[255]) == 0ULL) __builtin_amdgcn_s_sleep(8);
        }
        __syncthreads();
        __threadfence();
#pragma unroll
        for (int nt = 0; nt < 8; ++nt) {
            f32x4 acc = {0.f, 0.f, 0.f, 0.f};
            const int bn = nt * 16 + m15;
#pragma unroll
            for (int ks = 0; ks < 4; ++ks) {
                const uint4 z = *(const uint4*)(wt0 + (size_t)bn * 128 + ks * 32 + q * 8);
                acc = __builtin_amdgcn_mfma_f32_16x16x32_bf16(
                    a[ks], __builtin_bit_cast(bf16x8, z), acc, 0, 0, 0);
            }
            const int gc = nt * 16 + m15;
#pragma unroll
            for (int rr = 0; rr < 4; ++rr) {
                const int gr = bid * 64 + wid * 16 + q * 4 + rr;
                if (gr < n) t_buf[(size_t)gr * 128 + gc] = f2bf(clampf(acc[rr]));
            }
        }
    }
}

// ---------------- fused scan: rp + absolute chunk offsets, one kernel ----------------
// 196 resident blocks, 256 bins each. Publish via fence+atomicExch; poll via
// atomic LOADS on distinct addresses (no RMW serialization).

__launch_bounds__(256)
__global__ void scan_one(const unsigned short* __restrict__ cm,
                         unsigned* __restrict__ cmabs, int* __restrict__ rp,
                         unsigned long long* __restrict__ gpub,
                         int n, int NB, int E) {
    __shared__ int sd[256];
    const int g = blockIdx.x;
    const int t = threadIdx.x;
    const int bin = g * 256 + t;

    // phase 1: this bin's total over all chunks (coalesced u16 loads)
    unsigned tot = 0;
    for (int b = 0; b < NB; ++b) tot += cm[(size_t)b * NBINS + bin];

    // block-inclusive scan over 256 bins
    sd[t] = (int)tot;
    __syncthreads();
    for (int off = 1; off < 256; off <<= 1) {
        int xv = (t >= off) ? sd[t - off] : 0;
        __syncthreads();
        sd[t] += xv;
        __syncthreads();
    }
    const int excl = sd[t] - (int)tot;
    const int gtot = sd[255];
    __syncthreads();                 // protect sd[255] before reuse

    // publish this group's total (flag in high word)
    if (t == 0)
        atomicExch(&gpub[g], (1ULL << 32) | (unsigned long long)(unsigned)gtot);

    // poll earlier groups' totals (read-spin, distinct addresses)
    int my = 0;
    for (int p = t; p < g; p += 256) {
        unsigned long long v;
        do { v = aload(&gpub[p]); } while ((v >> 32) == 0ULL);
        my += (int)(unsigned)v;
    }
    sd[t] = my;
    __syncthreads();
    for (int off = 128; off > 0; off >>= 1) {
        if (t < off) sd[t] += sd[t + off];
        __syncthreads();
    }
    const int base = sd[0];

    const int rpf = base + excl;     // rp_final[bin]
    if (bin < n) rp[bin] = rpf;
    if (g == SCAN_BLOCKS - 1 && t == 255) rp[n] = E;

    // phase 3: absolute per-chunk offsets (coalesced; cm is L2-warm)
    int run = rpf;
    for (int b = 0; b < NB; ++b) {
        cmabs[(size_t)b * NBINS + bin] = (unsigned)run;
        run += (int)cm[(size_t)b * NBINS + bin];
    }
}

// ---------------- scatter (atomic-free, ONE random 16B line per edge) ----------------

__global__ void scatter_kernel(const int* __restrict__ row, const int* __restrict__ col,
                               const float* __restrict__ vA, const float* __restrict__ vZ,
                               const unsigned* __restrict__ cmabs,
                               const unsigned short* __restrict__ lrank,
                               uint4* __restrict__ packed16, int E) {
    int e = blockIdx.x * blockDim.x + threadIdx.x;
    if (e >= E) return;
    const int r = row[e];
    const int pos = (int)(cmabs[(size_t)(e >> HIST_EPB_LOG) * NBINS + r]
                          + (unsigned)lrank[e]);
    uint4 pk;
    pk.x = (unsigned)col[e];
    pk.y = __builtin_bit_cast(unsigned, vZ[e]);
    pk.z = __builtin_bit_cast(unsigned, vA[e]);
    pk.w = 0u;
    packed16[pos] = pk;
}

// ---------------- SpMM F=128: wave/row, 16-deep bursts; out = M⊙relu(...) bf16 ----------------

__launch_bounds__(256)
__global__ void spmm128_kernel(const uint4* __restrict__ packed16,
                               const int* __restrict__ rp, const unsigned short* __restrict__ X,
                               const float* __restrict__ AM, const float* __restrict__ Mv,
                               const float* __restrict__ bias,
                               unsigned short* __restrict__ out, int n) {
    const int lane = threadIdx.x & 63;
    const int r = (int)((blockIdx.x * (unsigned)blockDim.x + threadIdx.x) >> 6);
    if (r >= n) return;
    const int s = __builtin_amdgcn_readfirstlane(rp[r]);
    const int e = __builtin_amdgcn_readfirstlane(rp[r + 1]);

    float acc0 = 0.0f, acc1 = 0.0f;
    for (int base = s; base < e; base += 64) {
        const int nn = min(64, e - base);
        int ci = 0; float vf = 0.0f;
        if (lane < nn) {
            const uint4 pk = packed16[base + lane];
            ci = (int)pk.x;
            vf = __builtin_bit_cast(float, pk.y);
        }
        int j = 0;
        for (; j + 16 <= nn; j += 16) {         // avg deg = 16: one latency round
            unsigned u[16];
#pragma unroll
            for (int q = 0; q < 16; ++q) {
                const int cq = rl_i(ci, j + q);
                u[q] = *(const unsigned*)(X + (size_t)cq * 128 + lane * 2);
            }
#pragma unroll
            for (int q = 0; q < 16; ++q) {
                const float vq = rl_f(vf, j + q);
                acc0 += vq * bf_lo(u[q]);
                acc1 += vq * bf_hi(u[q]);
            }
        }
        for (; j + 8 <= nn; j += 8) {
            unsigned u[8];
#pragma unroll
            for (int q = 0; q < 8; ++q) {
                const int cq = rl_i(ci, j + q);
                u[q] = *(const unsigned*)(X + (size_t)cq * 128 + lane * 2);
            }
#pragma unroll
            for (int q = 0; q < 8; ++q) {
                const float vq = rl_f(vf, j + q);
                acc0 += vq * bf_lo(u[q]);
                acc1 += vq * bf_hi(u[q]);
            }
        }
        for (; j < nn; ++j) {
            const int cq = rl_i(ci, j);
            const float vq = rl_f(vf, j);
            const unsigned u = *(const unsigned*)(X + (size_t)cq * 128 + lane * 2);
            acc0 += vq * bf_lo(u);
            acc1 += vq * bf_hi(u);
        }
    }

    const float am = AM[r];
    const float mr = Mv[r];   // fold M (>=0): M⊙relu(y) = relu(M⊙y)
    const float o0 = fminf(fmaxf((acc0 * am + bias[2 * lane]) * mr, 0.0f), 1e30f);
    const float o1 = fminf(fmaxf((acc1 * am + bias[2 * lane + 1]) * mr, 0.0f), 1e30f);
    ((unsigned*)out)[(size_t)r * 64 + lane] = pack2bf(o0, o1);
}

// ---------------- SpMM F=64 + fused gemm2: out40 = relu(AM⊙agg+b1)@W2 ----------------
// After the xor-16/xor-32 reductions ALL 64 lanes hold the reduced a0..a3
// for ls=lane&15 -> every lane computes the h1 epilogue, then lane j
// accumulates y_j = sum_k h1[k]*W2[k][j] via 16 readlane steps (wt2 is
// [48][64] transposed, rows 40..47 zero).

__launch_bounds__(256)
__global__ void spmm64_gemm2(const uint4* __restrict__ packed16,
                             const int* __restrict__ rp, const unsigned short* __restrict__ X,
                             const float* __restrict__ AM, const float* __restrict__ bias1,
                             const unsigned short* __restrict__ wt2,
                             unsigned short* __restrict__ out40, int n) {
    const int lane = threadIdx.x & 63;
    const int g = lane >> 4;        // edge slot 0..3
    const int ls = lane & 15;       // feat quad: feats 4*ls..4*ls+3
    const int r = (int)((blockIdx.x * (unsigned)blockDim.x + threadIdx.x) >> 6);
    if (r >= n) return;
    const int s = __builtin_amdgcn_readfirstlane(rp[r]);
    const int e = __builtin_amdgcn_readfirstlane(rp[r + 1]);

    float a0 = 0.0f, a1 = 0.0f, a2 = 0.0f, a3 = 0.0f;
    for (int base = s; base < e; base += 64) {
        const int nn = min(64, e - base);
        int ci = 0; float vf = 0.0f;
        if (lane < nn) {
            const uint4 pk = packed16[base + lane];
            ci = (int)pk.x;
            vf = __builtin_bit_cast(float, pk.y);
        }
        for (int j = 0; j < nn; j += 16) {
#pragma unroll
            for (int q = 0; q < 4; ++q) {
                const int jj = j + 4 * q + g;
                const bool ok = jj < nn;
                const int idx = jj & 63;
                const int c = __shfl(ci, idx);
                const float v = __shfl(vf, idx);
                if (ok) {
                    const uint2 u = *(const uint2*)(X + (size_t)c * 64 + ls * 4);
                    a0 += v * bf_lo(u.x);
                    a1 += v * bf_hi(u.x);
                    a2 += v * bf_lo(u.y);
                    a3 += v * bf_hi(u.y);
                }
            }
        }
    }
    a0 += __shfl_xor(a0, 16); a0 += __shfl_xor(a0, 32);
    a1 += __shfl_xor(a1, 16); a1 += __shfl_xor(a1, 32);
    a2 += __shfl_xor(a2, 16); a2 += __shfl_xor(a2, 32);
    a3 += __shfl_xor(a3, 16); a3 += __shfl_xor(a3, 32);

    // h1 epilogue in every lane (for its ls)
    const float am = AM[r];
    const float o0 = fminf(fmaxf(a0 * am + bias1[4 * ls + 0], 0.0f), 1e30f);
    const float o1 = fminf(fmaxf(a1 * am + bias1[4 * ls + 1], 0.0f), 1e30f);
    const float o2 = fminf(fmaxf(a2 * am + bias1[4 * ls + 2], 0.0f), 1e30f);
    const float o3 = fminf(fmaxf(a3 * am + bias1[4 * ls + 3], 0.0f), 1e30f);

    // gemm2: lane j computes y_j (j<48; rows 40..47 of wt2 are zero-padded)
    const int wrow = (lane < 48) ? lane : 0;
    const unsigned short* wp = wt2 + wrow * 64;
    float y = 0.0f;
#pragma unroll
    for (int qq = 0; qq < 16; ++qq) {
        const uint2 w = *(const uint2*)(wp + 4 * qq);
        const float h0v = rl_f(o0, qq);
        const float h1v = rl_f(o1, qq);
        const float h2v = rl_f(o2, qq);
        const float h3v = rl_f(o3, qq);
        y += h0v * bf_lo(w.x) + h1v * bf_hi(w.x)
           + h2v * bf_lo(w.y) + h3v * bf_hi(w.y);
    }
    if (lane < 40) out40[(size_t)r * 40 + lane] = f2bf(clampf(y));
}

// ---------------- SpMM F=40 + log_softmax: 3 edges/wave, 24 in flight ----------------

__launch_bounds__(256)
__global__ void spmm40_kernel(const uint4* __restrict__ packed16,
                              const int* __restrict__ rp, const unsigned short* __restrict__ X,
                              const float* __restrict__ bias,
                              float* __restrict__ out, int n) {
    const int lane = threadIdx.x & 63;
    const int g = lane / 20;
    const int ls = lane - 20 * g;
    const bool active = g < 3;
    const int r = (int)((blockIdx.x * (unsigned)blockDim.x + threadIdx.x) >> 6);
    if (r >= n) return;
    const int s = __builtin_amdgcn_readfirstlane(rp[r]);
    const int e = __builtin_amdgcn_readfirstlane(rp[r + 1]);

    float acc0 = 0.0f, acc1 = 0.0f;
    for (int base = s; base < e; base += 64) {
        const int nn = min(64, e - base);
        int ci = 0; float vf = 0.0f;
        if (lane < nn) {
            const uint4 pk = packed16[base + lane];
            ci = (int)pk.x;
            vf = __builtin_bit_cast(float, pk.z);    // adj (not adjZ) values
        }
        for (int j = 0; j < nn; j += 24) {
#pragma unroll
            for (int q = 0; q < 8; ++q) {
                const int jj = j + 3 * q + g;
                const bool ok = active && jj < nn;
                const int idx = jj & 63;
                const int c = __shfl(ci, idx);
                const float v = __shfl(vf, idx);
                if (ok) {
                    const unsigned u = *(const unsigned*)(X + (size_t)c * 40 + ls * 2);
                    acc0 += v * bf_lo(u);
                    acc1 += v * bf_hi(u);
                }
            }
        }
    }
    {
        const float a1 = __shfl(acc0, (lane + 20) & 63);
        const float a2 = __shfl(acc0, (lane + 40) & 63);
        const float b1 = __shfl(acc1, (lane + 20) & 63);
        const float b2 = __shfl(acc1, (lane + 40) & 63);
        acc0 += a1 + a2;
        acc1 += b1 + b2;
    }

    const bool own = lane < 20;
    const float vv0 = own ? fminf(fmaxf(acc0 + bias[2 * ls], -1e30f), 1e30f) : -INFINITY;
    const float vv1 = own ? fminf(fmaxf(acc1 + bias[2 * ls + 1], -1e30f), 1e30f) : -INFINITY;
    float mx = fmaxf(vv0, vv1);
#pragma unroll
    for (int off = 32; off > 0; off >>= 1) mx = fmaxf(mx, __shfl_xor(mx, off));
    float sum = own ? (expf(vv0 - mx) + expf(vv1 - mx)) : 0.0f;
#pragma unroll
    for (int off = 32; off > 0; off >>= 1) sum += __shfl_xor(sum, off);
    if (own) {
        const float lse = mx + logf(sum);
        *(float2*)(out + (size_t)r * 40 + ls * 2) = make_float2(vv0 - lse, vv1 - lse);
    }
}

// ---------------- launch ----------------

extern "C" void kernel_launch(void* const* d_in, const int* in_sizes, int n_in,
                              void* d_out, int out_size, void* d_ws, size_t ws_size,
                              hipStream_t stream) {
    const float* x    = (const float*)d_in[0];
    const float* M    = (const float*)d_in[1];
    const float* AM   = (const float*)d_in[2];
    const float* adjv = (const float*)d_in[3];
    const float* adjZ = (const float*)d_in[4];
    const float* W0   = (const float*)d_in[5];
    const float* b0   = (const float*)d_in[6];
    const float* W1   = (const float*)d_in[7];
    const float* b1   = (const float*)d_in[8];
    const float* W2   = (const float*)d_in[9];
    const float* b2   = (const float*)d_in[10];
    const int* row    = (const int*)d_in[11];
    const int* col    = (const int*)d_in[12];
    float* out = (float*)d_out;

    const int n = in_sizes[1];   // N  (must be <= NBINS = 50176)
    const int E = in_sizes[3];   // edges (<= NBMAX*32768)

    // workspace layout (~39 MB):
    //   t_buf  : N*128 bf16 (gemm0 out / gemm1 out)
    //   wt0/1/2: bf16 W^T arrays
    //   h region (N*128 bf16 reserve) aliased by lrank/cntmat/cmabs (dead
    //     before spmm128 writes h_buf); later h0 [N][128], then t40 [N][40]
    //   rp     : N+2 int
    //   gpub   : 256 u64 sync slots ([0..195] scan, [255] wt flag)
    //   packed16: E uint4 {col, vZ, vA, 0}
    unsigned short* t_buf = (unsigned short*)d_ws;          // N*128 bf16
    unsigned short* wt0 = t_buf + (size_t)n * 128;          // 128*128
    unsigned short* wt1 = wt0 + 128 * 128;                  // 64*128
    unsigned short* wt2 = wt1 + 64 * 128;                   // 48*64
    unsigned short* h_buf = wt2 + 48 * 64;                  // N*128 bf16 reserve
    unsigned short* lrank  = h_buf;                         // E u16
    unsigned short* cntmat = lrank + (size_t)E;             // [NBMAX][NBINS] u16
    unsigned* cmabs = (unsigned*)(cntmat + (size_t)NBMAX * NBINS);
    int* rp = (int*)(h_buf + (size_t)n * 128);              // N+1 (+pad)
    unsigned long long* gpub = (unsigned long long*)
        (((uintptr_t)(rp + n + 2) + 7) & ~(uintptr_t)7);    // 256 u64
    uint4* packed16 = (uint4*)
        (((uintptr_t)(gpub + 256) + 15) & ~(uintptr_t)15);  // E uint4

    const int NB = (E + HIST_EPB - 1) >> HIST_EPB_LOG;      // hist chunks (<=26)
    const int gemmBlocks = (n + 63) / 64;                   // 4-wave gemm groups
    const int gemmB4 = (gemmBlocks + 3) / 4;                // 1024-thr gemm blocks

    // zero sync slots
    hipMemsetAsync(gpub, 0, 256 * sizeof(unsigned long long), stream);

    // fused W-prep + LDS histogram + gemm0 MFMA (grid 1+NB+gemmB4 <= 256)
    hist_gemm0<<<1 + NB + gemmB4, 1024, 0, stream>>>(row, cntmat, lrank, E, NB,
                                                     x, M, W0, W1, W2,
                                                     wt0, wt1, wt2, t_buf, gpub, n);

    // one-kernel scan: rp + absolute chunk offsets (publish/read-poll)
    scan_one<<<SCAN_BLOCKS, 256, 0, stream>>>(cntmat, cmabs, rp, gpub, n, NB, E);

    // standalone scatter (no sync; one 16B random store per edge)
    scatter_kernel<<<(E + 255) / 256, 256, 0, stream>>>(row, col, adjv, adjZ,
                                                        cmabs, lrank, packed16, E);

    const int spmmBlocks = (n + 3) / 4;   // 4 rows (waves) per block

    // layer 0 aggregate: h_buf = M⊙relu(AM⊙agg+b0) bf16 (overwrites aliases)
    spmm128_kernel<<<spmmBlocks, 256, 0, stream>>>(packed16, rp, t_buf, AM, M, b0, h_buf, n);
    // layer 1: t_buf = h0@W1 bf16 (M already folded into h0)
    gemm_mfma<128, 64, 64><<<gemmBlocks, 256, 0, stream>>>(h_buf, wt1, t_buf, n);
    // layer 1 aggregate + fused gemm2: h_buf(40-stride) = relu(AM⊙agg+b1)@W2
    spmm64_gemm2<<<spmmBlocks, 256, 0, stream>>>(packed16, rp, t_buf, AM, b1, wt2, h_buf, n);
    // layer 2 aggregate + log_softmax
    spmm40_kernel<<<spmmBlocks, 256, 0, stream>>>(packed16, rp, h_buf, b2, out, n);
}

// Round 8
// 287.588 us; speedup vs baseline: 1.6178x; 1.6065x over previous
//
#include <hip/hip_runtime.h>
#include <hip/hip_bf16.h>
#include <math.h>

// PaGCN forward, restructured:
//   h0 = relu(AM ⊙ spmm(adjZ, (M⊙x)@W0) + b0)      (spmm gathers 128 bf16 feats)
//   h1 = relu(AM ⊙ spmm(adjZ, (M⊙h0)@W1) + b1)     (spmm gathers 64 bf16 feats)
//   out = log_softmax(spmm(adj, h1@W2) + b2)        (spmm gathers 40 bf16 feats)
//
// R15: revert the in-kernel wt-ready gate. R14 profile: hist_gemm0 = 212µs
// (VALUBusy 1%, HBM 3%) vs <44µs for the identical ungated R12 version.
// The flag-gate (spin + acquire __threadfence in ~196 blocks) forces
// repeated XCD cache invalidations -- 100x the cost of a kernel boundary.
// TWICE-confirmed lesson (R13 scan_scatter gate = 170µs, R14 wt gate =
// ~170µs): never fuse dependent phases via in-kernel flags here.
// Structure = R12's front half (separate prep_wt; sync-free hist_gemm0;
// scan_one publish/poll on DISTINCT addresses which measured fine; 
// standalone scatter) + the one sync-free R13 win kept:
//  - gemm2 fused into spmm64 epilogue (in-wave 16-step readlane y=h1@W2,
//    f32 h1, proven correct in two passing runs) -> kills a launch + the
//    h1 round-trip. 9 dispatches total.
// Carried: LDS counting-sort hist (no global atomics), one 16B random
// store per edge (uint4 payload), no-LDS MFMA GEMMs (W L1-resident), bf16
// gather targets, M folded into spmm128 epilogue, clamped epilogues,
// 16-deep spmm128 bursts.

typedef __attribute__((ext_vector_type(8))) short bf16x8;
typedef __attribute__((ext_vector_type(4))) float f32x4;

#define HIST_EPB_LOG 15
#define HIST_EPB 32768          // edges per hist block (< 2^16: u16-safe)
#define NBINS 50176             // >= N, = 196*256, even (u16-pair packing)
#define NBMAX 26                // reserved chunk capacity (E <= 26*32768)
#define SCAN_BLOCKS 196         // 256 bins per block = 50176

__device__ __forceinline__ float rl_f(float v, int j) {
    return __builtin_bit_cast(float,
        __builtin_amdgcn_readlane(__builtin_bit_cast(int, v), j));
}
__device__ __forceinline__ int rl_i(int v, int j) {
    return __builtin_amdgcn_readlane(v, j);
}
__device__ __forceinline__ unsigned short f2bf(float f) {
    unsigned u = __builtin_bit_cast(unsigned, f);
    u += 0x7fffu + ((u >> 16) & 1u);   // round-to-nearest-even
    return (unsigned short)(u >> 16);
}
__device__ __forceinline__ unsigned pack2bf(float lo, float hi) {
    return (unsigned)f2bf(lo) | ((unsigned)f2bf(hi) << 16);
}
__device__ __forceinline__ float bf_lo(unsigned u) {
    return __builtin_bit_cast(float, u << 16);
}
__device__ __forceinline__ float bf_hi(unsigned u) {
    return __builtin_bit_cast(float, u & 0xffff0000u);
}
__device__ __forceinline__ float clampf(float v) {   // NaN -> -1e30 (finite)
    return fminf(fmaxf(v, -1e30f), 1e30f);
}
__device__ __forceinline__ unsigned long long aload(const unsigned long long* p) {
    return __hip_atomic_load(p, __ATOMIC_ACQUIRE, __HIP_MEMORY_SCOPE_AGENT);
}

// ---------------- W prep: Wt[n][k] = bf16(W[k][n]), n zero-padded ----------------

__global__ void prep_wt(const float* __restrict__ W0, const float* __restrict__ W1,
                        const float* __restrict__ W2,
                        unsigned short* __restrict__ wt0, unsigned short* __restrict__ wt1,
                        unsigned short* __restrict__ wt2) {
    int idx = blockIdx.x * 256 + threadIdx.x;
    if (idx < 128 * 128) {                       // wt0: [128][128]
        int nn = idx >> 7, k = idx & 127;
        wt0[idx] = f2bf(W0[k * 128 + nn]);
    }
    idx -= 128 * 128;
    if (idx >= 0 && idx < 64 * 128) {            // wt1: [64][128]
        int nn = idx >> 7, k = idx & 127;
        wt1[idx] = f2bf(W1[k * 64 + nn]);
    }
    idx -= 64 * 128;
    if (idx >= 0 && idx < 48 * 64) {             // wt2: [48][64], n>=40 zero
        int nn = idx >> 6, k = idx & 63;
        wt2[idx] = (nn < 40) ? f2bf(W2[k * 40 + nn]) : (unsigned short)0;
    }
}

// ---------------- MFMA GEMM (no LDS, no barriers) ----------------
// 4 waves per 256-thread group, each wave 16 rows x COLS via 16x16x32 bf16
// MFMA. Fragment maps (HW-verified): A[m=lane&15][k=(lane>>4)*8+j],
// B[k=(lane>>4)*8+j][n=lane&15], D[row=(lane>>4)*4+reg][col=lane&15].

template <int K, int COLS, int NTPAD>
__launch_bounds__(256)
__global__ void gemm_mfma(const unsigned short* __restrict__ A,
                          const unsigned short* __restrict__ Wt,
                          unsigned short* __restrict__ outp, int n) {
    constexpr int KS = K / 32;
    const int tid = threadIdx.x;
    const int bid = blockIdx.x;
    const int lane = tid & 63;
    const int wid = tid >> 6;
    const int m15 = lane & 15;
    const int q = lane >> 4;
    const int rA = bid * 64 + wid * 16 + m15;

    bf16x8 a[KS];
#pragma unroll
    for (int ks = 0; ks < KS; ++ks) {
        uint4 z = make_uint4(0u, 0u, 0u, 0u);
        if (rA < n) z = *(const uint4*)(A + (size_t)rA * K + ks * 32 + q * 8);
        a[ks] = __builtin_bit_cast(bf16x8, z);
    }

#pragma unroll
    for (int nt = 0; nt < NTPAD / 16; ++nt) {
        f32x4 acc = {0.f, 0.f, 0.f, 0.f};
        const int bn = nt * 16 + m15;
#pragma unroll
        for (int ks = 0; ks < KS; ++ks) {
            const uint4 z = *(const uint4*)(Wt + (size_t)bn * K + ks * 32 + q * 8);
            acc = __builtin_amdgcn_mfma_f32_16x16x32_bf16(
                a[ks], __builtin_bit_cast(bf16x8, z), acc, 0, 0, 0);
        }
        const int gc = nt * 16 + m15;
#pragma unroll
        for (int rr = 0; rr < 4; ++rr) {
            const int gr = bid * 64 + wid * 16 + q * 4 + rr;
            bool ok = gr < n;
            if constexpr (NTPAD != COLS) ok = ok && (gc < COLS);
            if (ok) outp[(size_t)gr * COLS + gc] = f2bf(clampf(acc[rr]));
        }
    }
}

// ---------------- fused LDS histogram (counting-sort rank) + gemm0 ----------------
// Blocks [0,NB): per-chunk LDS histogram over all bins (packed u16 pairs).
// Blocks [NB, NB+gemmB4): gemm0, 4x 256-thread groups per block.
// ZERO cross-block synchronization (the R13/R14 flag-gate cost 100x a
// kernel boundary).

__launch_bounds__(1024)
__global__ void hist_gemm0(const int* __restrict__ row,
                           unsigned short* __restrict__ cntmat,
                           unsigned short* __restrict__ lrank, int E, int NB,
                           const float* __restrict__ x, const float* __restrict__ Mv,
                           const unsigned short* __restrict__ Wt0,
                           unsigned short* __restrict__ t_buf, int n) {
    __shared__ __align__(16) unsigned hcnt[NBINS / 2];   // 98KB: u16 bin pairs
    const int blk = blockIdx.x;
    const int t = threadIdx.x;
    if (blk < NB) {
        uint4* h4 = (uint4*)hcnt;
        const uint4 z4 = make_uint4(0u, 0u, 0u, 0u);
        for (int i = t; i < NBINS / 8; i += 1024) h4[i] = z4;
        __syncthreads();
        const int s = blk << HIST_EPB_LOG;
        const int e = min(E, s + HIST_EPB);
        for (int i = s + t; i < e; i += 1024) {
            const int r = row[i];               // r < n <= NBINS
            const unsigned sh = (unsigned)(r & 1) << 4;
            const unsigned old = atomicAdd(&hcnt[r >> 1], 1u << sh);
            lrank[i] = (unsigned short)((old >> sh) & 0xffffu);
        }
        __syncthreads();
        uint4* dst = (uint4*)(cntmat + (size_t)blk * NBINS);
        for (int i = t; i < NBINS / 8; i += 1024) dst[i] = h4[i];
    } else {
        // ---- gemm0: (M⊙x)@W0 -> t_buf bf16, 4x 256-thread groups ----
        const int tid = t & 255;
        const int bid = (blk - NB) * 4 + (t >> 8);
        const int lane = tid & 63;
        const int wid = tid >> 6;
        const int m15 = lane & 15;
        const int q = lane >> 4;
        const int rA = bid * 64 + wid * 16 + m15;

        bf16x8 a[4];
        {
            float m = 1.0f;
            if (rA < n) m = Mv[rA];
#pragma unroll
            for (int ks = 0; ks < 4; ++ks) {
                float4 lo = make_float4(0.f, 0.f, 0.f, 0.f);
                float4 hi = make_float4(0.f, 0.f, 0.f, 0.f);
                if (rA < n) {
                    lo = *(const float4*)(x + (size_t)rA * 128 + ks * 32 + q * 8);
                    hi = *(const float4*)(x + (size_t)rA * 128 + ks * 32 + q * 8 + 4);
                }
                union { bf16x8 v; unsigned short u[8]; } pk;
                pk.u[0] = f2bf(lo.x * m); pk.u[1] = f2bf(lo.y * m);
                pk.u[2] = f2bf(lo.z * m); pk.u[3] = f2bf(lo.w * m);
                pk.u[4] = f2bf(hi.x * m); pk.u[5] = f2bf(hi.y * m);
                pk.u[6] = f2bf(hi.z * m); pk.u[7] = f2bf(hi.w * m);
                a[ks] = pk.v;
            }
        }
#pragma unroll
        for (int nt = 0; nt < 8; ++nt) {
            f32x4 acc = {0.f, 0.f, 0.f, 0.f};
            const int bn = nt * 16 + m15;
#pragma unroll
            for (int ks = 0; ks < 4; ++ks) {
                const uint4 z = *(const uint4*)(Wt0 + (size_t)bn * 128 + ks * 32 + q * 8);
                acc = __builtin_amdgcn_mfma_f32_16x16x32_bf16(
                    a[ks], __builtin_bit_cast(bf16x8, z), acc, 0, 0, 0);
            }
            const int gc = nt * 16 + m15;
#pragma unroll
            for (int rr = 0; rr < 4; ++rr) {
                const int gr = bid * 64 + wid * 16 + q * 4 + rr;
                if (gr < n) t_buf[(size_t)gr * 128 + gc] = f2bf(clampf(acc[rr]));
            }
        }
    }
}

// ---------------- fused scan: rp + absolute chunk offsets, one kernel ----------------
// 196 resident blocks, 256 bins each. Publish via fence+atomicExch; poll via
// atomic LOADS on DISTINCT addresses (this pattern measured fine in R11/R12;
// the pathological case is many blocks polling ONE line / fencing).

__launch_bounds__(256)
__global__ void scan_one(const unsigned short* __restrict__ cm,
                         unsigned* __restrict__ cmabs, int* __restrict__ rp,
                         unsigned long long* __restrict__ gpub,
                         int n, int NB, int E) {
    __shared__ int sd[256];
    const int g = blockIdx.x;
    const int t = threadIdx.x;
    const int bin = g * 256 + t;

    // phase 1: this bin's total over all chunks (coalesced u16 loads)
    unsigned tot = 0;
    for (int b = 0; b < NB; ++b) tot += cm[(size_t)b * NBINS + bin];

    // block-inclusive scan over 256 bins
    sd[t] = (int)tot;
    __syncthreads();
    for (int off = 1; off < 256; off <<= 1) {
        int xv = (t >= off) ? sd[t - off] : 0;
        __syncthreads();
        sd[t] += xv;
        __syncthreads();
    }
    const int excl = sd[t] - (int)tot;
    const int gtot = sd[255];
    __syncthreads();                 // protect sd[255] before reuse

    // publish this group's total (flag in high word)
    if (t == 0)
        atomicExch(&gpub[g], (1ULL << 32) | (unsigned long long)(unsigned)gtot);

    // poll earlier groups' totals (read-spin, distinct addresses)
    int my = 0;
    for (int p = t; p < g; p += 256) {
        unsigned long long v;
        do { v = aload(&gpub[p]); } while ((v >> 32) == 0ULL);
        my += (int)(unsigned)v;
    }
    sd[t] = my;
    __syncthreads();
    for (int off = 128; off > 0; off >>= 1) {
        if (t < off) sd[t] += sd[t + off];
        __syncthreads();
    }
    const int base = sd[0];

    const int rpf = base + excl;     // rp_final[bin]
    if (bin < n) rp[bin] = rpf;
    if (g == SCAN_BLOCKS - 1 && t == 255) rp[n] = E;

    // phase 3: absolute per-chunk offsets (coalesced; cm is L2-warm)
    int run = rpf;
    for (int b = 0; b < NB; ++b) {
        cmabs[(size_t)b * NBINS + bin] = (unsigned)run;
        run += (int)cm[(size_t)b * NBINS + bin];
    }
}

// ---------------- scatter (atomic-free, ONE random 16B line per edge) ----------------

__global__ void scatter_kernel(const int* __restrict__ row, const int* __restrict__ col,
                               const float* __restrict__ vA, const float* __restrict__ vZ,
                               const unsigned* __restrict__ cmabs,
                               const unsigned short* __restrict__ lrank,
                               uint4* __restrict__ packed16, int E) {
    int e = blockIdx.x * blockDim.x + threadIdx.x;
    if (e >= E) return;
    const int r = row[e];
    const int pos = (int)(cmabs[(size_t)(e >> HIST_EPB_LOG) * NBINS + r]
                          + (unsigned)lrank[e]);
    uint4 pk;
    pk.x = (unsigned)col[e];
    pk.y = __builtin_bit_cast(unsigned, vZ[e]);
    pk.z = __builtin_bit_cast(unsigned, vA[e]);
    pk.w = 0u;
    packed16[pos] = pk;
}

// ---------------- SpMM F=128: wave/row, 16-deep bursts; out = M⊙relu(...) bf16 ----------------

__launch_bounds__(256)
__global__ void spmm128_kernel(const uint4* __restrict__ packed16,
                               const int* __restrict__ rp, const unsigned short* __restrict__ X,
                               const float* __restrict__ AM, const float* __restrict__ Mv,
                               const float* __restrict__ bias,
                               unsigned short* __restrict__ out, int n) {
    const int lane = threadIdx.x & 63;
    const int r = (int)((blockIdx.x * (unsigned)blockDim.x + threadIdx.x) >> 6);
    if (r >= n) return;
    const int s = __builtin_amdgcn_readfirstlane(rp[r]);
    const int e = __builtin_amdgcn_readfirstlane(rp[r + 1]);

    float acc0 = 0.0f, acc1 = 0.0f;
    for (int base = s; base < e; base += 64) {
        const int nn = min(64, e - base);
        int ci = 0; float vf = 0.0f;
        if (lane < nn) {
            const uint4 pk = packed16[base + lane];
            ci = (int)pk.x;
            vf = __builtin_bit_cast(float, pk.y);
        }
        int j = 0;
        for (; j + 16 <= nn; j += 16) {         // avg deg = 16: one latency round
            unsigned u[16];
#pragma unroll
            for (int q = 0; q < 16; ++q) {
                const int cq = rl_i(ci, j + q);
                u[q] = *(const unsigned*)(X + (size_t)cq * 128 + lane * 2);
            }
#pragma unroll
            for (int q = 0; q < 16; ++q) {
                const float vq = rl_f(vf, j + q);
                acc0 += vq * bf_lo(u[q]);
                acc1 += vq * bf_hi(u[q]);
            }
        }
        for (; j + 8 <= nn; j += 8) {
            unsigned u[8];
#pragma unroll
            for (int q = 0; q < 8; ++q) {
                const int cq = rl_i(ci, j + q);
                u[q] = *(const unsigned*)(X + (size_t)cq * 128 + lane * 2);
            }
#pragma unroll
            for (int q = 0; q < 8; ++q) {
                const float vq = rl_f(vf, j + q);
                acc0 += vq * bf_lo(u[q]);
                acc1 += vq * bf_hi(u[q]);
            }
        }
        for (; j < nn; ++j) {
            const int cq = rl_i(ci, j);
            const float vq = rl_f(vf, j);
            const unsigned u = *(const unsigned*)(X + (size_t)cq * 128 + lane * 2);
            acc0 += vq * bf_lo(u);
            acc1 += vq * bf_hi(u);
        }
    }

    const float am = AM[r];
    const float mr = Mv[r];   // fold M (>=0): M⊙relu(y) = relu(M⊙y)
    const float o0 = fminf(fmaxf((acc0 * am + bias[2 * lane]) * mr, 0.0f), 1e30f);
    const float o1 = fminf(fmaxf((acc1 * am + bias[2 * lane + 1]) * mr, 0.0f), 1e30f);
    ((unsigned*)out)[(size_t)r * 64 + lane] = pack2bf(o0, o1);
}

// ---------------- SpMM F=64 + fused gemm2: out40 = relu(AM⊙agg+b1)@W2 ----------------
// After the xor-16/xor-32 reductions ALL 64 lanes hold the reduced a0..a3
// for ls=lane&15 -> every lane computes the h1 epilogue, then lane j
// accumulates y_j = sum_k h1[k]*W2[k][j] via 16 readlane steps (wt2 is
// [48][64] transposed, rows 40..47 zero). Proven correct in R13/R14 runs.

__launch_bounds__(256)
__global__ void spmm64_gemm2(const uint4* __restrict__ packed16,
                             const int* __restrict__ rp, const unsigned short* __restrict__ X,
                             const float* __restrict__ AM, const float* __restrict__ bias1,
                             const unsigned short* __restrict__ wt2,
                             unsigned short* __restrict__ out40, int n) {
    const int lane = threadIdx.x & 63;
    const int g = lane >> 4;        // edge slot 0..3
    const int ls = lane & 15;       // feat quad: feats 4*ls..4*ls+3
    const int r = (int)((blockIdx.x * (unsigned)blockDim.x + threadIdx.x) >> 6);
    if (r >= n) return;
    const int s = __builtin_amdgcn_readfirstlane(rp[r]);
    const int e = __builtin_amdgcn_readfirstlane(rp[r + 1]);

    float a0 = 0.0f, a1 = 0.0f, a2 = 0.0f, a3 = 0.0f;
    for (int base = s; base < e; base += 64) {
        const int nn = min(64, e - base);
        int ci = 0; float vf = 0.0f;
        if (lane < nn) {
            const uint4 pk = packed16[base + lane];
            ci = (int)pk.x;
            vf = __builtin_bit_cast(float, pk.y);
        }
        for (int j = 0; j < nn; j += 16) {
#pragma unroll
            for (int q = 0; q < 4; ++q) {
                const int jj = j + 4 * q + g;
                const bool ok = jj < nn;
                const int idx = jj & 63;
                const int c = __shfl(ci, idx);
                const float v = __shfl(vf, idx);
                if (ok) {
                    const uint2 u = *(const uint2*)(X + (size_t)c * 64 + ls * 4);
                    a0 += v * bf_lo(u.x);
                    a1 += v * bf_hi(u.x);
                    a2 += v * bf_lo(u.y);
                    a3 += v * bf_hi(u.y);
                }
            }
        }
    }
    a0 += __shfl_xor(a0, 16); a0 += __shfl_xor(a0, 32);
    a1 += __shfl_xor(a1, 16); a1 += __shfl_xor(a1, 32);
    a2 += __shfl_xor(a2, 16); a2 += __shfl_xor(a2, 32);
    a3 += __shfl_xor(a3, 16); a3 += __shfl_xor(a3, 32);

    // h1 epilogue in every lane (for its ls)
    const float am = AM[r];
    const float o0 = fminf(fmaxf(a0 * am + bias1[4 * ls + 0], 0.0f), 1e30f);
    const float o1 = fminf(fmaxf(a1 * am + bias1[4 * ls + 1], 0.0f), 1e30f);
    const float o2 = fminf(fmaxf(a2 * am + bias1[4 * ls + 2], 0.0f), 1e30f);
    const float o3 = fminf(fmaxf(a3 * am + bias1[4 * ls + 3], 0.0f), 1e30f);

    // gemm2: lane j computes y_j (j<48; rows 40..47 of wt2 are zero-padded)
    const int wrow = (lane < 48) ? lane : 0;
    const unsigned short* wp = wt2 + wrow * 64;
    float y = 0.0f;
#pragma unroll
    for (int qq = 0; qq < 16; ++qq) {
        const uint2 w = *(const uint2*)(wp + 4 * qq);
        const float h0v = rl_f(o0, qq);
        const float h1v = rl_f(o1, qq);
        const float h2v = rl_f(o2, qq);
        const float h3v = rl_f(o3, qq);
        y += h0v * bf_lo(w.x) + h1v * bf_hi(w.x)
           + h2v * bf_lo(w.y) + h3v * bf_hi(w.y);
    }
    if (lane < 40) out40[(size_t)r * 40 + lane] = f2bf(clampf(y));
}

// ---------------- SpMM F=40 + log_softmax: 3 edges/wave, 24 in flight ----------------

__launch_bounds__(256)
__global__ void spmm40_kernel(const uint4* __restrict__ packed16,
                              const int* __restrict__ rp, const unsigned short* __restrict__ X,
                              const float* __restrict__ bias,
                              float* __restrict__ out, int n) {
    const int lane = threadIdx.x & 63;
    const int g = lane / 20;
    const int ls = lane - 20 * g;
    const bool active = g < 3;
    const int r = (int)((blockIdx.x * (unsigned)blockDim.x + threadIdx.x) >> 6);
    if (r >= n) return;
    const int s = __builtin_amdgcn_readfirstlane(rp[r]);
    const int e = __builtin_amdgcn_readfirstlane(rp[r + 1]);

    float acc0 = 0.0f, acc1 = 0.0f;
    for (int base = s; base < e; base += 64) {
        const int nn = min(64, e - base);
        int ci = 0; float vf = 0.0f;
        if (lane < nn) {
            const uint4 pk = packed16[base + lane];
            ci = (int)pk.x;
            vf = __builtin_bit_cast(float, pk.z);    // adj (not adjZ) values
        }
        for (int j = 0; j < nn; j += 24) {
#pragma unroll
            for (int q = 0; q < 8; ++q) {
                const int jj = j + 3 * q + g;
                const bool ok = active && jj < nn;
                const int idx = jj & 63;
                const int c = __shfl(ci, idx);
                const float v = __shfl(vf, idx);
                if (ok) {
                    const unsigned u = *(const unsigned*)(X + (size_t)c * 40 + ls * 2);
                    acc0 += v * bf_lo(u);
                    acc1 += v * bf_hi(u);
                }
            }
        }
    }
    {
        const float a1 = __shfl(acc0, (lane + 20) & 63);
        const float a2 = __shfl(acc0, (lane + 40) & 63);
        const float b1 = __shfl(acc1, (lane + 20) & 63);
        const float b2 = __shfl(acc1, (lane + 40) & 63);
        acc0 += a1 + a2;
        acc1 += b1 + b2;
    }

    const bool own = lane < 20;
    const float vv0 = own ? fminf(fmaxf(acc0 + bias[2 * ls], -1e30f), 1e30f) : -INFINITY;
    const float vv1 = own ? fminf(fmaxf(acc1 + bias[2 * ls + 1], -1e30f), 1e30f) : -INFINITY;
    float mx = fmaxf(vv0, vv1);
#pragma unroll
    for (int off = 32; off > 0; off >>= 1) mx = fmaxf(mx, __shfl_xor(mx, off));
    float sum = own ? (expf(vv0 - mx) + expf(vv1 - mx)) : 0.0f;
#pragma unroll
    for (int off = 32; off > 0; off >>= 1) sum += __shfl_xor(sum, off);
    if (own) {
        const float lse = mx + logf(sum);
        *(float2*)(out + (size_t)r * 40 + ls * 2) = make_float2(vv0 - lse, vv1 - lse);
    }
}

// ---------------- launch ----------------

extern "C" void kernel_launch(void* const* d_in, const int* in_sizes, int n_in,
                              void* d_out, int out_size, void* d_ws, size_t ws_size,
                              hipStream_t stream) {
    const float* x    = (const float*)d_in[0];
    const float* M    = (const float*)d_in[1];
    const float* AM   = (const float*)d_in[2];
    const float* adjv = (const float*)d_in[3];
    const float* adjZ = (const float*)d_in[4];
    const float* W0   = (const float*)d_in[5];
    const float* b0   = (const float*)d_in[6];
    const float* W1   = (const float*)d_in[7];
    const float* b1   = (const float*)d_in[8];
    const float* W2   = (const float*)d_in[9];
    const float* b2   = (const float*)d_in[10];
    const int* row    = (const int*)d_in[11];
    const int* col    = (const int*)d_in[12];
    float* out = (float*)d_out;

    const int n = in_sizes[1];   // N  (must be <= NBINS = 50176)
    const int E = in_sizes[3];   // edges (<= NBMAX*32768)

    // workspace layout (~39 MB):
    //   t_buf  : N*128 bf16 (gemm0 out / gemm1 out)
    //   wt0/1/2: bf16 W^T arrays
    //   h region (N*128 bf16 reserve) aliased by lrank/cntmat/cmabs (dead
    //     before spmm128 writes h_buf); later h0 [N][128], then out40 [N][40]
    //   rp     : N+2 int
    //   gpub   : 256 u64 sync slots ([0..195] scan publish)
    //   packed16: E uint4 {col, vZ, vA, 0}
    unsigned short* t_buf = (unsigned short*)d_ws;          // N*128 bf16
    unsigned short* wt0 = t_buf + (size_t)n * 128;          // 128*128
    unsigned short* wt1 = wt0 + 128 * 128;                  // 64*128
    unsigned short* wt2 = wt1 + 64 * 128;                   // 48*64
    unsigned short* h_buf = wt2 + 48 * 64;                  // N*128 bf16 reserve
    unsigned short* lrank  = h_buf;                         // E u16
    unsigned short* cntmat = lrank + (size_t)E;             // [NBMAX][NBINS] u16
    unsigned* cmabs = (unsigned*)(cntmat + (size_t)NBMAX * NBINS);
    int* rp = (int*)(h_buf + (size_t)n * 128);              // N+1 (+pad)
    unsigned long long* gpub = (unsigned long long*)
        (((uintptr_t)(rp + n + 2) + 7) & ~(uintptr_t)7);    // 256 u64
    uint4* packed16 = (uint4*)
        (((uintptr_t)(gpub + 256) + 15) & ~(uintptr_t)15);  // E uint4

    const int NB = (E + HIST_EPB - 1) >> HIST_EPB_LOG;      // hist chunks (<=26)
    const int gemmBlocks = (n + 63) / 64;                   // 4-wave gemm groups
    const int gemmB4 = (gemmBlocks + 3) / 4;                // 1024-thr gemm blocks

    // zero sync slots
    hipMemsetAsync(gpub, 0, 256 * sizeof(unsigned long long), stream);
    prep_wt<<<(128 * 128 + 64 * 128 + 48 * 64 + 255) / 256, 256, 0, stream>>>(
        W0, W1, W2, wt0, wt1, wt2);

    // fused LDS histogram (rank+count, no sync) + gemm0 MFMA
    hist_gemm0<<<NB + gemmB4, 1024, 0, stream>>>(row, cntmat, lrank, E, NB,
                                                 x, M, wt0, t_buf, n);

    // one-kernel scan: rp + absolute chunk offsets (publish/read-poll, distinct addrs)
    scan_one<<<SCAN_BLOCKS, 256, 0, stream>>>(cntmat, cmabs, rp, gpub, n, NB, E);

    // standalone scatter (no sync; one 16B random store per edge)
    scatter_kernel<<<(E + 255) / 256, 256, 0, stream>>>(row, col, adjv, adjZ,
                                                        cmabs, lrank, packed16, E);

    const int spmmBlocks = (n + 3) / 4;   // 4 rows (waves) per block

    // layer 0 aggregate: h_buf = M⊙relu(AM⊙agg+b0) bf16 (overwrites aliases)
    spmm128_kernel<<<spmmBlocks, 256, 0, stream>>>(packed16, rp, t_buf, AM, M, b0, h_buf, n);
    // layer 1: t_buf = h0@W1 bf16 (M already folded into h0)
    gemm_mfma<128, 64, 64><<<gemmBlocks, 256, 0, stream>>>(h_buf, wt1, t_buf, n);
    // layer 1 aggregate + fused gemm2: h_buf(40-stride) = relu(AM⊙agg+b1)@W2
    spmm64_gemm2<<<spmmBlocks, 256, 0, stream>>>(packed16, rp, t_buf, AM, b1, wt2, h_buf, n);
    // layer 2 aggregate + log_softmax
    spmm40_kernel<<<spmmBlocks, 256, 0, stream>>>(packed16, rp, h_buf, b2, out, n);
}

// Round 10
// 263.965 us; speedup vs baseline: 1.7626x; 1.0895x over previous
//
#include <hip/hip_runtime.h>
#include <hip/hip_bf16.h>
#include <math.h>

// PaGCN forward, restructured:
//   h0 = relu(AM ⊙ spmm(adjZ, (M⊙x)@W0) + b0)      (spmm gathers 128 bf16 feats)
//   h1 = relu(AM ⊙ spmm(adjZ, (M⊙h0)@W1) + b1)     (spmm gathers 64 bf16 feats)
//   out = log_softmax(spmm(adj, h1@W2) + b2)        (spmm gathers 40 bf16 feats)
//
// R16 (resubmit; R9 bench was an infra container failure, no measurement):
// MFMA-fused dense layers. R15's readlane gemm2 epilogue was VALU-bound
// (spmm64_gemm2: 52µs, VALUBusy 44% -- 16-step serial readlane chain).
// Replace with LDS-staged MFMA for BOTH dense layers:
//  - spmm128_g1: block = 16 rows (4 waves x 4 rows sequential gather).
//    Epilogue writes M⊙h0 to LDS [16][136] bf16 (272B stride: 16B-aligned,
//    2-way banks), one barrier, then wave w computes cols w*16.. of
//    (M⊙h0)@W1 with 4 MFMAs (A-frags via ds_read_b128; fragment map
//    A[m=lane&15][k=(lane>>4)*8+j] == LDS h16[m15][ks*32+q*8..+7]).
//    Kills the gemm1 launch AND the h0 round-trip (25.6MB HBM).
//  - spmm64_g2: same, LDS [16][72], K=64 (2 MFMAs), 3 col-tiles (waves 0-2),
//    writes h1@W2 (40 cols, wt2 zero-padded to 48) directly.
// Sync-free front half carried from R15 (twice-confirmed: in-kernel flag
// gates cost 100x a kernel boundary -- R13 170µs, R14 212µs).
// Carried: LDS counting-sort hist (no global atomics), publish/read-poll
// scan on distinct addresses, one 16B random store per edge, no-LDS MFMA
// gemm0 (W L1-resident), bf16 gather targets, M folded into spmm128
// epilogue, clamped epilogues, 16-deep spmm128 bursts. 8 dispatches.

typedef __attribute__((ext_vector_type(8))) short bf16x8;
typedef __attribute__((ext_vector_type(4))) float f32x4;

#define HIST_EPB_LOG 15
#define HIST_EPB 32768          // edges per hist block (< 2^16: u16-safe)
#define NBINS 50176             // >= N, = 196*256, even (u16-pair packing)
#define NBMAX 26                // reserved chunk capacity (E <= 26*32768)
#define SCAN_BLOCKS 196         // 256 bins per block = 50176

__device__ __forceinline__ float rl_f(float v, int j) {
    return __builtin_bit_cast(float,
        __builtin_amdgcn_readlane(__builtin_bit_cast(int, v), j));
}
__device__ __forceinline__ int rl_i(int v, int j) {
    return __builtin_amdgcn_readlane(v, j);
}
__device__ __forceinline__ unsigned short f2bf(float f) {
    unsigned u = __builtin_bit_cast(unsigned, f);
    u += 0x7fffu + ((u >> 16) & 1u);   // round-to-nearest-even
    return (unsigned short)(u >> 16);
}
__device__ __forceinline__ unsigned pack2bf(float lo, float hi) {
    return (unsigned)f2bf(lo) | ((unsigned)f2bf(hi) << 16);
}
__device__ __forceinline__ float bf_lo(unsigned u) {
    return __builtin_bit_cast(float, u << 16);
}
__device__ __forceinline__ float bf_hi(unsigned u) {
    return __builtin_bit_cast(float, u & 0xffff0000u);
}
__device__ __forceinline__ float clampf(float v) {   // NaN -> -1e30 (finite)
    return fminf(fmaxf(v, -1e30f), 1e30f);
}
__device__ __forceinline__ unsigned long long aload(const unsigned long long* p) {
    return __hip_atomic_load(p, __ATOMIC_ACQUIRE, __HIP_MEMORY_SCOPE_AGENT);
}

// ---------------- W prep: Wt[n][k] = bf16(W[k][n]), n zero-padded ----------------

__global__ void prep_wt(const float* __restrict__ W0, const float* __restrict__ W1,
                        const float* __restrict__ W2,
                        unsigned short* __restrict__ wt0, unsigned short* __restrict__ wt1,
                        unsigned short* __restrict__ wt2) {
    int idx = blockIdx.x * 256 + threadIdx.x;
    if (idx < 128 * 128) {                       // wt0: [128][128]
        int nn = idx >> 7, k = idx & 127;
        wt0[idx] = f2bf(W0[k * 128 + nn]);
    }
    idx -= 128 * 128;
    if (idx >= 0 && idx < 64 * 128) {            // wt1: [64][128]
        int nn = idx >> 7, k = idx & 127;
        wt1[idx] = f2bf(W1[k * 64 + nn]);
    }
    idx -= 64 * 128;
    if (idx >= 0 && idx < 48 * 64) {             // wt2: [48][64], n>=40 zero
        int nn = idx >> 6, k = idx & 63;
        wt2[idx] = (nn < 40) ? f2bf(W2[k * 40 + nn]) : (unsigned short)0;
    }
}

// ---------------- fused LDS histogram (counting-sort rank) + gemm0 ----------------
// Blocks [0,NB): per-chunk LDS histogram over all bins (packed u16 pairs).
// Blocks [NB, NB+gemmB4): gemm0, 4x 256-thread groups per block.
// ZERO cross-block synchronization.

__launch_bounds__(1024)
__global__ void hist_gemm0(const int* __restrict__ row,
                           unsigned short* __restrict__ cntmat,
                           unsigned short* __restrict__ lrank, int E, int NB,
                           const float* __restrict__ x, const float* __restrict__ Mv,
                           const unsigned short* __restrict__ Wt0,
                           unsigned short* __restrict__ t_buf, int n) {
    __shared__ __align__(16) unsigned hcnt[NBINS / 2];   // 98KB: u16 bin pairs
    const int blk = blockIdx.x;
    const int t = threadIdx.x;
    if (blk < NB) {
        uint4* h4 = (uint4*)hcnt;
        const uint4 z4 = make_uint4(0u, 0u, 0u, 0u);
        for (int i = t; i < NBINS / 8; i += 1024) h4[i] = z4;
        __syncthreads();
        const int s = blk << HIST_EPB_LOG;
        const int e = min(E, s + HIST_EPB);
        for (int i = s + t; i < e; i += 1024) {
            const int r = row[i];               // r < n <= NBINS
            const unsigned sh = (unsigned)(r & 1) << 4;
            const unsigned old = atomicAdd(&hcnt[r >> 1], 1u << sh);
            lrank[i] = (unsigned short)((old >> sh) & 0xffffu);
        }
        __syncthreads();
        uint4* dst = (uint4*)(cntmat + (size_t)blk * NBINS);
        for (int i = t; i < NBINS / 8; i += 1024) dst[i] = h4[i];
    } else {
        // ---- gemm0: (M⊙x)@W0 -> t_buf bf16, 4x 256-thread groups ----
        const int tid = t & 255;
        const int bid = (blk - NB) * 4 + (t >> 8);
        const int lane = tid & 63;
        const int wid = tid >> 6;
        const int m15 = lane & 15;
        const int q = lane >> 4;
        const int rA = bid * 64 + wid * 16 + m15;

        bf16x8 a[4];
        {
            float m = 1.0f;
            if (rA < n) m = Mv[rA];
#pragma unroll
            for (int ks = 0; ks < 4; ++ks) {
                float4 lo = make_float4(0.f, 0.f, 0.f, 0.f);
                float4 hi = make_float4(0.f, 0.f, 0.f, 0.f);
                if (rA < n) {
                    lo = *(const float4*)(x + (size_t)rA * 128 + ks * 32 + q * 8);
                    hi = *(const float4*)(x + (size_t)rA * 128 + ks * 32 + q * 8 + 4);
                }
                union { bf16x8 v; unsigned short u[8]; } pk;
                pk.u[0] = f2bf(lo.x * m); pk.u[1] = f2bf(lo.y * m);
                pk.u[2] = f2bf(lo.z * m); pk.u[3] = f2bf(lo.w * m);
                pk.u[4] = f2bf(hi.x * m); pk.u[5] = f2bf(hi.y * m);
                pk.u[6] = f2bf(hi.z * m); pk.u[7] = f2bf(hi.w * m);
                a[ks] = pk.v;
            }
        }
#pragma unroll
        for (int nt = 0; nt < 8; ++nt) {
            f32x4 acc = {0.f, 0.f, 0.f, 0.f};
            const int bn = nt * 16 + m15;
#pragma unroll
            for (int ks = 0; ks < 4; ++ks) {
                const uint4 z = *(const uint4*)(Wt0 + (size_t)bn * 128 + ks * 32 + q * 8);
                acc = __builtin_amdgcn_mfma_f32_16x16x32_bf16(
                    a[ks], __builtin_bit_cast(bf16x8, z), acc, 0, 0, 0);
            }
            const int gc = nt * 16 + m15;
#pragma unroll
            for (int rr = 0; rr < 4; ++rr) {
                const int gr = bid * 64 + wid * 16 + q * 4 + rr;
                if (gr < n) t_buf[(size_t)gr * 128 + gc] = f2bf(clampf(acc[rr]));
            }
        }
    }
}

// ---------------- fused scan: rp + absolute chunk offsets, one kernel ----------------
// 196 resident blocks, 256 bins each. Publish via fence+atomicExch; poll via
// atomic LOADS on DISTINCT addresses (measured fine R11/R12/R15).

__launch_bounds__(256)
__global__ void scan_one(const unsigned short* __restrict__ cm,
                         unsigned* __restrict__ cmabs, int* __restrict__ rp,
                         unsigned long long* __restrict__ gpub,
                         int n, int NB, int E) {
    __shared__ int sd[256];
    const int g = blockIdx.x;
    const int t = threadIdx.x;
    const int bin = g * 256 + t;

    unsigned tot = 0;
    for (int b = 0; b < NB; ++b) tot += cm[(size_t)b * NBINS + bin];

    sd[t] = (int)tot;
    __syncthreads();
    for (int off = 1; off < 256; off <<= 1) {
        int xv = (t >= off) ? sd[t - off] : 0;
        __syncthreads();
        sd[t] += xv;
        __syncthreads();
    }
    const int excl = sd[t] - (int)tot;
    const int gtot = sd[255];
    __syncthreads();

    if (t == 0)
        atomicExch(&gpub[g], (1ULL << 32) | (unsigned long long)(unsigned)gtot);

    int my = 0;
    for (int p = t; p < g; p += 256) {
        unsigned long long v;
        do { v = aload(&gpub[p]); } while ((v >> 32) == 0ULL);
        my += (int)(unsigned)v;
    }
    sd[t] = my;
    __syncthreads();
    for (int off = 128; off > 0; off >>= 1) {
        if (t < off) sd[t] += sd[t + off];
        __syncthreads();
    }
    const int base = sd[0];

    const int rpf = base + excl;
    if (bin < n) rp[bin] = rpf;
    if (g == SCAN_BLOCKS - 1 && t == 255) rp[n] = E;

    int run = rpf;
    for (int b = 0; b < NB; ++b) {
        cmabs[(size_t)b * NBINS + bin] = (unsigned)run;
        run += (int)cm[(size_t)b * NBINS + bin];
    }
}

// ---------------- scatter (atomic-free, ONE random 16B line per edge) ----------------

__global__ void scatter_kernel(const int* __restrict__ row, const int* __restrict__ col,
                               const float* __restrict__ vA, const float* __restrict__ vZ,
                               const unsigned* __restrict__ cmabs,
                               const unsigned short* __restrict__ lrank,
                               uint4* __restrict__ packed16, int E) {
    int e = blockIdx.x * blockDim.x + threadIdx.x;
    if (e >= E) return;
    const int r = row[e];
    const int pos = (int)(cmabs[(size_t)(e >> HIST_EPB_LOG) * NBINS + r]
                          + (unsigned)lrank[e]);
    uint4 pk;
    pk.x = (unsigned)col[e];
    pk.y = __builtin_bit_cast(unsigned, vZ[e]);
    pk.z = __builtin_bit_cast(unsigned, vA[e]);
    pk.w = 0u;
    packed16[pos] = pk;
}

// ---------------- SpMM F=128 + MFMA gemm1: g1 = (M⊙h0)@W1 ----------------
// Block = 16 rows: 4 waves x 4 rows (sequential gather per wave). Gather
// epilogue (M⊙relu(AM⊙agg+b0)) -> LDS h16[16][136] bf16 (272B stride:
// 16B-aligned, 2-way banks). Barrier. Wave w computes output cols
// w*16..w*16+15 via 4 MFMAs; writes g1[grow*64+gcol].

__launch_bounds__(256)
__global__ void spmm128_g1(const uint4* __restrict__ packed16,
                           const int* __restrict__ rp, const unsigned short* __restrict__ X,
                           const float* __restrict__ AM, const float* __restrict__ Mv,
                           const float* __restrict__ bias,
                           const unsigned short* __restrict__ wt1,
                           unsigned short* __restrict__ g1, int n) {
    __shared__ __align__(16) unsigned short h16[16][136];
    const int t = threadIdx.x;
    const int lane = t & 63;
    const int w = t >> 6;
    const int rbase = blockIdx.x * 16;

    for (int i = 0; i < 4; ++i) {
        const int lr = w * 4 + i;
        const int r = rbase + lr;
        float o0 = 0.0f, o1 = 0.0f;
        if (r < n) {
            const int s = __builtin_amdgcn_readfirstlane(rp[r]);
            const int e = __builtin_amdgcn_readfirstlane(rp[r + 1]);
            float acc0 = 0.0f, acc1 = 0.0f;
            for (int base = s; base < e; base += 64) {
                const int nn = min(64, e - base);
                int ci = 0; float vf = 0.0f;
                if (lane < nn) {
                    const uint4 pk = packed16[base + lane];
                    ci = (int)pk.x;
                    vf = __builtin_bit_cast(float, pk.y);
                }
                int j = 0;
                for (; j + 16 <= nn; j += 16) {
                    unsigned u[16];
#pragma unroll
                    for (int q = 0; q < 16; ++q) {
                        const int cq = rl_i(ci, j + q);
                        u[q] = *(const unsigned*)(X + (size_t)cq * 128 + lane * 2);
                    }
#pragma unroll
                    for (int q = 0; q < 16; ++q) {
                        const float vq = rl_f(vf, j + q);
                        acc0 += vq * bf_lo(u[q]);
                        acc1 += vq * bf_hi(u[q]);
                    }
                }
                for (; j + 8 <= nn; j += 8) {
                    unsigned u[8];
#pragma unroll
                    for (int q = 0; q < 8; ++q) {
                        const int cq = rl_i(ci, j + q);
                        u[q] = *(const unsigned*)(X + (size_t)cq * 128 + lane * 2);
                    }
#pragma unroll
                    for (int q = 0; q < 8; ++q) {
                        const float vq = rl_f(vf, j + q);
                        acc0 += vq * bf_lo(u[q]);
                        acc1 += vq * bf_hi(u[q]);
                    }
                }
                for (; j < nn; ++j) {
                    const int cq = rl_i(ci, j);
                    const float vq = rl_f(vf, j);
                    const unsigned u = *(const unsigned*)(X + (size_t)cq * 128 + lane * 2);
                    acc0 += vq * bf_lo(u);
                    acc1 += vq * bf_hi(u);
                }
            }
            const float am = AM[r];
            const float mr = Mv[r];   // fold M (>=0): M⊙relu(y) = relu(M⊙y)
            o0 = fminf(fmaxf((acc0 * am + bias[2 * lane]) * mr, 0.0f), 1e30f);
            o1 = fminf(fmaxf((acc1 * am + bias[2 * lane + 1]) * mr, 0.0f), 1e30f);
        }
        *(unsigned*)&h16[lr][2 * lane] = pack2bf(o0, o1);
    }
    __syncthreads();

    // MFMA gemm1: wave w -> cols w*16 .. w*16+15
    const int m15 = lane & 15;
    const int q = lane >> 4;
    bf16x8 a[4];
#pragma unroll
    for (int ks = 0; ks < 4; ++ks)
        a[ks] = __builtin_bit_cast(bf16x8,
                    *(const uint4*)&h16[m15][ks * 32 + q * 8]);
    f32x4 acc = {0.f, 0.f, 0.f, 0.f};
    const int bn = w * 16 + m15;
#pragma unroll
    for (int ks = 0; ks < 4; ++ks) {
        const uint4 z = *(const uint4*)(wt1 + (size_t)bn * 128 + ks * 32 + q * 8);
        acc = __builtin_amdgcn_mfma_f32_16x16x32_bf16(
            a[ks], __builtin_bit_cast(bf16x8, z), acc, 0, 0, 0);
    }
    const int gcol = w * 16 + m15;
#pragma unroll
    for (int rr = 0; rr < 4; ++rr) {
        const int grow = rbase + q * 4 + rr;
        if (grow < n) g1[(size_t)grow * 64 + gcol] = f2bf(clampf(acc[rr]));
    }
}

// ---------------- SpMM F=64 + MFMA gemm2: out40 = relu(AM⊙agg+b1)@W2 ----------------
// Block = 16 rows: 4 waves x 4 rows. Gather = 4-edge-parallel (uint2/lane);
// after reduction lanes<16 hold 4 feats -> LDS h16[16][72] bf16 (144B
// stride). Barrier. Waves 0-2 compute col-tiles 0..2 (48 padded cols, 2
// MFMAs each); write cols<40 of out40.

__launch_bounds__(256)
__global__ void spmm64_g2(const uint4* __restrict__ packed16,
                          const int* __restrict__ rp, const unsigned short* __restrict__ X,
                          const float* __restrict__ AM, const float* __restrict__ bias1,
                          const unsigned short* __restrict__ wt2,
                          unsigned short* __restrict__ out40, int n) {
    __shared__ __align__(16) unsigned short h16[16][72];
    const int t = threadIdx.x;
    const int lane = t & 63;
    const int w = t >> 6;
    const int g = lane >> 4;        // edge slot 0..3
    const int ls = lane & 15;       // feat quad: feats 4*ls..4*ls+3
    const int rbase = blockIdx.x * 16;

    for (int i = 0; i < 4; ++i) {
        const int lr = w * 4 + i;
        const int r = rbase + lr;
        float a0 = 0.0f, a1 = 0.0f, a2 = 0.0f, a3 = 0.0f;
        if (r < n) {
            const int s = __builtin_amdgcn_readfirstlane(rp[r]);
            const int e = __builtin_amdgcn_readfirstlane(rp[r + 1]);
            for (int base = s; base < e; base += 64) {
                const int nn = min(64, e - base);
                int ci = 0; float vf = 0.0f;
                if (lane < nn) {
                    const uint4 pk = packed16[base + lane];
                    ci = (int)pk.x;
                    vf = __builtin_bit_cast(float, pk.y);
                }
                for (int j = 0; j < nn; j += 16) {
#pragma unroll
                    for (int q = 0; q < 4; ++q) {
                        const int jj = j + 4 * q + g;
                        const bool ok = jj < nn;
                        const int idx = jj & 63;
                        const int c = __shfl(ci, idx);
                        const float v = __shfl(vf, idx);
                        if (ok) {
                            const uint2 u = *(const uint2*)(X + (size_t)c * 64 + ls * 4);
                            a0 += v * bf_lo(u.x);
                            a1 += v * bf_hi(u.x);
                            a2 += v * bf_lo(u.y);
                            a3 += v * bf_hi(u.y);
                        }
                    }
                }
            }
            a0 += __shfl_xor(a0, 16); a0 += __shfl_xor(a0, 32);
            a1 += __shfl_xor(a1, 16); a1 += __shfl_xor(a1, 32);
            a2 += __shfl_xor(a2, 16); a2 += __shfl_xor(a2, 32);
            a3 += __shfl_xor(a3, 16); a3 += __shfl_xor(a3, 32);
            const float am = AM[r];
            a0 = fminf(fmaxf(a0 * am + bias1[4 * ls + 0], 0.0f), 1e30f);
            a1 = fminf(fmaxf(a1 * am + bias1[4 * ls + 1], 0.0f), 1e30f);
            a2 = fminf(fmaxf(a2 * am + bias1[4 * ls + 2], 0.0f), 1e30f);
            a3 = fminf(fmaxf(a3 * am + bias1[4 * ls + 3], 0.0f), 1e30f);
        }
        if (lane < 16) {
            uint2 wv;
            wv.x = pack2bf(a0, a1);
            wv.y = pack2bf(a2, a3);
            *(uint2*)&h16[lr][4 * ls] = wv;
        }
    }
    __syncthreads();

    // MFMA gemm2: waves 0-2 -> col tiles 0..2 (cols 0..47, wt2 zero-padded)
    if (w < 3) {
        const int m15 = lane & 15;
        const int q = lane >> 4;
        bf16x8 a[2];
#pragma unroll
        for (int ks = 0; ks < 2; ++ks)
            a[ks] = __builtin_bit_cast(bf16x8,
                        *(const uint4*)&h16[m15][ks * 32 + q * 8]);
        f32x4 acc = {0.f, 0.f, 0.f, 0.f};
        const int bn = w * 16 + m15;
#pragma unroll
        for (int ks = 0; ks < 2; ++ks) {
            const uint4 z = *(const uint4*)(wt2 + (size_t)bn * 64 + ks * 32 + q * 8);
            acc = __builtin_amdgcn_mfma_f32_16x16x32_bf16(
                a[ks], __builtin_bit_cast(bf16x8, z), acc, 0, 0, 0);
        }
        const int gcol = w * 16 + m15;
        if (gcol < 40) {
#pragma unroll
            for (int rr = 0; rr < 4; ++rr) {
                const int grow = rbase + q * 4 + rr;
                if (grow < n) out40[(size_t)grow * 40 + gcol] = f2bf(clampf(acc[rr]));
            }
        }
    }
}

// ---------------- SpMM F=40 + log_softmax: 3 edges/wave, 24 in flight ----------------

__launch_bounds__(256)
__global__ void spmm40_kernel(const uint4* __restrict__ packed16,
                              const int* __restrict__ rp, const unsigned short* __restrict__ X,
                              const float* __restrict__ bias,
                              float* __restrict__ out, int n) {
    const int lane = threadIdx.x & 63;
    const int g = lane / 20;
    const int ls = lane - 20 * g;
    const bool active = g < 3;
    const int r = (int)((blockIdx.x * (unsigned)blockDim.x + threadIdx.x) >> 6);
    if (r >= n) return;
    const int s = __builtin_amdgcn_readfirstlane(rp[r]);
    const int e = __builtin_amdgcn_readfirstlane(rp[r + 1]);

    float acc0 = 0.0f, acc1 = 0.0f;
    for (int base = s; base < e; base += 64) {
        const int nn = min(64, e - base);
        int ci = 0; float vf = 0.0f;
        if (lane < nn) {
            const uint4 pk = packed16[base + lane];
            ci = (int)pk.x;
            vf = __builtin_bit_cast(float, pk.z);    // adj (not adjZ) values
        }
        for (int j = 0; j < nn; j += 24) {
#pragma unroll
            for (int q = 0; q < 8; ++q) {
                const int jj = j + 3 * q + g;
                const bool ok = active && jj < nn;
                const int idx = jj & 63;
                const int c = __shfl(ci, idx);
                const float v = __shfl(vf, idx);
                if (ok) {
                    const unsigned u = *(const unsigned*)(X + (size_t)c * 40 + ls * 2);
                    acc0 += v * bf_lo(u);
                    acc1 += v * bf_hi(u);
                }
            }
        }
    }
    {
        const float a1 = __shfl(acc0, (lane + 20) & 63);
        const float a2 = __shfl(acc0, (lane + 40) & 63);
        const float b1 = __shfl(acc1, (lane + 20) & 63);
        const float b2 = __shfl(acc1, (lane + 40) & 63);
        acc0 += a1 + a2;
        acc1 += b1 + b2;
    }

    const bool own = lane < 20;
    const float vv0 = own ? fminf(fmaxf(acc0 + bias[2 * ls], -1e30f), 1e30f) : -INFINITY;
    const float vv1 = own ? fminf(fmaxf(acc1 + bias[2 * ls + 1], -1e30f), 1e30f) : -INFINITY;
    float mx = fmaxf(vv0, vv1);
#pragma unroll
    for (int off = 32; off > 0; off >>= 1) mx = fmaxf(mx, __shfl_xor(mx, off));
    float sum = own ? (expf(vv0 - mx) + expf(vv1 - mx)) : 0.0f;
#pragma unroll
    for (int off = 32; off > 0; off >>= 1) sum += __shfl_xor(sum, off);
    if (own) {
        const float lse = mx + logf(sum);
        *(float2*)(out + (size_t)r * 40 + ls * 2) = make_float2(vv0 - lse, vv1 - lse);
    }
}

// ---------------- launch ----------------

extern "C" void kernel_launch(void* const* d_in, const int* in_sizes, int n_in,
                              void* d_out, int out_size, void* d_ws, size_t ws_size,
                              hipStream_t stream) {
    const float* x    = (const float*)d_in[0];
    const float* M    = (const float*)d_in[1];
    const float* AM   = (const float*)d_in[2];
    const float* adjv = (const float*)d_in[3];
    const float* adjZ = (const float*)d_in[4];
    const float* W0   = (const float*)d_in[5];
    const float* b0   = (const float*)d_in[6];
    const float* W1   = (const float*)d_in[7];
    const float* b1   = (const float*)d_in[8];
    const float* W2   = (const float*)d_in[9];
    const float* b2   = (const float*)d_in[10];
    const int* row    = (const int*)d_in[11];
    const int* col    = (const int*)d_in[12];
    float* out = (float*)d_out;

    const int n = in_sizes[1];   // N  (must be <= NBINS = 50176)
    const int E = in_sizes[3];   // edges (<= NBMAX*32768)

    // workspace layout (~39 MB):
    //   t_buf  : N*128 bf16 (gemm0 out; later reused stride-40 by spmm64_g2)
    //   wt0/1/2: bf16 W^T arrays
    //   h region (N*128 bf16 reserve) aliased by lrank/cntmat/cmabs (dead
    //     before spmm128_g1 writes g1 stride-64 there)
    //   rp     : N+2 int
    //   gpub   : 256 u64 sync slots ([0..195] scan publish)
    //   packed16: E uint4 {col, vZ, vA, 0}
    unsigned short* t_buf = (unsigned short*)d_ws;          // N*128 bf16
    unsigned short* wt0 = t_buf + (size_t)n * 128;          // 128*128
    unsigned short* wt1 = wt0 + 128 * 128;                  // 64*128
    unsigned short* wt2 = wt1 + 64 * 128;                   // 48*64
    unsigned short* h_buf = wt2 + 48 * 64;                  // N*128 bf16 reserve
    unsigned short* lrank  = h_buf;                         // E u16
    unsigned short* cntmat = lrank + (size_t)E;             // [NBMAX][NBINS] u16
    unsigned* cmabs = (unsigned*)(cntmat + (size_t)NBMAX * NBINS);
    int* rp = (int*)(h_buf + (size_t)n * 128);              // N+1 (+pad)
    unsigned long long* gpub = (unsigned long long*)
        (((uintptr_t)(rp + n + 2) + 7) & ~(uintptr_t)7);    // 256 u64
    uint4* packed16 = (uint4*)
        (((uintptr_t)(gpub + 256) + 15) & ~(uintptr_t)15);  // E uint4

    const int NB = (E + HIST_EPB - 1) >> HIST_EPB_LOG;      // hist chunks (<=26)
    const int gemmBlocks = (n + 63) / 64;                   // 4-wave gemm groups
    const int gemmB4 = (gemmBlocks + 3) / 4;                // 1024-thr gemm blocks

    hipMemsetAsync(gpub, 0, 256 * sizeof(unsigned long long), stream);
    prep_wt<<<(128 * 128 + 64 * 128 + 48 * 64 + 255) / 256, 256, 0, stream>>>(
        W0, W1, W2, wt0, wt1, wt2);

    // fused LDS histogram (rank+count, no sync) + gemm0 MFMA
    hist_gemm0<<<NB + gemmB4, 1024, 0, stream>>>(row, cntmat, lrank, E, NB,
                                                 x, M, wt0, t_buf, n);

    // one-kernel scan: rp + absolute chunk offsets (publish/read-poll)
    scan_one<<<SCAN_BLOCKS, 256, 0, stream>>>(cntmat, cmabs, rp, gpub, n, NB, E);

    // standalone scatter (no sync; one 16B random store per edge)
    scatter_kernel<<<(E + 255) / 256, 256, 0, stream>>>(row, col, adjv, adjZ,
                                                        cmabs, lrank, packed16, E);

    const int blk16 = (n + 15) / 16;   // 16 rows per block

    // layer 0 aggregate + MFMA gemm1: h_buf(stride 64) = (M⊙h0)@W1
    spmm128_g1<<<blk16, 256, 0, stream>>>(packed16, rp, t_buf, AM, M, b0, wt1,
                                          h_buf, n);
    // layer 1 aggregate + MFMA gemm2: t_buf(stride 40) = relu(AM⊙agg+b1)@W2
    spmm64_g2<<<blk16, 256, 0, stream>>>(packed16, rp, h_buf, AM, b1, wt2,
                                         t_buf, n);
    // layer 2 aggregate + log_softmax
    spmm40_kernel<<<blk16 * 4, 256, 0, stream>>>(packed16, rp, t_buf, b2, out, n);
}

// Round 11
// 261.997 us; speedup vs baseline: 1.7759x; 1.0075x over previous
//
#include <hip/hip_runtime.h>
#include <hip/hip_bf16.h>
#include <math.h>

// PaGCN forward, restructured:
//   h0 = relu(AM ⊙ spmm(adjZ, (M⊙x)@W0) + b0)      (spmm gathers 128 bf16 feats)
//   h1 = relu(AM ⊙ spmm(adjZ, (M⊙h0)@W1) + b1)     (spmm gathers 64 bf16 feats)
//   out = log_softmax(spmm(adj, h1@W2) + b2)        (spmm gathers 40 bf16 feats)
//
// R17 (on measured-good R16 = 264µs): two structural trims, no new sync.
//  - HIST_EPB 32768->16384: hist blocks each serialize EPB LDS-atomic rank
//    updates on one CU (25 hist blocks vs 196 gemm0 blocks -> hist is the
//    tail). NB=49 doubles hist parallelism; grid 49+196=245<=256 keeps one
//    block-wave at 98KB LDS/block. Ranks <2^16, u16 counters carry-free.
//  - gpub zeroing folded into prep_wt block 0 (drops the memset dispatch;
//    prep_wt is stream-ordered before any gpub consumer). 7 dispatches.
//  - cntmat/cmabs (bigger at NB<=50) moved to a dedicated region after
//    packed16 (~55MB total, within proven ws) -- kills the h-region
//    aliasing hazard too.
// Carried from R16 (measured 264): LDS-staged MFMA dense layers fused into
// the gather kernels (spmm128_g1, spmm64_g2), sync-free hist+gemm0,
// publish/read-poll scan on distinct addresses, one 16B random store per
// edge, bf16 gather targets, M folded into spmm128 epilogue, clamped
// epilogues, 16-deep spmm128 bursts.
// Standing lessons: in-kernel flag gates cost 100x a kernel boundary
// (R13/R14); readlane dense GEMM is VALU-bound, use MFMA (R15).

typedef __attribute__((ext_vector_type(8))) short bf16x8;
typedef __attribute__((ext_vector_type(4))) float f32x4;

#define HIST_EPB_LOG 14
#define HIST_EPB 16384          // edges per hist block (< 2^16: u16-safe)
#define NBINS 50176             // >= N, = 196*256, even (u16-pair packing)
#define NBMAX 50                // reserved chunk capacity (E <= 50*16384)
#define SCAN_BLOCKS 196         // 256 bins per block = 50176

__device__ __forceinline__ float rl_f(float v, int j) {
    return __builtin_bit_cast(float,
        __builtin_amdgcn_readlane(__builtin_bit_cast(int, v), j));
}
__device__ __forceinline__ int rl_i(int v, int j) {
    return __builtin_amdgcn_readlane(v, j);
}
__device__ __forceinline__ unsigned short f2bf(float f) {
    unsigned u = __builtin_bit_cast(unsigned, f);
    u += 0x7fffu + ((u >> 16) & 1u);   // round-to-nearest-even
    return (unsigned short)(u >> 16);
}
__device__ __forceinline__ unsigned pack2bf(float lo, float hi) {
    return (unsigned)f2bf(lo) | ((unsigned)f2bf(hi) << 16);
}
__device__ __forceinline__ float bf_lo(unsigned u) {
    return __builtin_bit_cast(float, u << 16);
}
__device__ __forceinline__ float bf_hi(unsigned u) {
    return __builtin_bit_cast(float, u & 0xffff0000u);
}
__device__ __forceinline__ float clampf(float v) {   // NaN -> -1e30 (finite)
    return fminf(fmaxf(v, -1e30f), 1e30f);
}
__device__ __forceinline__ unsigned long long aload(const unsigned long long* p) {
    return __hip_atomic_load(p, __ATOMIC_ACQUIRE, __HIP_MEMORY_SCOPE_AGENT);
}

// ---------------- W prep (+ gpub zero): Wt[n][k] = bf16(W[k][n]) ----------------

__global__ void prep_wt(const float* __restrict__ W0, const float* __restrict__ W1,
                        const float* __restrict__ W2,
                        unsigned short* __restrict__ wt0, unsigned short* __restrict__ wt1,
                        unsigned short* __restrict__ wt2,
                        unsigned long long* __restrict__ gpub) {
    if (blockIdx.x == 0) gpub[threadIdx.x] = 0ULL;   // 256 sync slots
    int idx = blockIdx.x * 256 + threadIdx.x;
    if (idx < 128 * 128) {                       // wt0: [128][128]
        int nn = idx >> 7, k = idx & 127;
        wt0[idx] = f2bf(W0[k * 128 + nn]);
    }
    idx -= 128 * 128;
    if (idx >= 0 && idx < 64 * 128) {            // wt1: [64][128]
        int nn = idx >> 7, k = idx & 127;
        wt1[idx] = f2bf(W1[k * 64 + nn]);
    }
    idx -= 64 * 128;
    if (idx >= 0 && idx < 48 * 64) {             // wt2: [48][64], n>=40 zero
        int nn = idx >> 6, k = idx & 63;
        wt2[idx] = (nn < 40) ? f2bf(W2[k * 40 + nn]) : (unsigned short)0;
    }
}

// ---------------- fused LDS histogram (counting-sort rank) + gemm0 ----------------
// Blocks [0,NB): per-chunk LDS histogram over all bins (packed u16 pairs).
// Blocks [NB, NB+gemmB4): gemm0, 4x 256-thread groups per block.
// ZERO cross-block synchronization.

__launch_bounds__(1024)
__global__ void hist_gemm0(const int* __restrict__ row,
                           unsigned short* __restrict__ cntmat,
                           unsigned short* __restrict__ lrank, int E, int NB,
                           const float* __restrict__ x, const float* __restrict__ Mv,
                           const unsigned short* __restrict__ Wt0,
                           unsigned short* __restrict__ t_buf, int n) {
    __shared__ __align__(16) unsigned hcnt[NBINS / 2];   // 98KB: u16 bin pairs
    const int blk = blockIdx.x;
    const int t = threadIdx.x;
    if (blk < NB) {
        uint4* h4 = (uint4*)hcnt;
        const uint4 z4 = make_uint4(0u, 0u, 0u, 0u);
        for (int i = t; i < NBINS / 8; i += 1024) h4[i] = z4;
        __syncthreads();
        const int s = blk << HIST_EPB_LOG;
        const int e = min(E, s + HIST_EPB);
        for (int i = s + t; i < e; i += 1024) {
            const int r = row[i];               // r < n <= NBINS
            const unsigned sh = (unsigned)(r & 1) << 4;
            const unsigned old = atomicAdd(&hcnt[r >> 1], 1u << sh);
            lrank[i] = (unsigned short)((old >> sh) & 0xffffu);
        }
        __syncthreads();
        uint4* dst = (uint4*)(cntmat + (size_t)blk * NBINS);
        for (int i = t; i < NBINS / 8; i += 1024) dst[i] = h4[i];
    } else {
        // ---- gemm0: (M⊙x)@W0 -> t_buf bf16, 4x 256-thread groups ----
        const int tid = t & 255;
        const int bid = (blk - NB) * 4 + (t >> 8);
        const int lane = tid & 63;
        const int wid = tid >> 6;
        const int m15 = lane & 15;
        const int q = lane >> 4;
        const int rA = bid * 64 + wid * 16 + m15;

        bf16x8 a[4];
        {
            float m = 1.0f;
            if (rA < n) m = Mv[rA];
#pragma unroll
            for (int ks = 0; ks < 4; ++ks) {
                float4 lo = make_float4(0.f, 0.f, 0.f, 0.f);
                float4 hi = make_float4(0.f, 0.f, 0.f, 0.f);
                if (rA < n) {
                    lo = *(const float4*)(x + (size_t)rA * 128 + ks * 32 + q * 8);
                    hi = *(const float4*)(x + (size_t)rA * 128 + ks * 32 + q * 8 + 4);
                }
                union { bf16x8 v; unsigned short u[8]; } pk;
                pk.u[0] = f2bf(lo.x * m); pk.u[1] = f2bf(lo.y * m);
                pk.u[2] = f2bf(lo.z * m); pk.u[3] = f2bf(lo.w * m);
                pk.u[4] = f2bf(hi.x * m); pk.u[5] = f2bf(hi.y * m);
                pk.u[6] = f2bf(hi.z * m); pk.u[7] = f2bf(hi.w * m);
                a[ks] = pk.v;
            }
        }
#pragma unroll
        for (int nt = 0; nt < 8; ++nt) {
            f32x4 acc = {0.f, 0.f, 0.f, 0.f};
            const int bn = nt * 16 + m15;
#pragma unroll
            for (int ks = 0; ks < 4; ++ks) {
                const uint4 z = *(const uint4*)(Wt0 + (size_t)bn * 128 + ks * 32 + q * 8);
                acc = __builtin_amdgcn_mfma_f32_16x16x32_bf16(
                    a[ks], __builtin_bit_cast(bf16x8, z), acc, 0, 0, 0);
            }
            const int gc = nt * 16 + m15;
#pragma unroll
            for (int rr = 0; rr < 4; ++rr) {
                const int gr = bid * 64 + wid * 16 + q * 4 + rr;
                if (gr < n) t_buf[(size_t)gr * 128 + gc] = f2bf(clampf(acc[rr]));
            }
        }
    }
}

// ---------------- fused scan: rp + absolute chunk offsets, one kernel ----------------
// 196 resident blocks, 256 bins each. Publish via fence+atomicExch; poll via
// atomic LOADS on DISTINCT addresses (measured fine R11/R12/R15/R16).

__launch_bounds__(256)
__global__ void scan_one(const unsigned short* __restrict__ cm,
                         unsigned* __restrict__ cmabs, int* __restrict__ rp,
                         unsigned long long* __restrict__ gpub,
                         int n, int NB, int E) {
    __shared__ int sd[256];
    const int g = blockIdx.x;
    const int t = threadIdx.x;
    const int bin = g * 256 + t;

    unsigned tot = 0;
    for (int b = 0; b < NB; ++b) tot += cm[(size_t)b * NBINS + bin];

    sd[t] = (int)tot;
    __syncthreads();
    for (int off = 1; off < 256; off <<= 1) {
        int xv = (t >= off) ? sd[t - off] : 0;
        __syncthreads();
        sd[t] += xv;
        __syncthreads();
    }
    const int excl = sd[t] - (int)tot;
    const int gtot = sd[255];
    __syncthreads();

    if (t == 0)
        atomicExch(&gpub[g], (1ULL << 32) | (unsigned long long)(unsigned)gtot);

    int my = 0;
    for (int p = t; p < g; p += 256) {
        unsigned long long v;
        do { v = aload(&gpub[p]); } while ((v >> 32) == 0ULL);
        my += (int)(unsigned)v;
    }
    sd[t] = my;
    __syncthreads();
    for (int off = 128; off > 0; off >>= 1) {
        if (t < off) sd[t] += sd[t + off];
        __syncthreads();
    }
    const int base = sd[0];

    const int rpf = base + excl;
    if (bin < n) rp[bin] = rpf;
    if (g == SCAN_BLOCKS - 1 && t == 255) rp[n] = E;

    int run = rpf;
    for (int b = 0; b < NB; ++b) {
        cmabs[(size_t)b * NBINS + bin] = (unsigned)run;
        run += (int)cm[(size_t)b * NBINS + bin];
    }
}

// ---------------- scatter (atomic-free, ONE random 16B line per edge) ----------------

__global__ void scatter_kernel(const int* __restrict__ row, const int* __restrict__ col,
                               const float* __restrict__ vA, const float* __restrict__ vZ,
                               const unsigned* __restrict__ cmabs,
                               const unsigned short* __restrict__ lrank,
                               uint4* __restrict__ packed16, int E) {
    int e = blockIdx.x * blockDim.x + threadIdx.x;
    if (e >= E) return;
    const int r = row[e];
    const int pos = (int)(cmabs[(size_t)(e >> HIST_EPB_LOG) * NBINS + r]
                          + (unsigned)lrank[e]);
    uint4 pk;
    pk.x = (unsigned)col[e];
    pk.y = __builtin_bit_cast(unsigned, vZ[e]);
    pk.z = __builtin_bit_cast(unsigned, vA[e]);
    pk.w = 0u;
    packed16[pos] = pk;
}

// ---------------- SpMM F=128 + MFMA gemm1: g1 = (M⊙h0)@W1 ----------------
// Block = 16 rows: 4 waves x 4 rows (sequential gather per wave). Gather
// epilogue (M⊙relu(AM⊙agg+b0)) -> LDS h16[16][136] bf16 (272B stride:
// 16B-aligned, 2-way banks). Barrier. Wave w computes output cols
// w*16..w*16+15 via 4 MFMAs; writes g1[grow*64+gcol].

__launch_bounds__(256)
__global__ void spmm128_g1(const uint4* __restrict__ packed16,
                           const int* __restrict__ rp, const unsigned short* __restrict__ X,
                           const float* __restrict__ AM, const float* __restrict__ Mv,
                           const float* __restrict__ bias,
                           const unsigned short* __restrict__ wt1,
                           unsigned short* __restrict__ g1, int n) {
    __shared__ __align__(16) unsigned short h16[16][136];
    const int t = threadIdx.x;
    const int lane = t & 63;
    const int w = t >> 6;
    const int rbase = blockIdx.x * 16;

    for (int i = 0; i < 4; ++i) {
        const int lr = w * 4 + i;
        const int r = rbase + lr;
        float o0 = 0.0f, o1 = 0.0f;
        if (r < n) {
            const int s = __builtin_amdgcn_readfirstlane(rp[r]);
            const int e = __builtin_amdgcn_readfirstlane(rp[r + 1]);
            float acc0 = 0.0f, acc1 = 0.0f;
            for (int base = s; base < e; base += 64) {
                const int nn = min(64, e - base);
                int ci = 0; float vf = 0.0f;
                if (lane < nn) {
                    const uint4 pk = packed16[base + lane];
                    ci = (int)pk.x;
                    vf = __builtin_bit_cast(float, pk.y);
                }
                int j = 0;
                for (; j + 16 <= nn; j += 16) {
                    unsigned u[16];
#pragma unroll
                    for (int q = 0; q < 16; ++q) {
                        const int cq = rl_i(ci, j + q);
                        u[q] = *(const unsigned*)(X + (size_t)cq * 128 + lane * 2);
                    }
#pragma unroll
                    for (int q = 0; q < 16; ++q) {
                        const float vq = rl_f(vf, j + q);
                        acc0 += vq * bf_lo(u[q]);
                        acc1 += vq * bf_hi(u[q]);
                    }
                }
                for (; j + 8 <= nn; j += 8) {
                    unsigned u[8];
#pragma unroll
                    for (int q = 0; q < 8; ++q) {
                        const int cq = rl_i(ci, j + q);
                        u[q] = *(const unsigned*)(X + (size_t)cq * 128 + lane * 2);
                    }
#pragma unroll
                    for (int q = 0; q < 8; ++q) {
                        const float vq = rl_f(vf, j + q);
                        acc0 += vq * bf_lo(u[q]);
                        acc1 += vq * bf_hi(u[q]);
                    }
                }
                for (; j < nn; ++j) {
                    const int cq = rl_i(ci, j);
                    const float vq = rl_f(vf, j);
                    const unsigned u = *(const unsigned*)(X + (size_t)cq * 128 + lane * 2);
                    acc0 += vq * bf_lo(u);
                    acc1 += vq * bf_hi(u);
                }
            }
            const float am = AM[r];
            const float mr = Mv[r];   // fold M (>=0): M⊙relu(y) = relu(M⊙y)
            o0 = fminf(fmaxf((acc0 * am + bias[2 * lane]) * mr, 0.0f), 1e30f);
            o1 = fminf(fmaxf((acc1 * am + bias[2 * lane + 1]) * mr, 0.0f), 1e30f);
        }
        *(unsigned*)&h16[lr][2 * lane] = pack2bf(o0, o1);
    }
    __syncthreads();

    // MFMA gemm1: wave w -> cols w*16 .. w*16+15
    const int m15 = lane & 15;
    const int q = lane >> 4;
    bf16x8 a[4];
#pragma unroll
    for (int ks = 0; ks < 4; ++ks)
        a[ks] = __builtin_bit_cast(bf16x8,
                    *(const uint4*)&h16[m15][ks * 32 + q * 8]);
    f32x4 acc = {0.f, 0.f, 0.f, 0.f};
    const int bn = w * 16 + m15;
#pragma unroll
    for (int ks = 0; ks < 4; ++ks) {
        const uint4 z = *(const uint4*)(wt1 + (size_t)bn * 128 + ks * 32 + q * 8);
        acc = __builtin_amdgcn_mfma_f32_16x16x32_bf16(
            a[ks], __builtin_bit_cast(bf16x8, z), acc, 0, 0, 0);
    }
    const int gcol = w * 16 + m15;
#pragma unroll
    for (int rr = 0; rr < 4; ++rr) {
        const int grow = rbase + q * 4 + rr;
        if (grow < n) g1[(size_t)grow * 64 + gcol] = f2bf(clampf(acc[rr]));
    }
}

// ---------------- SpMM F=64 + MFMA gemm2: out40 = relu(AM⊙agg+b1)@W2 ----------------
// Block = 16 rows: 4 waves x 4 rows. Gather = 4-edge-parallel (uint2/lane);
// after reduction lanes<16 hold 4 feats -> LDS h16[16][72] bf16 (144B
// stride). Barrier. Waves 0-2 compute col-tiles 0..2 (48 padded cols, 2
// MFMAs each); write cols<40 of out40.

__launch_bounds__(256)
__global__ void spmm64_g2(const uint4* __restrict__ packed16,
                          const int* __restrict__ rp, const unsigned short* __restrict__ X,
                          const float* __restrict__ AM, const float* __restrict__ bias1,
                          const unsigned short* __restrict__ wt2,
                          unsigned short* __restrict__ out40, int n) {
    __shared__ __align__(16) unsigned short h16[16][72];
    const int t = threadIdx.x;
    const int lane = t & 63;
    const int w = t >> 6;
    const int g = lane >> 4;        // edge slot 0..3
    const int ls = lane & 15;       // feat quad: feats 4*ls..4*ls+3
    const int rbase = blockIdx.x * 16;

    for (int i = 0; i < 4; ++i) {
        const int lr = w * 4 + i;
        const int r = rbase + lr;
        float a0 = 0.0f, a1 = 0.0f, a2 = 0.0f, a3 = 0.0f;
        if (r < n) {
            const int s = __builtin_amdgcn_readfirstlane(rp[r]);
            const int e = __builtin_amdgcn_readfirstlane(rp[r + 1]);
            for (int base = s; base < e; base += 64) {
                const int nn = min(64, e - base);
                int ci = 0; float vf = 0.0f;
                if (lane < nn) {
                    const uint4 pk = packed16[base + lane];
                    ci = (int)pk.x;
                    vf = __builtin_bit_cast(float, pk.y);
                }
                for (int j = 0; j < nn; j += 16) {
#pragma unroll
                    for (int q = 0; q < 4; ++q) {
                        const int jj = j + 4 * q + g;
                        const bool ok = jj < nn;
                        const int idx = jj & 63;
                        const int c = __shfl(ci, idx);
                        const float v = __shfl(vf, idx);
                        if (ok) {
                            const uint2 u = *(const uint2*)(X + (size_t)c * 64 + ls * 4);
                            a0 += v * bf_lo(u.x);
                            a1 += v * bf_hi(u.x);
                            a2 += v * bf_lo(u.y);
                            a3 += v * bf_hi(u.y);
                        }
                    }
                }
            }
            a0 += __shfl_xor(a0, 16); a0 += __shfl_xor(a0, 32);
            a1 += __shfl_xor(a1, 16); a1 += __shfl_xor(a1, 32);
            a2 += __shfl_xor(a2, 16); a2 += __shfl_xor(a2, 32);
            a3 += __shfl_xor(a3, 16); a3 += __shfl_xor(a3, 32);
            const float am = AM[r];
            a0 = fminf(fmaxf(a0 * am + bias1[4 * ls + 0], 0.0f), 1e30f);
            a1 = fminf(fmaxf(a1 * am + bias1[4 * ls + 1], 0.0f), 1e30f);
            a2 = fminf(fmaxf(a2 * am + bias1[4 * ls + 2], 0.0f), 1e30f);
            a3 = fminf(fmaxf(a3 * am + bias1[4 * ls + 3], 0.0f), 1e30f);
        }
        if (lane < 16) {
            uint2 wv;
            wv.x = pack2bf(a0, a1);
            wv.y = pack2bf(a2, a3);
            *(uint2*)&h16[lr][4 * ls] = wv;
        }
    }
    __syncthreads();

    // MFMA gemm2: waves 0-2 -> col tiles 0..2 (cols 0..47, wt2 zero-padded)
    if (w < 3) {
        const int m15 = lane & 15;
        const int q = lane >> 4;
        bf16x8 a[2];
#pragma unroll
        for (int ks = 0; ks < 2; ++ks)
            a[ks] = __builtin_bit_cast(bf16x8,
                        *(const uint4*)&h16[m15][ks * 32 + q * 8]);
        f32x4 acc = {0.f, 0.f, 0.f, 0.f};
        const int bn = w * 16 + m15;
#pragma unroll
        for (int ks = 0; ks < 2; ++ks) {
            const uint4 z = *(const uint4*)(wt2 + (size_t)bn * 64 + ks * 32 + q * 8);
            acc = __builtin_amdgcn_mfma_f32_16x16x32_bf16(
                a[ks], __builtin_bit_cast(bf16x8, z), acc, 0, 0, 0);
        }
        const int gcol = w * 16 + m15;
        if (gcol < 40) {
#pragma unroll
            for (int rr = 0; rr < 4; ++rr) {
                const int grow = rbase + q * 4 + rr;
                if (grow < n) out40[(size_t)grow * 40 + gcol] = f2bf(clampf(acc[rr]));
            }
        }
    }
}

// ---------------- SpMM F=40 + log_softmax: 3 edges/wave, 24 in flight ----------------

__launch_bounds__(256)
__global__ void spmm40_kernel(const uint4* __restrict__ packed16,
                              const int* __restrict__ rp, const unsigned short* __restrict__ X,
                              const float* __restrict__ bias,
                              float* __restrict__ out, int n) {
    const int lane = threadIdx.x & 63;
    const int g = lane / 20;
    const int ls = lane - 20 * g;
    const bool active = g < 3;
    const int r = (int)((blockIdx.x * (unsigned)blockDim.x + threadIdx.x) >> 6);
    if (r >= n) return;
    const int s = __builtin_amdgcn_readfirstlane(rp[r]);
    const int e = __builtin_amdgcn_readfirstlane(rp[r + 1]);

    float acc0 = 0.0f, acc1 = 0.0f;
    for (int base = s; base < e; base += 64) {
        const int nn = min(64, e - base);
        int ci = 0; float vf = 0.0f;
        if (lane < nn) {
            const uint4 pk = packed16[base + lane];
            ci = (int)pk.x;
            vf = __builtin_bit_cast(float, pk.z);    // adj (not adjZ) values
        }
        for (int j = 0; j < nn; j += 24) {
#pragma unroll
            for (int q = 0; q < 8; ++q) {
                const int jj = j + 3 * q + g;
                const bool ok = active && jj < nn;
                const int idx = jj & 63;
                const int c = __shfl(ci, idx);
                const float v = __shfl(vf, idx);
                if (ok) {
                    const unsigned u = *(const unsigned*)(X + (size_t)c * 40 + ls * 2);
                    acc0 += v * bf_lo(u);
                    acc1 += v * bf_hi(u);
                }
            }
        }
    }
    {
        const float a1 = __shfl(acc0, (lane + 20) & 63);
        const float a2 = __shfl(acc0, (lane + 40) & 63);
        const float b1 = __shfl(acc1, (lane + 20) & 63);
        const float b2 = __shfl(acc1, (lane + 40) & 63);
        acc0 += a1 + a2;
        acc1 += b1 + b2;
    }

    const bool own = lane < 20;
    const float vv0 = own ? fminf(fmaxf(acc0 + bias[2 * ls], -1e30f), 1e30f) : -INFINITY;
    const float vv1 = own ? fminf(fmaxf(acc1 + bias[2 * ls + 1], -1e30f), 1e30f) : -INFINITY;
    float mx = fmaxf(vv0, vv1);
#pragma unroll
    for (int off = 32; off > 0; off >>= 1) mx = fmaxf(mx, __shfl_xor(mx, off));
    float sum = own ? (expf(vv0 - mx) + expf(vv1 - mx)) : 0.0f;
#pragma unroll
    for (int off = 32; off > 0; off >>= 1) sum += __shfl_xor(sum, off);
    if (own) {
        const float lse = mx + logf(sum);
        *(float2*)(out + (size_t)r * 40 + ls * 2) = make_float2(vv0 - lse, vv1 - lse);
    }
}

// ---------------- launch ----------------

extern "C" void kernel_launch(void* const* d_in, const int* in_sizes, int n_in,
                              void* d_out, int out_size, void* d_ws, size_t ws_size,
                              hipStream_t stream) {
    const float* x    = (const float*)d_in[0];
    const float* M    = (const float*)d_in[1];
    const float* AM   = (const float*)d_in[2];
    const float* adjv = (const float*)d_in[3];
    const float* adjZ = (const float*)d_in[4];
    const float* W0   = (const float*)d_in[5];
    const float* b0   = (const float*)d_in[6];
    const float* W1   = (const float*)d_in[7];
    const float* b1   = (const float*)d_in[8];
    const float* W2   = (const float*)d_in[9];
    const float* b2   = (const float*)d_in[10];
    const int* row    = (const int*)d_in[11];
    const int* col    = (const int*)d_in[12];
    float* out = (float*)d_out;

    const int n = in_sizes[1];   // N  (must be <= NBINS = 50176)
    const int E = in_sizes[3];   // edges (<= NBMAX*16384)

    // workspace layout (~55 MB, NO aliasing):
    //   t_buf   : N*128 bf16 (gemm0 out; later stride-40 out of spmm64_g2)
    //   wt0/1/2 : bf16 W^T arrays
    //   h_buf   : N*128 bf16 (g1 stride-64 out of spmm128_g1)
    //   rp      : N+2 int
    //   gpub    : 256 u64 sync slots (zeroed by prep_wt blk 0)
    //   packed16: E uint4 {col, vZ, vA, 0}
    //   lrank   : E u16 | cntmat [NBMAX][NBINS] u16 | cmabs [NBMAX][NBINS] u32
    unsigned short* t_buf = (unsigned short*)d_ws;          // N*128 bf16
    unsigned short* wt0 = t_buf + (size_t)n * 128;          // 128*128
    unsigned short* wt1 = wt0 + 128 * 128;                  // 64*128
    unsigned short* wt2 = wt1 + 64 * 128;                   // 48*64
    unsigned short* h_buf = wt2 + 48 * 64;                  // N*128 bf16
    int* rp = (int*)(h_buf + (size_t)n * 128);              // N+1 (+pad)
    unsigned long long* gpub = (unsigned long long*)
        (((uintptr_t)(rp + n + 2) + 7) & ~(uintptr_t)7);    // 256 u64
    uint4* packed16 = (uint4*)
        (((uintptr_t)(gpub + 256) + 15) & ~(uintptr_t)15);  // E uint4
    unsigned short* lrank = (unsigned short*)(packed16 + (size_t)E);   // E u16
    unsigned short* cntmat = lrank + (size_t)E;             // [NBMAX][NBINS] u16
    unsigned* cmabs = (unsigned*)(cntmat + (size_t)NBMAX * NBINS);     // u32

    const int NB = (E + HIST_EPB - 1) >> HIST_EPB_LOG;      // hist chunks (<=49)
    const int gemmBlocks = (n + 63) / 64;                   // 4-wave gemm groups
    const int gemmB4 = (gemmBlocks + 3) / 4;                // 1024-thr gemm blocks
    // grid NB + gemmB4 must stay <= 256 (one block-wave at 98KB LDS/block)

    prep_wt<<<(128 * 128 + 64 * 128 + 48 * 64 + 255) / 256, 256, 0, stream>>>(
        W0, W1, W2, wt0, wt1, wt2, gpub);

    // fused LDS histogram (rank+count, no sync) + gemm0 MFMA
    hist_gemm0<<<NB + gemmB4, 1024, 0, stream>>>(row, cntmat, lrank, E, NB,
                                                 x, M, wt0, t_buf, n);

    // one-kernel scan: rp + absolute chunk offsets (publish/read-poll)
    scan_one<<<SCAN_BLOCKS, 256, 0, stream>>>(cntmat, cmabs, rp, gpub, n, NB, E);

    // standalone scatter (no sync; one 16B random store per edge)
    scatter_kernel<<<(E + 255) / 256, 256, 0, stream>>>(row, col, adjv, adjZ,
                                                        cmabs, lrank, packed16, E);

    const int blk16 = (n + 15) / 16;   // 16 rows per block

    // layer 0 aggregate + MFMA gemm1: h_buf(stride 64) = (M⊙h0)@W1
    spmm128_g1<<<blk16, 256, 0, stream>>>(packed16, rp, t_buf, AM, M, b0, wt1,
                                          h_buf, n);
    // layer 1 aggregate + MFMA gemm2: t_buf(stride 40) = relu(AM⊙agg+b1)@W2
    spmm64_g2<<<blk16, 256, 0, stream>>>(packed16, rp, h_buf, AM, b1, wt2,
                                         t_buf, n);
    // layer 2 aggregate + log_softmax
    spmm40_kernel<<<blk16 * 4, 256, 0, stream>>>(packed16, rp, t_buf, b2, out, n);
}

// Round 12
// 253.206 us; speedup vs baseline: 1.8375x; 1.0347x over previous
//
#include <hip/hip_runtime.h>
#include <hip/hip_bf16.h>
#include <math.h>

// PaGCN forward, restructured:
//   h0 = relu(AM ⊙ spmm(adjZ, (M⊙x)@W0) + b0)      (spmm gathers 128 bf16 feats)
//   h1 = relu(AM ⊙ spmm(adjZ, (M⊙h0)@W1) + b1)     (spmm gathers 64 bf16 feats)
//   out = log_softmax(spmm(adj, h1@W2) + b2)        (spmm gathers 40 bf16 feats)
//
// R18 (on measured R17 = 262µs): dispatch + L2-locality trims, no new sync.
//  - prep_wt dispatch ELIMINATED (7->6) with zero gates: gemm0 blocks
//    self-transpose W0 into their own LDS (aliasing the 98KB hcnt buffer;
//    [128][136] u16 pad -> 16B-aligned ds_read_b128 B-frags, 2-way banks =
//    free). wt1/wt2 (first consumed TWO kernel boundaries later -> kernel-
//    boundary visibility suffices) + gpub zeroing prep'd by one dedicated
//    extra block. Grid 49+196+1 = 246 <= 256 keeps one block-wave.
//  - scatter grid XCD-swizzled: chunk c's cmabs row (200KB) fits one XCD
//    L2, but round-robin dispatch spread each chunk's 64 blocks over all 8
//    XCDs (8x refetch). p -> chunk=(p%8)+8*(p/512), off=(p>>3)&63 pins a
//    chunk to one XCD (perf heuristic only; correctness mapping-free).
// Carried from R16/R17 (measured 262): LDS-staged MFMA dense layers fused
// into gather kernels (spmm128_g1, spmm64_g2), sync-free hist+gemm0,
// publish/read-poll scan on distinct addresses, one 16B random store per
// edge, bf16 gather targets, M folded into spmm128 epilogue, clamped
// epilogues, 16-deep spmm128 bursts, HIST_EPB=16384 (NB<=49).
// Standing lessons: in-kernel flag gates cost 100x a kernel boundary
// (R13/R14); readlane dense GEMM is VALU-bound, use MFMA (R15).

typedef __attribute__((ext_vector_type(8))) short bf16x8;
typedef __attribute__((ext_vector_type(4))) float f32x4;

#define HIST_EPB_LOG 14
#define HIST_EPB 16384          // edges per hist block (< 2^16: u16-safe)
#define NBINS 50176             // >= N, = 196*256, even (u16-pair packing)
#define NBMAX 50                // reserved chunk capacity (E <= 50*16384)
#define SCAN_BLOCKS 196         // 256 bins per block = 50176

__device__ __forceinline__ float rl_f(float v, int j) {
    return __builtin_bit_cast(float,
        __builtin_amdgcn_readlane(__builtin_bit_cast(int, v), j));
}
__device__ __forceinline__ int rl_i(int v, int j) {
    return __builtin_amdgcn_readlane(v, j);
}
__device__ __forceinline__ unsigned short f2bf(float f) {
    unsigned u = __builtin_bit_cast(unsigned, f);
    u += 0x7fffu + ((u >> 16) & 1u);   // round-to-nearest-even
    return (unsigned short)(u >> 16);
}
__device__ __forceinline__ unsigned pack2bf(float lo, float hi) {
    return (unsigned)f2bf(lo) | ((unsigned)f2bf(hi) << 16);
}
__device__ __forceinline__ float bf_lo(unsigned u) {
    return __builtin_bit_cast(float, u << 16);
}
__device__ __forceinline__ float bf_hi(unsigned u) {
    return __builtin_bit_cast(float, u & 0xffff0000u);
}
__device__ __forceinline__ float clampf(float v) {   // NaN -> -1e30 (finite)
    return fminf(fmaxf(v, -1e30f), 1e30f);
}
__device__ __forceinline__ unsigned long long aload(const unsigned long long* p) {
    return __hip_atomic_load(p, __ATOMIC_ACQUIRE, __HIP_MEMORY_SCOPE_AGENT);
}

// ---------------- fused LDS histogram + gemm0 + wt1/wt2 prep ----------------
// Blocks [0,NB): per-chunk LDS histogram over all bins (packed u16 pairs).
// Blocks [NB, NB+gemmB4): gemm0, 4x 256-thread groups; W0 self-transposed
//   into this block's LDS (aliases hcnt) -- no global wt0, no prep gate.
// Block NB+gemmB4: preps wt1/wt2 (global) + zeroes gpub. Consumers are >=2
//   kernel boundaries later -> ordinary kernel-boundary visibility.
// ZERO cross-block synchronization.

__launch_bounds__(1024)
__global__ void hist_gemm0(const int* __restrict__ row,
                           unsigned short* __restrict__ cntmat,
                           unsigned short* __restrict__ lrank, int E, int NB,
                           const float* __restrict__ x, const float* __restrict__ Mv,
                           const float* __restrict__ W0, const float* __restrict__ W1,
                           const float* __restrict__ W2,
                           unsigned short* __restrict__ wt1,
                           unsigned short* __restrict__ wt2,
                           unsigned long long* __restrict__ gpub,
                           unsigned short* __restrict__ t_buf, int n, int gemmB4) {
    __shared__ __align__(16) unsigned hcnt[NBINS / 2];   // 98KB: u16 bin pairs
    const int blk = blockIdx.x;
    const int t = threadIdx.x;
    if (blk < NB) {
        uint4* h4 = (uint4*)hcnt;
        const uint4 z4 = make_uint4(0u, 0u, 0u, 0u);
        for (int i = t; i < NBINS / 8; i += 1024) h4[i] = z4;
        __syncthreads();
        const int s = blk << HIST_EPB_LOG;
        const int e = min(E, s + HIST_EPB);
        for (int i = s + t; i < e; i += 1024) {
            const int r = row[i];               // r < n <= NBINS
            const unsigned sh = (unsigned)(r & 1) << 4;
            const unsigned old = atomicAdd(&hcnt[r >> 1], 1u << sh);
            lrank[i] = (unsigned short)((old >> sh) & 0xffffu);
        }
        __syncthreads();
        uint4* dst = (uint4*)(cntmat + (size_t)blk * NBINS);
        for (int i = t; i < NBINS / 8; i += 1024) dst[i] = h4[i];
    } else if (blk < NB + gemmB4) {
        // ---- gemm0: (M⊙x)@W0 -> t_buf bf16; W0^T staged in LDS ----
        unsigned short* w0l = (unsigned short*)hcnt;     // [128][136] u16, 34.8KB
        const int tid = t & 255;
        const int bid = (blk - NB) * 4 + (t >> 8);
        const int lane = tid & 63;
        const int wid = tid >> 6;
        const int m15 = lane & 15;
        const int q = lane >> 4;
        const int rA = bid * 64 + wid * 16 + m15;

        // A-fragments first (independent of LDS) -- latency hides under transpose
        bf16x8 a[4];
        {
            float m = 1.0f;
            if (rA < n) m = Mv[rA];
#pragma unroll
            for (int ks = 0; ks < 4; ++ks) {
                float4 lo = make_float4(0.f, 0.f, 0.f, 0.f);
                float4 hi = make_float4(0.f, 0.f, 0.f, 0.f);
                if (rA < n) {
                    lo = *(const float4*)(x + (size_t)rA * 128 + ks * 32 + q * 8);
                    hi = *(const float4*)(x + (size_t)rA * 128 + ks * 32 + q * 8 + 4);
                }
                union { bf16x8 v; unsigned short u[8]; } pk;
                pk.u[0] = f2bf(lo.x * m); pk.u[1] = f2bf(lo.y * m);
                pk.u[2] = f2bf(lo.z * m); pk.u[3] = f2bf(lo.w * m);
                pk.u[4] = f2bf(hi.x * m); pk.u[5] = f2bf(hi.y * m);
                pk.u[6] = f2bf(hi.z * m); pk.u[7] = f2bf(hi.w * m);
                a[ks] = pk.v;
            }
        }
        // cooperative W0 transpose: w0l[nn][k] = bf16(W0[k][nn])
        // coalesced global read; LDS u16 writes (8-way conflict, ~16K elems: cheap)
#pragma unroll
        for (int i = 0; i < 16; ++i) {
            const int idx = t + i * 1024;                // k-major source
            const int k = idx >> 7, nn = idx & 127;
            w0l[nn * 136 + k] = f2bf(W0[idx]);
        }
        __syncthreads();
#pragma unroll
        for (int nt = 0; nt < 8; ++nt) {
            f32x4 acc = {0.f, 0.f, 0.f, 0.f};
            const int bn = nt * 16 + m15;
#pragma unroll
            for (int ks = 0; ks < 4; ++ks) {
                const uint4 z = *(const uint4*)&w0l[bn * 136 + ks * 32 + q * 8];
                acc = __builtin_amdgcn_mfma_f32_16x16x32_bf16(
                    a[ks], __builtin_bit_cast(bf16x8, z), acc, 0, 0, 0);
            }
            const int gc = nt * 16 + m15;
#pragma unroll
            for (int rr = 0; rr < 4; ++rr) {
                const int gr = bid * 64 + wid * 16 + q * 4 + rr;
                if (gr < n) t_buf[(size_t)gr * 128 + gc] = f2bf(clampf(acc[rr]));
            }
        }
    } else {
        // ---- prep: wt1[64][128], wt2[48][64] (consumed 2+ launches later) ----
        if (t < 256) gpub[t] = 0ULL;
        for (int idx = t; idx < 64 * 128; idx += 1024) {
            int nn = idx >> 7, k = idx & 127;
            wt1[idx] = f2bf(W1[k * 64 + nn]);
        }
        for (int idx = t; idx < 48 * 64; idx += 1024) {
            int nn = idx >> 6, k = idx & 63;
            wt2[idx] = (nn < 40) ? f2bf(W2[k * 40 + nn]) : (unsigned short)0;
        }
    }
}

// ---------------- fused scan: rp + absolute chunk offsets, one kernel ----------------
// 196 resident blocks, 256 bins each. Publish via fence+atomicExch; poll via
// atomic LOADS on DISTINCT addresses (measured fine R11-R17).

__launch_bounds__(256)
__global__ void scan_one(const unsigned short* __restrict__ cm,
                         unsigned* __restrict__ cmabs, int* __restrict__ rp,
                         unsigned long long* __restrict__ gpub,
                         int n, int NB, int E) {
    __shared__ int sd[256];
    const int g = blockIdx.x;
    const int t = threadIdx.x;
    const int bin = g * 256 + t;

    unsigned tot = 0;
    for (int b = 0; b < NB; ++b) tot += cm[(size_t)b * NBINS + bin];

    sd[t] = (int)tot;
    __syncthreads();
    for (int off = 1; off < 256; off <<= 1) {
        int xv = (t >= off) ? sd[t - off] : 0;
        __syncthreads();
        sd[t] += xv;
        __syncthreads();
    }
    const int excl = sd[t] - (int)tot;
    const int gtot = sd[255];
    __syncthreads();

    if (t == 0)
        atomicExch(&gpub[g], (1ULL << 32) | (unsigned long long)(unsigned)gtot);

    int my = 0;
    for (int p = t; p < g; p += 256) {
        unsigned long long v;
        do { v = aload(&gpub[p]); } while ((v >> 32) == 0ULL);
        my += (int)(unsigned)v;
    }
    sd[t] = my;
    __syncthreads();
    for (int off = 128; off > 0; off >>= 1) {
        if (t < off) sd[t] += sd[t + off];
        __syncthreads();
    }
    const int base = sd[0];

    const int rpf = base + excl;
    if (bin < n) rp[bin] = rpf;
    if (g == SCAN_BLOCKS - 1 && t == 255) rp[n] = E;

    int run = rpf;
    for (int b = 0; b < NB; ++b) {
        cmabs[(size_t)b * NBINS + bin] = (unsigned)run;
        run += (int)cm[(size_t)b * NBINS + bin];
    }
}

// ---------------- scatter (atomic-free, ONE random 16B line per edge) ----------------
// XCD-swizzled grid: chunk c's 64 blocks map to physical ids with the same
// residue mod 8 -> one XCD owns c's 200KB cmabs row in its L2 (heuristic;
// correctness independent of the bid->XCD mapping).

__launch_bounds__(256)
__global__ void scatter_kernel(const int* __restrict__ row, const int* __restrict__ col,
                               const float* __restrict__ vA, const float* __restrict__ vZ,
                               const unsigned* __restrict__ cmabs,
                               const unsigned short* __restrict__ lrank,
                               uint4* __restrict__ packed16, int E, int NB) {
    const int p = blockIdx.x;
    const int c = (p & 7) + 8 * (p >> 9);       // chunk (8 chunks / 512 blocks)
    if (c >= NB) return;
    const int o = (p >> 3) & 63;                // block within chunk (64x256=16384)
    const int e = (c << HIST_EPB_LOG) + o * 256 + threadIdx.x;
    if (e >= E) return;
    const int r = row[e];
    const int pos = (int)(cmabs[(size_t)c * NBINS + r] + (unsigned)lrank[e]);
    uint4 pk;
    pk.x = (unsigned)col[e];
    pk.y = __builtin_bit_cast(unsigned, vZ[e]);
    pk.z = __builtin_bit_cast(unsigned, vA[e]);
    pk.w = 0u;
    packed16[pos] = pk;
}

// ---------------- SpMM F=128 + MFMA gemm1: g1 = (M⊙h0)@W1 ----------------
// Block = 16 rows: 4 waves x 4 rows (sequential gather per wave). Gather
// epilogue (M⊙relu(AM⊙agg+b0)) -> LDS h16[16][136] bf16 (272B stride:
// 16B-aligned, 2-way banks). Barrier. Wave w computes output cols
// w*16..w*16+15 via 4 MFMAs; writes g1[grow*64+gcol].

__launch_bounds__(256)
__global__ void spmm128_g1(const uint4* __restrict__ packed16,
                           const int* __restrict__ rp, const unsigned short* __restrict__ X,
                           const float* __restrict__ AM, const float* __restrict__ Mv,
                           const float* __restrict__ bias,
                           const unsigned short* __restrict__ wt1,
                           unsigned short* __restrict__ g1, int n) {
    __shared__ __align__(16) unsigned short h16[16][136];
    const int t = threadIdx.x;
    const int lane = t & 63;
    const int w = t >> 6;
    const int rbase = blockIdx.x * 16;

    for (int i = 0; i < 4; ++i) {
        const int lr = w * 4 + i;
        const int r = rbase + lr;
        float o0 = 0.0f, o1 = 0.0f;
        if (r < n) {
            const int s = __builtin_amdgcn_readfirstlane(rp[r]);
            const int e = __builtin_amdgcn_readfirstlane(rp[r + 1]);
            float acc0 = 0.0f, acc1 = 0.0f;
            for (int base = s; base < e; base += 64) {
                const int nn = min(64, e - base);
                int ci = 0; float vf = 0.0f;
                if (lane < nn) {
                    const uint4 pk = packed16[base + lane];
                    ci = (int)pk.x;
                    vf = __builtin_bit_cast(float, pk.y);
                }
                int j = 0;
                for (; j + 16 <= nn; j += 16) {
                    unsigned u[16];
#pragma unroll
                    for (int q = 0; q < 16; ++q) {
                        const int cq = rl_i(ci, j + q);
                        u[q] = *(const unsigned*)(X + (size_t)cq * 128 + lane * 2);
                    }
#pragma unroll
                    for (int q = 0; q < 16; ++q) {
                        const float vq = rl_f(vf, j + q);
                        acc0 += vq * bf_lo(u[q]);
                        acc1 += vq * bf_hi(u[q]);
                    }
                }
                for (; j + 8 <= nn; j += 8) {
                    unsigned u[8];
#pragma unroll
                    for (int q = 0; q < 8; ++q) {
                        const int cq = rl_i(ci, j + q);
                        u[q] = *(const unsigned*)(X + (size_t)cq * 128 + lane * 2);
                    }
#pragma unroll
                    for (int q = 0; q < 8; ++q) {
                        const float vq = rl_f(vf, j + q);
                        acc0 += vq * bf_lo(u[q]);
                        acc1 += vq * bf_hi(u[q]);
                    }
                }
                for (; j < nn; ++j) {
                    const int cq = rl_i(ci, j);
                    const float vq = rl_f(vf, j);
                    const unsigned u = *(const unsigned*)(X + (size_t)cq * 128 + lane * 2);
                    acc0 += vq * bf_lo(u);
                    acc1 += vq * bf_hi(u);
                }
            }
            const float am = AM[r];
            const float mr = Mv[r];   // fold M (>=0): M⊙relu(y) = relu(M⊙y)
            o0 = fminf(fmaxf((acc0 * am + bias[2 * lane]) * mr, 0.0f), 1e30f);
            o1 = fminf(fmaxf((acc1 * am + bias[2 * lane + 1]) * mr, 0.0f), 1e30f);
        }
        *(unsigned*)&h16[lr][2 * lane] = pack2bf(o0, o1);
    }
    __syncthreads();

    // MFMA gemm1: wave w -> cols w*16 .. w*16+15
    const int m15 = lane & 15;
    const int q = lane >> 4;
    bf16x8 a[4];
#pragma unroll
    for (int ks = 0; ks < 4; ++ks)
        a[ks] = __builtin_bit_cast(bf16x8,
                    *(const uint4*)&h16[m15][ks * 32 + q * 8]);
    f32x4 acc = {0.f, 0.f, 0.f, 0.f};
    const int bn = w * 16 + m15;
#pragma unroll
    for (int ks = 0; ks < 4; ++ks) {
        const uint4 z = *(const uint4*)(wt1 + (size_t)bn * 128 + ks * 32 + q * 8);
        acc = __builtin_amdgcn_mfma_f32_16x16x32_bf16(
            a[ks], __builtin_bit_cast(bf16x8, z), acc, 0, 0, 0);
    }
    const int gcol = w * 16 + m15;
#pragma unroll
    for (int rr = 0; rr < 4; ++rr) {
        const int grow = rbase + q * 4 + rr;
        if (grow < n) g1[(size_t)grow * 64 + gcol] = f2bf(clampf(acc[rr]));
    }
}

// ---------------- SpMM F=64 + MFMA gemm2: out40 = relu(AM⊙agg+b1)@W2 ----------------
// Block = 16 rows: 4 waves x 4 rows. Gather = 4-edge-parallel (uint2/lane);
// after reduction lanes<16 hold 4 feats -> LDS h16[16][72] bf16 (144B
// stride). Barrier. Waves 0-2 compute col-tiles 0..2 (48 padded cols, 2
// MFMAs each); write cols<40 of out40.

__launch_bounds__(256)
__global__ void spmm64_g2(const uint4* __restrict__ packed16,
                          const int* __restrict__ rp, const unsigned short* __restrict__ X,
                          const float* __restrict__ AM, const float* __restrict__ bias1,
                          const unsigned short* __restrict__ wt2,
                          unsigned short* __restrict__ out40, int n) {
    __shared__ __align__(16) unsigned short h16[16][72];
    const int t = threadIdx.x;
    const int lane = t & 63;
    const int w = t >> 6;
    const int g = lane >> 4;        // edge slot 0..3
    const int ls = lane & 15;       // feat quad: feats 4*ls..4*ls+3
    const int rbase = blockIdx.x * 16;

    for (int i = 0; i < 4; ++i) {
        const int lr = w * 4 + i;
        const int r = rbase + lr;
        float a0 = 0.0f, a1 = 0.0f, a2 = 0.0f, a3 = 0.0f;
        if (r < n) {
            const int s = __builtin_amdgcn_readfirstlane(rp[r]);
            const int e = __builtin_amdgcn_readfirstlane(rp[r + 1]);
            for (int base = s; base < e; base += 64) {
                const int nn = min(64, e - base);
                int ci = 0; float vf = 0.0f;
                if (lane < nn) {
                    const uint4 pk = packed16[base + lane];
                    ci = (int)pk.x;
                    vf = __builtin_bit_cast(float, pk.y);
                }
                for (int j = 0; j < nn; j += 16) {
#pragma unroll
                    for (int q = 0; q < 4; ++q) {
                        const int jj = j + 4 * q + g;
                        const bool ok = jj < nn;
                        const int idx = jj & 63;
                        const int c = __shfl(ci, idx);
                        const float v = __shfl(vf, idx);
                        if (ok) {
                            const uint2 u = *(const uint2*)(X + (size_t)c * 64 + ls * 4);
                            a0 += v * bf_lo(u.x);
                            a1 += v * bf_hi(u.x);
                            a2 += v * bf_lo(u.y);
                            a3 += v * bf_hi(u.y);
                        }
                    }
                }
            }
            a0 += __shfl_xor(a0, 16); a0 += __shfl_xor(a0, 32);
            a1 += __shfl_xor(a1, 16); a1 += __shfl_xor(a1, 32);
            a2 += __shfl_xor(a2, 16); a2 += __shfl_xor(a2, 32);
            a3 += __shfl_xor(a3, 16); a3 += __shfl_xor(a3, 32);
            const float am = AM[r];
            a0 = fminf(fmaxf(a0 * am + bias1[4 * ls + 0], 0.0f), 1e30f);
            a1 = fminf(fmaxf(a1 * am + bias1[4 * ls + 1], 0.0f), 1e30f);
            a2 = fminf(fmaxf(a2 * am + bias1[4 * ls + 2], 0.0f), 1e30f);
            a3 = fminf(fmaxf(a3 * am + bias1[4 * ls + 3], 0.0f), 1e30f);
        }
        if (lane < 16) {
            uint2 wv;
            wv.x = pack2bf(a0, a1);
            wv.y = pack2bf(a2, a3);
            *(uint2*)&h16[lr][4 * ls] = wv;
        }
    }
    __syncthreads();

    // MFMA gemm2: waves 0-2 -> col tiles 0..2 (cols 0..47, wt2 zero-padded)
    if (w < 3) {
        const int m15 = lane & 15;
        const int q = lane >> 4;
        bf16x8 a[2];
#pragma unroll
        for (int ks = 0; ks < 2; ++ks)
            a[ks] = __builtin_bit_cast(bf16x8,
                        *(const uint4*)&h16[m15][ks * 32 + q * 8]);
        f32x4 acc = {0.f, 0.f, 0.f, 0.f};
        const int bn = w * 16 + m15;
#pragma unroll
        for (int ks = 0; ks < 2; ++ks) {
            const uint4 z = *(const uint4*)(wt2 + (size_t)bn * 64 + ks * 32 + q * 8);
            acc = __builtin_amdgcn_mfma_f32_16x16x32_bf16(
                a[ks], __builtin_bit_cast(bf16x8, z), acc, 0, 0, 0);
        }
        const int gcol = w * 16 + m15;
        if (gcol < 40) {
#pragma unroll
            for (int rr = 0; rr < 4; ++rr) {
                const int grow = rbase + q * 4 + rr;
                if (grow < n) out40[(size_t)grow * 40 + gcol] = f2bf(clampf(acc[rr]));
            }
        }
    }
}

// ---------------- SpMM F=40 + log_softmax: 3 edges/wave, 24 in flight ----------------

__launch_bounds__(256)
__global__ void spmm40_kernel(const uint4* __restrict__ packed16,
                              const int* __restrict__ rp, const unsigned short* __restrict__ X,
                              const float* __restrict__ bias,
                              float* __restrict__ out, int n) {
    const int lane = threadIdx.x & 63;
    const int g = lane / 20;
    const int ls = lane - 20 * g;
    const bool active = g < 3;
    const int r = (int)((blockIdx.x * (unsigned)blockDim.x + threadIdx.x) >> 6);
    if (r >= n) return;
    const int s = __builtin_amdgcn_readfirstlane(rp[r]);
    const int e = __builtin_amdgcn_readfirstlane(rp[r + 1]);

    float acc0 = 0.0f, acc1 = 0.0f;
    for (int base = s; base < e; base += 64) {
        const int nn = min(64, e - base);
        int ci = 0; float vf = 0.0f;
        if (lane < nn) {
            const uint4 pk = packed16[base + lane];
            ci = (int)pk.x;
            vf = __builtin_bit_cast(float, pk.z);    // adj (not adjZ) values
        }
        for (int j = 0; j < nn; j += 24) {
#pragma unroll
            for (int q = 0; q < 8; ++q) {
                const int jj = j + 3 * q + g;
                const bool ok = active && jj < nn;
                const int idx = jj & 63;
                const int c = __shfl(ci, idx);
                const float v = __shfl(vf, idx);
                if (ok) {
                    const unsigned u = *(const unsigned*)(X + (size_t)c * 40 + ls * 2);
                    acc0 += v * bf_lo(u);
                    acc1 += v * bf_hi(u);
                }
            }
        }
    }
    {
        const float a1 = __shfl(acc0, (lane + 20) & 63);
        const float a2 = __shfl(acc0, (lane + 40) & 63);
        const float b1 = __shfl(acc1, (lane + 20) & 63);
        const float b2 = __shfl(acc1, (lane + 40) & 63);
        acc0 += a1 + a2;
        acc1 += b1 + b2;
    }

    const bool own = lane < 20;
    const float vv0 = own ? fminf(fmaxf(acc0 + bias[2 * ls], -1e30f), 1e30f) : -INFINITY;
    const float vv1 = own ? fminf(fmaxf(acc1 + bias[2 * ls + 1], -1e30f), 1e30f) : -INFINITY;
    float mx = fmaxf(vv0, vv1);
#pragma unroll
    for (int off = 32; off > 0; off >>= 1) mx = fmaxf(mx, __shfl_xor(mx, off));
    float sum = own ? (expf(vv0 - mx) + expf(vv1 - mx)) : 0.0f;
#pragma unroll
    for (int off = 32; off > 0; off >>= 1) sum += __shfl_xor(sum, off);
    if (own) {
        const float lse = mx + logf(sum);
        *(float2*)(out + (size_t)r * 40 + ls * 2) = make_float2(vv0 - lse, vv1 - lse);
    }
}

// ---------------- launch ----------------

extern "C" void kernel_launch(void* const* d_in, const int* in_sizes, int n_in,
                              void* d_out, int out_size, void* d_ws, size_t ws_size,
                              hipStream_t stream) {
    const float* x    = (const float*)d_in[0];
    const float* M    = (const float*)d_in[1];
    const float* AM   = (const float*)d_in[2];
    const float* adjv = (const float*)d_in[3];
    const float* adjZ = (const float*)d_in[4];
    const float* W0   = (const float*)d_in[5];
    const float* b0   = (const float*)d_in[6];
    const float* W1   = (const float*)d_in[7];
    const float* b1   = (const float*)d_in[8];
    const float* W2   = (const float*)d_in[9];
    const float* b2   = (const float*)d_in[10];
    const int* row    = (const int*)d_in[11];
    const int* col    = (const int*)d_in[12];
    float* out = (float*)d_out;

    const int n = in_sizes[1];   // N  (must be <= NBINS = 50176)
    const int E = in_sizes[3];   // edges (<= NBMAX*16384)

    // workspace layout (~55 MB, NO aliasing):
    //   t_buf   : N*128 bf16 (gemm0 out; later stride-40 out of spmm64_g2)
    //   wt1/2   : bf16 W^T arrays (prep'd by hist_gemm0's extra block)
    //   h_buf   : N*128 bf16 (g1 stride-64 out of spmm128_g1)
    //   rp      : N+2 int
    //   gpub    : 256 u64 sync slots (zeroed by hist_gemm0's extra block)
    //   packed16: E uint4 {col, vZ, vA, 0}
    //   lrank   : E u16 | cntmat [NBMAX][NBINS] u16 | cmabs [NBMAX][NBINS] u32
    unsigned short* t_buf = (unsigned short*)d_ws;          // N*128 bf16
    unsigned short* wt1 = t_buf + (size_t)n * 128;          // 64*128
    unsigned short* wt2 = wt1 + 64 * 128;                   // 48*64
    unsigned short* h_buf = wt2 + 48 * 64;                  // N*128 bf16
    int* rp = (int*)(h_buf + (size_t)n * 128);              // N+1 (+pad)
    unsigned long long* gpub = (unsigned long long*)
        (((uintptr_t)(rp + n + 2) + 7) & ~(uintptr_t)7);    // 256 u64
    uint4* packed16 = (uint4*)
        (((uintptr_t)(gpub + 256) + 15) & ~(uintptr_t)15);  // E uint4
    unsigned short* lrank = (unsigned short*)(packed16 + (size_t)E);   // E u16
    unsigned short* cntmat = lrank + (size_t)E;             // [NBMAX][NBINS] u16
    unsigned* cmabs = (unsigned*)(cntmat + (size_t)NBMAX * NBINS);     // u32

    const int NB = (E + HIST_EPB - 1) >> HIST_EPB_LOG;      // hist chunks (<=49)
    const int gemmBlocks = (n + 63) / 64;                   // 4-wave gemm groups
    const int gemmB4 = (gemmBlocks + 3) / 4;                // 1024-thr gemm blocks
    // grid NB + gemmB4 + 1 must stay <= 256 (one block-wave at 98KB LDS)

    // fused LDS histogram + gemm0 (W0 self-transposed) + wt1/wt2/gpub prep
    hist_gemm0<<<NB + gemmB4 + 1, 1024, 0, stream>>>(row, cntmat, lrank, E, NB,
                                                     x, M, W0, W1, W2,
                                                     wt1, wt2, gpub, t_buf, n,
                                                     gemmB4);

    // one-kernel scan: rp + absolute chunk offsets (publish/read-poll)
    scan_one<<<SCAN_BLOCKS, 256, 0, stream>>>(cntmat, cmabs, rp, gpub, n, NB, E);

    // scatter, XCD-swizzled (one 16B random store per edge)
    const int scatGrid = 512 * ((NB + 7) / 8);
    scatter_kernel<<<scatGrid, 256, 0, stream>>>(row, col, adjv, adjZ,
                                                 cmabs, lrank, packed16, E, NB);

    const int blk16 = (n + 15) / 16;   // 16 rows per block

    // layer 0 aggregate + MFMA gemm1: h_buf(stride 64) = (M⊙h0)@W1
    spmm128_g1<<<blk16, 256, 0, stream>>>(packed16, rp, t_buf, AM, M, b0, wt1,
                                          h_buf, n);
    // layer 1 aggregate + MFMA gemm2: t_buf(stride 40) = relu(AM⊙agg+b1)@W2
    spmm64_g2<<<blk16, 256, 0, stream>>>(packed16, rp, h_buf, AM, b1, wt2,
                                         t_buf, n);
    // layer 2 aggregate + log_softmax
    spmm40_kernel<<<blk16 * 4, 256, 0, stream>>>(packed16, rp, t_buf, b2, out, n);
}

// Round 13
// 241.251 us; speedup vs baseline: 1.9286x; 1.0496x over previous
//
#include <hip/hip_runtime.h>
#include <hip/hip_bf16.h>
#include <math.h>

// PaGCN forward, restructured:
//   h0 = relu(AM ⊙ spmm(adjZ, (M⊙x)@W0) + b0)      (spmm gathers 128 bf16 feats)
//   h1 = relu(AM ⊙ spmm(adjZ, (M⊙h0)@W1) + b1)     (spmm gathers 64 bf16 feats)
//   out = log_softmax(spmm(adj, h1@W2) + b2)        (spmm gathers 40 bf16 feats)
//
// R19 (on measured R18 = 253µs): spmm128_g1 gather -> 2-edge-parallel uint2
// (the spmm64-proven pattern). Old: per 16 edges, 32 readlane + 16 dword
// loads (4B/lane). New: half-waves own alternate edges, each reads uint2
// (8B = 4 feats); per 32-edge group: 16 loads + 32 bpermute-shfl, same FMA
// and same bytes-in-flight. Final shfl_xor(32) merges halves. ONLY this
// kernel changed vs R18.
// Carried from R18 (measured 253): prep_wt folded away (gemm0 blocks
// self-transpose W0 in LDS; wt1/wt2+gpub prep'd by one extra block),
// XCD-swizzled scatter (chunk's cmabs row pinned to one XCD L2),
// LDS-staged MFMA dense layers (spmm128_g1, spmm64_g2), sync-free
// hist+gemm0, publish/read-poll scan on distinct addresses, one 16B random
// store per edge, bf16 gather targets, M folded into spmm128 epilogue,
// clamped epilogues, HIST_EPB=16384 (NB<=49). 6 dispatches.
// Standing lessons: in-kernel flag gates cost 100x a kernel boundary
// (R13/R14); readlane dense GEMM is VALU-bound, use MFMA (R15).

typedef __attribute__((ext_vector_type(8))) short bf16x8;
typedef __attribute__((ext_vector_type(4))) float f32x4;

#define HIST_EPB_LOG 14
#define HIST_EPB 16384          // edges per hist block (< 2^16: u16-safe)
#define NBINS 50176             // >= N, = 196*256, even (u16-pair packing)
#define NBMAX 50                // reserved chunk capacity (E <= 50*16384)
#define SCAN_BLOCKS 196         // 256 bins per block = 50176

__device__ __forceinline__ float rl_f(float v, int j) {
    return __builtin_bit_cast(float,
        __builtin_amdgcn_readlane(__builtin_bit_cast(int, v), j));
}
__device__ __forceinline__ int rl_i(int v, int j) {
    return __builtin_amdgcn_readlane(v, j);
}
__device__ __forceinline__ unsigned short f2bf(float f) {
    unsigned u = __builtin_bit_cast(unsigned, f);
    u += 0x7fffu + ((u >> 16) & 1u);   // round-to-nearest-even
    return (unsigned short)(u >> 16);
}
__device__ __forceinline__ unsigned pack2bf(float lo, float hi) {
    return (unsigned)f2bf(lo) | ((unsigned)f2bf(hi) << 16);
}
__device__ __forceinline__ float bf_lo(unsigned u) {
    return __builtin_bit_cast(float, u << 16);
}
__device__ __forceinline__ float bf_hi(unsigned u) {
    return __builtin_bit_cast(float, u & 0xffff0000u);
}
__device__ __forceinline__ float clampf(float v) {   // NaN -> -1e30 (finite)
    return fminf(fmaxf(v, -1e30f), 1e30f);
}
__device__ __forceinline__ unsigned long long aload(const unsigned long long* p) {
    return __hip_atomic_load(p, __ATOMIC_ACQUIRE, __HIP_MEMORY_SCOPE_AGENT);
}

// ---------------- fused LDS histogram + gemm0 + wt1/wt2 prep ----------------
// Blocks [0,NB): per-chunk LDS histogram over all bins (packed u16 pairs).
// Blocks [NB, NB+gemmB4): gemm0, 4x 256-thread groups; W0 self-transposed
//   into this block's LDS (aliases hcnt) -- no global wt0, no prep gate.
// Block NB+gemmB4: preps wt1/wt2 (global) + zeroes gpub. Consumers are >=2
//   kernel boundaries later -> ordinary kernel-boundary visibility.
// ZERO cross-block synchronization.

__launch_bounds__(1024)
__global__ void hist_gemm0(const int* __restrict__ row,
                           unsigned short* __restrict__ cntmat,
                           unsigned short* __restrict__ lrank, int E, int NB,
                           const float* __restrict__ x, const float* __restrict__ Mv,
                           const float* __restrict__ W0, const float* __restrict__ W1,
                           const float* __restrict__ W2,
                           unsigned short* __restrict__ wt1,
                           unsigned short* __restrict__ wt2,
                           unsigned long long* __restrict__ gpub,
                           unsigned short* __restrict__ t_buf, int n, int gemmB4) {
    __shared__ __align__(16) unsigned hcnt[NBINS / 2];   // 98KB: u16 bin pairs
    const int blk = blockIdx.x;
    const int t = threadIdx.x;
    if (blk < NB) {
        uint4* h4 = (uint4*)hcnt;
        const uint4 z4 = make_uint4(0u, 0u, 0u, 0u);
        for (int i = t; i < NBINS / 8; i += 1024) h4[i] = z4;
        __syncthreads();
        const int s = blk << HIST_EPB_LOG;
        const int e = min(E, s + HIST_EPB);
        for (int i = s + t; i < e; i += 1024) {
            const int r = row[i];               // r < n <= NBINS
            const unsigned sh = (unsigned)(r & 1) << 4;
            const unsigned old = atomicAdd(&hcnt[r >> 1], 1u << sh);
            lrank[i] = (unsigned short)((old >> sh) & 0xffffu);
        }
        __syncthreads();
        uint4* dst = (uint4*)(cntmat + (size_t)blk * NBINS);
        for (int i = t; i < NBINS / 8; i += 1024) dst[i] = h4[i];
    } else if (blk < NB + gemmB4) {
        // ---- gemm0: (M⊙x)@W0 -> t_buf bf16; W0^T staged in LDS ----
        unsigned short* w0l = (unsigned short*)hcnt;     // [128][136] u16, 34.8KB
        const int tid = t & 255;
        const int bid = (blk - NB) * 4 + (t >> 8);
        const int lane = tid & 63;
        const int wid = tid >> 6;
        const int m15 = lane & 15;
        const int q = lane >> 4;
        const int rA = bid * 64 + wid * 16 + m15;

        // A-fragments first (independent of LDS) -- latency hides under transpose
        bf16x8 a[4];
        {
            float m = 1.0f;
            if (rA < n) m = Mv[rA];
#pragma unroll
            for (int ks = 0; ks < 4; ++ks) {
                float4 lo = make_float4(0.f, 0.f, 0.f, 0.f);
                float4 hi = make_float4(0.f, 0.f, 0.f, 0.f);
                if (rA < n) {
                    lo = *(const float4*)(x + (size_t)rA * 128 + ks * 32 + q * 8);
                    hi = *(const float4*)(x + (size_t)rA * 128 + ks * 32 + q * 8 + 4);
                }
                union { bf16x8 v; unsigned short u[8]; } pk;
                pk.u[0] = f2bf(lo.x * m); pk.u[1] = f2bf(lo.y * m);
                pk.u[2] = f2bf(lo.z * m); pk.u[3] = f2bf(lo.w * m);
                pk.u[4] = f2bf(hi.x * m); pk.u[5] = f2bf(hi.y * m);
                pk.u[6] = f2bf(hi.z * m); pk.u[7] = f2bf(hi.w * m);
                a[ks] = pk.v;
            }
        }
        // cooperative W0 transpose: w0l[nn][k] = bf16(W0[k][nn])
#pragma unroll
        for (int i = 0; i < 16; ++i) {
            const int idx = t + i * 1024;                // k-major source
            const int k = idx >> 7, nn = idx & 127;
            w0l[nn * 136 + k] = f2bf(W0[idx]);
        }
        __syncthreads();
#pragma unroll
        for (int nt = 0; nt < 8; ++nt) {
            f32x4 acc = {0.f, 0.f, 0.f, 0.f};
            const int bn = nt * 16 + m15;
#pragma unroll
            for (int ks = 0; ks < 4; ++ks) {
                const uint4 z = *(const uint4*)&w0l[bn * 136 + ks * 32 + q * 8];
                acc = __builtin_amdgcn_mfma_f32_16x16x32_bf16(
                    a[ks], __builtin_bit_cast(bf16x8, z), acc, 0, 0, 0);
            }
            const int gc = nt * 16 + m15;
#pragma unroll
            for (int rr = 0; rr < 4; ++rr) {
                const int gr = bid * 64 + wid * 16 + q * 4 + rr;
                if (gr < n) t_buf[(size_t)gr * 128 + gc] = f2bf(clampf(acc[rr]));
            }
        }
    } else {
        // ---- prep: wt1[64][128], wt2[48][64] (consumed 2+ launches later) ----
        if (t < 256) gpub[t] = 0ULL;
        for (int idx = t; idx < 64 * 128; idx += 1024) {
            int nn = idx >> 7, k = idx & 127;
            wt1[idx] = f2bf(W1[k * 64 + nn]);
        }
        for (int idx = t; idx < 48 * 64; idx += 1024) {
            int nn = idx >> 6, k = idx & 63;
            wt2[idx] = (nn < 40) ? f2bf(W2[k * 40 + nn]) : (unsigned short)0;
        }
    }
}

// ---------------- fused scan: rp + absolute chunk offsets, one kernel ----------------
// 196 resident blocks, 256 bins each. Publish via fence+atomicExch; poll via
// atomic LOADS on DISTINCT addresses (measured fine R11-R18).

__launch_bounds__(256)
__global__ void scan_one(const unsigned short* __restrict__ cm,
                         unsigned* __restrict__ cmabs, int* __restrict__ rp,
                         unsigned long long* __restrict__ gpub,
                         int n, int NB, int E) {
    __shared__ int sd[256];
    const int g = blockIdx.x;
    const int t = threadIdx.x;
    const int bin = g * 256 + t;

    unsigned tot = 0;
    for (int b = 0; b < NB; ++b) tot += cm[(size_t)b * NBINS + bin];

    sd[t] = (int)tot;
    __syncthreads();
    for (int off = 1; off < 256; off <<= 1) {
        int xv = (t >= off) ? sd[t - off] : 0;
        __syncthreads();
        sd[t] += xv;
        __syncthreads();
    }
    const int excl = sd[t] - (int)tot;
    const int gtot = sd[255];
    __syncthreads();

    if (t == 0)
        atomicExch(&gpub[g], (1ULL << 32) | (unsigned long long)(unsigned)gtot);

    int my = 0;
    for (int p = t; p < g; p += 256) {
        unsigned long long v;
        do { v = aload(&gpub[p]); } while ((v >> 32) == 0ULL);
        my += (int)(unsigned)v;
    }
    sd[t] = my;
    __syncthreads();
    for (int off = 128; off > 0; off >>= 1) {
        if (t < off) sd[t] += sd[t + off];
        __syncthreads();
    }
    const int base = sd[0];

    const int rpf = base + excl;
    if (bin < n) rp[bin] = rpf;
    if (g == SCAN_BLOCKS - 1 && t == 255) rp[n] = E;

    int run = rpf;
    for (int b = 0; b < NB; ++b) {
        cmabs[(size_t)b * NBINS + bin] = (unsigned)run;
        run += (int)cm[(size_t)b * NBINS + bin];
    }
}

// ---------------- scatter (atomic-free, ONE random 16B line per edge) ----------------
// XCD-swizzled grid: chunk c's 64 blocks map to physical ids with the same
// residue mod 8 -> one XCD owns c's 200KB cmabs row in its L2 (heuristic;
// correctness independent of the bid->XCD mapping).

__launch_bounds__(256)
__global__ void scatter_kernel(const int* __restrict__ row, const int* __restrict__ col,
                               const float* __restrict__ vA, const float* __restrict__ vZ,
                               const unsigned* __restrict__ cmabs,
                               const unsigned short* __restrict__ lrank,
                               uint4* __restrict__ packed16, int E, int NB) {
    const int p = blockIdx.x;
    const int c = (p & 7) + 8 * (p >> 9);       // chunk (8 chunks / 512 blocks)
    if (c >= NB) return;
    const int o = (p >> 3) & 63;                // block within chunk (64x256=16384)
    const int e = (c << HIST_EPB_LOG) + o * 256 + threadIdx.x;
    if (e >= E) return;
    const int r = row[e];
    const int pos = (int)(cmabs[(size_t)c * NBINS + r] + (unsigned)lrank[e]);
    uint4 pk;
    pk.x = (unsigned)col[e];
    pk.y = __builtin_bit_cast(unsigned, vZ[e]);
    pk.z = __builtin_bit_cast(unsigned, vA[e]);
    pk.w = 0u;
    packed16[pos] = pk;
}

// ---------------- SpMM F=128 + MFMA gemm1: g1 = (M⊙h0)@W1 ----------------
// Block = 16 rows: 4 waves x 4 rows. Gather = 2-edge-parallel (uint2/lane,
// spmm64 pattern): half-wave h=lane>>5 owns edges j+2q+h; lane reads 4
// feats (8B) at ls=lane&31. shfl_xor(32) merges halves. Epilogue
// (M⊙relu(AM⊙agg+b0)) -> LDS h16[16][136] bf16. Barrier. Wave w computes
// output cols w*16..w*16+15 via 4 MFMAs; writes g1[grow*64+gcol].

__launch_bounds__(256)
__global__ void spmm128_g1(const uint4* __restrict__ packed16,
                           const int* __restrict__ rp, const unsigned short* __restrict__ X,
                           const float* __restrict__ AM, const float* __restrict__ Mv,
                           const float* __restrict__ bias,
                           const unsigned short* __restrict__ wt1,
                           unsigned short* __restrict__ g1, int n) {
    __shared__ __align__(16) unsigned short h16[16][136];
    const int t = threadIdx.x;
    const int lane = t & 63;
    const int w = t >> 6;
    const int h = lane >> 5;        // edge slot 0/1
    const int ls = lane & 31;       // feat quad: feats 4*ls..4*ls+3
    const int rbase = blockIdx.x * 16;

    for (int i = 0; i < 4; ++i) {
        const int lr = w * 4 + i;
        const int r = rbase + lr;
        float a0 = 0.0f, a1 = 0.0f, a2 = 0.0f, a3 = 0.0f;
        if (r < n) {
            const int s = __builtin_amdgcn_readfirstlane(rp[r]);
            const int e = __builtin_amdgcn_readfirstlane(rp[r + 1]);
            for (int base = s; base < e; base += 64) {
                const int nn = min(64, e - base);
                int ci = 0; float vf = 0.0f;
                if (lane < nn) {
                    const uint4 pk = packed16[base + lane];
                    ci = (int)pk.x;
                    vf = __builtin_bit_cast(float, pk.y);
                }
                for (int j = 0; j < nn; j += 32) {       // 32 edges/group: 16 loads in flight
                    uint2 uu[16]; float vv[16];
#pragma unroll
                    for (int q = 0; q < 16; ++q) {
                        const int jj = j + 2 * q + h;
                        const bool ok = jj < nn;
                        const int idx = jj & 63;
                        const int c = __shfl(ci, idx);
                        const float v = __shfl(vf, idx);
                        vv[q] = ok ? v : 0.0f;
                        uint2 u = make_uint2(0u, 0u);
                        if (ok) u = *(const uint2*)(X + (size_t)c * 128 + ls * 4);
                        uu[q] = u;
                    }
#pragma unroll
                    for (int q = 0; q < 16; ++q) {
                        a0 += vv[q] * bf_lo(uu[q].x);
                        a1 += vv[q] * bf_hi(uu[q].x);
                        a2 += vv[q] * bf_lo(uu[q].y);
                        a3 += vv[q] * bf_hi(uu[q].y);
                    }
                }
            }
            a0 += __shfl_xor(a0, 32);
            a1 += __shfl_xor(a1, 32);
            a2 += __shfl_xor(a2, 32);
            a3 += __shfl_xor(a3, 32);
            const float am = AM[r];
            const float mr = Mv[r];   // fold M (>=0): M⊙relu(y) = relu(M⊙y)
            a0 = fminf(fmaxf((a0 * am + bias[4 * ls + 0]) * mr, 0.0f), 1e30f);
            a1 = fminf(fmaxf((a1 * am + bias[4 * ls + 1]) * mr, 0.0f), 1e30f);
            a2 = fminf(fmaxf((a2 * am + bias[4 * ls + 2]) * mr, 0.0f), 1e30f);
            a3 = fminf(fmaxf((a3 * am + bias[4 * ls + 3]) * mr, 0.0f), 1e30f);
        }
        if (lane < 32) {
            uint2 wv;
            wv.x = pack2bf(a0, a1);
            wv.y = pack2bf(a2, a3);
            *(uint2*)&h16[lr][4 * ls] = wv;
        }
    }
    __syncthreads();

    // MFMA gemm1: wave w -> cols w*16 .. w*16+15
    const int m15 = lane & 15;
    const int q = lane >> 4;
    bf16x8 a[4];
#pragma unroll
    for (int ks = 0; ks < 4; ++ks)
        a[ks] = __builtin_bit_cast(bf16x8,
                    *(const uint4*)&h16[m15][ks * 32 + q * 8]);
    f32x4 acc = {0.f, 0.f, 0.f, 0.f};
    const int bn = w * 16 + m15;
#pragma unroll
    for (int ks = 0; ks < 4; ++ks) {
        const uint4 z = *(const uint4*)(wt1 + (size_t)bn * 128 + ks * 32 + q * 8);
        acc = __builtin_amdgcn_mfma_f32_16x16x32_bf16(
            a[ks], __builtin_bit_cast(bf16x8, z), acc, 0, 0, 0);
    }
    const int gcol = w * 16 + m15;
#pragma unroll
    for (int rr = 0; rr < 4; ++rr) {
        const int grow = rbase + q * 4 + rr;
        if (grow < n) g1[(size_t)grow * 64 + gcol] = f2bf(clampf(acc[rr]));
    }
}

// ---------------- SpMM F=64 + MFMA gemm2: out40 = relu(AM⊙agg+b1)@W2 ----------------
// Block = 16 rows: 4 waves x 4 rows. Gather = 4-edge-parallel (uint2/lane);
// after reduction lanes<16 hold 4 feats -> LDS h16[16][72] bf16 (144B
// stride). Barrier. Waves 0-2 compute col-tiles 0..2 (48 padded cols, 2
// MFMAs each); write cols<40 of out40.

__launch_bounds__(256)
__global__ void spmm64_g2(const uint4* __restrict__ packed16,
                          const int* __restrict__ rp, const unsigned short* __restrict__ X,
                          const float* __restrict__ AM, const float* __restrict__ bias1,
                          const unsigned short* __restrict__ wt2,
                          unsigned short* __restrict__ out40, int n) {
    __shared__ __align__(16) unsigned short h16[16][72];
    const int t = threadIdx.x;
    const int lane = t & 63;
    const int w = t >> 6;
    const int g = lane >> 4;        // edge slot 0..3
    const int ls = lane & 15;       // feat quad: feats 4*ls..4*ls+3
    const int rbase = blockIdx.x * 16;

    for (int i = 0; i < 4; ++i) {
        const int lr = w * 4 + i;
        const int r = rbase + lr;
        float a0 = 0.0f, a1 = 0.0f, a2 = 0.0f, a3 = 0.0f;
        if (r < n) {
            const int s = __builtin_amdgcn_readfirstlane(rp[r]);
            const int e = __builtin_amdgcn_readfirstlane(rp[r + 1]);
            for (int base = s; base < e; base += 64) {
                const int nn = min(64, e - base);
                int ci = 0; float vf = 0.0f;
                if (lane < nn) {
                    const uint4 pk = packed16[base + lane];
                    ci = (int)pk.x;
                    vf = __builtin_bit_cast(float, pk.y);
                }
                for (int j = 0; j < nn; j += 16) {
#pragma unroll
                    for (int q = 0; q < 4; ++q) {
                        const int jj = j + 4 * q + g;
                        const bool ok = jj < nn;
                        const int idx = jj & 63;
                        const int c = __shfl(ci, idx);
                        const float v = __shfl(vf, idx);
                        if (ok) {
                            const uint2 u = *(const uint2*)(X + (size_t)c * 64 + ls * 4);
                            a0 += v * bf_lo(u.x);
                            a1 += v * bf_hi(u.x);
                            a2 += v * bf_lo(u.y);
                            a3 += v * bf_hi(u.y);
                        }
                    }
                }
            }
            a0 += __shfl_xor(a0, 16); a0 += __shfl_xor(a0, 32);
            a1 += __shfl_xor(a1, 16); a1 += __shfl_xor(a1, 32);
            a2 += __shfl_xor(a2, 16); a2 += __shfl_xor(a2, 32);
            a3 += __shfl_xor(a3, 16); a3 += __shfl_xor(a3, 32);
            const float am = AM[r];
            a0 = fminf(fmaxf(a0 * am + bias1[4 * ls + 0], 0.0f), 1e30f);
            a1 = fminf(fmaxf(a1 * am + bias1[4 * ls + 1], 0.0f), 1e30f);
            a2 = fminf(fmaxf(a2 * am + bias1[4 * ls + 2], 0.0f), 1e30f);
            a3 = fminf(fmaxf(a3 * am + bias1[4 * ls + 3], 0.0f), 1e30f);
        }
        if (lane < 16) {
            uint2 wv;
            wv.x = pack2bf(a0, a1);
            wv.y = pack2bf(a2, a3);
            *(uint2*)&h16[lr][4 * ls] = wv;
        }
    }
    __syncthreads();

    // MFMA gemm2: waves 0-2 -> col tiles 0..2 (cols 0..47, wt2 zero-padded)
    if (w < 3) {
        const int m15 = lane & 15;
        const int q = lane >> 4;
        bf16x8 a[2];
#pragma unroll
        for (int ks = 0; ks < 2; ++ks)
            a[ks] = __builtin_bit_cast(bf16x8,
                        *(const uint4*)&h16[m15][ks * 32 + q * 8]);
        f32x4 acc = {0.f, 0.f, 0.f, 0.f};
        const int bn = w * 16 + m15;
#pragma unroll
        for (int ks = 0; ks < 2; ++ks) {
            const uint4 z = *(const uint4*)(wt2 + (size_t)bn * 64 + ks * 32 + q * 8);
            acc = __builtin_amdgcn_mfma_f32_16x16x32_bf16(
                a[ks], __builtin_bit_cast(bf16x8, z), acc, 0, 0, 0);
        }
        const int gcol = w * 16 + m15;
        if (gcol < 40) {
#pragma unroll
            for (int rr = 0; rr < 4; ++rr) {
                const int grow = rbase + q * 4 + rr;
                if (grow < n) out40[(size_t)grow * 40 + gcol] = f2bf(clampf(acc[rr]));
            }
        }
    }
}

// ---------------- SpMM F=40 + log_softmax: 3 edges/wave, 24 in flight ----------------

__launch_bounds__(256)
__global__ void spmm40_kernel(const uint4* __restrict__ packed16,
                              const int* __restrict__ rp, const unsigned short* __restrict__ X,
                              const float* __restrict__ bias,
                              float* __restrict__ out, int n) {
    const int lane = threadIdx.x & 63;
    const int g = lane / 20;
    const int ls = lane - 20 * g;
    const bool active = g < 3;
    const int r = (int)((blockIdx.x * (unsigned)blockDim.x + threadIdx.x) >> 6);
    if (r >= n) return;
    const int s = __builtin_amdgcn_readfirstlane(rp[r]);
    const int e = __builtin_amdgcn_readfirstlane(rp[r + 1]);

    float acc0 = 0.0f, acc1 = 0.0f;
    for (int base = s; base < e; base += 64) {
        const int nn = min(64, e - base);
        int ci = 0; float vf = 0.0f;
        if (lane < nn) {
            const uint4 pk = packed16[base + lane];
            ci = (int)pk.x;
            vf = __builtin_bit_cast(float, pk.z);    // adj (not adjZ) values
        }
        for (int j = 0; j < nn; j += 24) {
#pragma unroll
            for (int q = 0; q < 8; ++q) {
                const int jj = j + 3 * q + g;
                const bool ok = active && jj < nn;
                const int idx = jj & 63;
                const int c = __shfl(ci, idx);
                const float v = __shfl(vf, idx);
                if (ok) {
                    const unsigned u = *(const unsigned*)(X + (size_t)c * 40 + ls * 2);
                    acc0 += v * bf_lo(u);
                    acc1 += v * bf_hi(u);
                }
            }
        }
    }
    {
        const float a1 = __shfl(acc0, (lane + 20) & 63);
        const float a2 = __shfl(acc0, (lane + 40) & 63);
        const float b1 = __shfl(acc1, (lane + 20) & 63);
        const float b2 = __shfl(acc1, (lane + 40) & 63);
        acc0 += a1 + a2;
        acc1 += b1 + b2;
    }

    const bool own = lane < 20;
    const float vv0 = own ? fminf(fmaxf(acc0 + bias[2 * ls], -1e30f), 1e30f) : -INFINITY;
    const float vv1 = own ? fminf(fmaxf(acc1 + bias[2 * ls + 1], -1e30f), 1e30f) : -INFINITY;
    float mx = fmaxf(vv0, vv1);
#pragma unroll
    for (int off = 32; off > 0; off >>= 1) mx = fmaxf(mx, __shfl_xor(mx, off));
    float sum = own ? (expf(vv0 - mx) + expf(vv1 - mx)) : 0.0f;
#pragma unroll
    for (int off = 32; off > 0; off >>= 1) sum += __shfl_xor(sum, off);
    if (own) {
        const float lse = mx + logf(sum);
        *(float2*)(out + (size_t)r * 40 + ls * 2) = make_float2(vv0 - lse, vv1 - lse);
    }
}

// ---------------- launch ----------------

extern "C" void kernel_launch(void* const* d_in, const int* in_sizes, int n_in,
                              void* d_out, int out_size, void* d_ws, size_t ws_size,
                              hipStream_t stream) {
    const float* x    = (const float*)d_in[0];
    const float* M    = (const float*)d_in[1];
    const float* AM   = (const float*)d_in[2];
    const float* adjv = (const float*)d_in[3];
    const float* adjZ = (const float*)d_in[4];
    const float* W0   = (const float*)d_in[5];
    const float* b0   = (const float*)d_in[6];
    const float* W1   = (const float*)d_in[7];
    const float* b1   = (const float*)d_in[8];
    const float* W2   = (const float*)d_in[9];
    const float* b2   = (const float*)d_in[10];
    const int* row    = (const int*)d_in[11];
    const int* col    = (const int*)d_in[12];
    float* out = (float*)d_out;

    const int n = in_sizes[1];   // N  (must be <= NBINS = 50176)
    const int E = in_sizes[3];   // edges (<= NBMAX*16384)

    // workspace layout (~55 MB, NO aliasing):
    //   t_buf   : N*128 bf16 (gemm0 out; later stride-40 out of spmm64_g2)
    //   wt1/2   : bf16 W^T arrays (prep'd by hist_gemm0's extra block)
    //   h_buf   : N*128 bf16 (g1 stride-64 out of spmm128_g1)
    //   rp      : N+2 int
    //   gpub    : 256 u64 sync slots (zeroed by hist_gemm0's extra block)
    //   packed16: E uint4 {col, vZ, vA, 0}
    //   lrank   : E u16 | cntmat [NBMAX][NBINS] u16 | cmabs [NBMAX][NBINS] u32
    unsigned short* t_buf = (unsigned short*)d_ws;          // N*128 bf16
    unsigned short* wt1 = t_buf + (size_t)n * 128;          // 64*128
    unsigned short* wt2 = wt1 + 64 * 128;                   // 48*64
    unsigned short* h_buf = wt2 + 48 * 64;                  // N*128 bf16
    int* rp = (int*)(h_buf + (size_t)n * 128);              // N+1 (+pad)
    unsigned long long* gpub = (unsigned long long*)
        (((uintptr_t)(rp + n + 2) + 7) & ~(uintptr_t)7);    // 256 u64
    uint4* packed16 = (uint4*)
        (((uintptr_t)(gpub + 256) + 15) & ~(uintptr_t)15);  // E uint4
    unsigned short* lrank = (unsigned short*)(packed16 + (size_t)E);   // E u16
    unsigned short* cntmat = lrank + (size_t)E;             // [NBMAX][NBINS] u16
    unsigned* cmabs = (unsigned*)(cntmat + (size_t)NBMAX * NBINS);     // u32

    const int NB = (E + HIST_EPB - 1) >> HIST_EPB_LOG;      // hist chunks (<=49)
    const int gemmBlocks = (n + 63) / 64;                   // 4-wave gemm groups
    const int gemmB4 = (gemmBlocks + 3) / 4;                // 1024-thr gemm blocks
    // grid NB + gemmB4 + 1 must stay <= 256 (one block-wave at 98KB LDS)

    // fused LDS histogram + gemm0 (W0 self-transposed) + wt1/wt2/gpub prep
    hist_gemm0<<<NB + gemmB4 + 1, 1024, 0, stream>>>(row, cntmat, lrank, E, NB,
                                                     x, M, W0, W1, W2,
                                                     wt1, wt2, gpub, t_buf, n,
                                                     gemmB4);

    // one-kernel scan: rp + absolute chunk offsets (publish/read-poll)
    scan_one<<<SCAN_BLOCKS, 256, 0, stream>>>(cntmat, cmabs, rp, gpub, n, NB, E);

    // scatter, XCD-swizzled (one 16B random store per edge)
    const int scatGrid = 512 * ((NB + 7) / 8);
    scatter_kernel<<<scatGrid, 256, 0, stream>>>(row, col, adjv, adjZ,
                                                 cmabs, lrank, packed16, E, NB);

    const int blk16 = (n + 15) / 16;   // 16 rows per block

    // layer 0 aggregate + MFMA gemm1: h_buf(stride 64) = (M⊙h0)@W1
    spmm128_g1<<<blk16, 256, 0, stream>>>(packed16, rp, t_buf, AM, M, b0, wt1,
                                          h_buf, n);
    // layer 1 aggregate + MFMA gemm2: t_buf(stride 40) = relu(AM⊙agg+b1)@W2
    spmm64_g2<<<blk16, 256, 0, stream>>>(packed16, rp, h_buf, AM, b1, wt2,
                                         t_buf, n);
    // layer 2 aggregate + log_softmax
    spmm40_kernel<<<blk16 * 4, 256, 0, stream>>>(packed16, rp, t_buf, b2, out, n);
}